// Round 1
// baseline (225.733 us; speedup 1.0000x reference)
//
#include <hip/hip_runtime.h>
#include <hip/hip_fp16.h>

#define S_LEN 2048
#define NH 16
#define DK 64
#define DM 1024
#define NB 2
#define QKV_SZ (NB * NH * S_LEN * DK)  // 4194304 halfs per tensor

typedef _Float16 half8 __attribute__((ext_vector_type(8)));
typedef _Float16 half4v __attribute__((ext_vector_type(4)));
typedef __fp16 fp16x2 __attribute__((ext_vector_type(2)));
typedef float f32x4 __attribute__((ext_vector_type(4)));

// pack 4 f32 -> 4 f16 (rtz) as one 64-bit value
static __device__ __forceinline__ half4v pack4(const f32x4 v) {
  fp16x2 lo = __builtin_amdgcn_cvt_pkrtz(v[0], v[1]);
  fp16x2 hi = __builtin_amdgcn_cvt_pkrtz(v[2], v[3]);
  half4v r;
  ((fp16x2*)&r)[0] = lo;
  ((fp16x2*)&r)[1] = hi;
  return r;
}

#define GLL(gp, lp)                                                              \
  __builtin_amdgcn_global_load_lds(                                              \
      (const __attribute__((address_space(1))) unsigned int*)(gp),               \
      (__attribute__((address_space(3))) unsigned int*)(lp), 16, 0, 0)

// ---------------- conversion kernels ----------------

__global__ __launch_bounds__(256) void conv_f32_f16(const float* __restrict__ in,
                                                    _Float16* __restrict__ out, int n4) {
  int i = blockIdx.x * 256 + threadIdx.x;
  if (i >= n4) return;
  float4 v = ((const float4*)in)[i];
  half4v o;
  o[0] = (_Float16)v.x; o[1] = (_Float16)v.y; o[2] = (_Float16)v.z; o[3] = (_Float16)v.w;
  ((half4v*)out)[i] = o;
}

// All 4 weight transposes in one launch; z selects matrix.
// Wt[n][k] = (f16)(scale * W[k][n]), 1024x1024 each.
__global__ __launch_bounds__(256) void transpose_conv4(
    const float* __restrict__ Wq, const float* __restrict__ Wk,
    const float* __restrict__ Wv, const float* __restrict__ Wo,
    _Float16* __restrict__ Wqkvt, _Float16* __restrict__ Wot) {
  __shared__ float tile[32][33];
  int z = blockIdx.z;
  const float* W = (z == 0) ? Wq : (z == 1) ? Wk : (z == 2) ? Wv : Wo;
  _Float16* Wt = (z < 3) ? (Wqkvt + (size_t)z * 1048576) : Wot;
  float scale = (z == 0) ? 1.44269504f : 1.0f;  // fold log2(e) into Q path
  int tx = threadIdx.x, ty = threadIdx.y;
  int nx = blockIdx.x * 32 + tx;
  int ky = blockIdx.y * 32;
#pragma unroll
  for (int i = 0; i < 32; i += 8) tile[ty + i][tx] = W[(size_t)(ky + ty + i) * DM + nx];
  __syncthreads();
  int kx = ky + tx;
  int ny = blockIdx.x * 32;
#pragma unroll
  for (int i = 0; i < 32; i += 8)
    Wt[(size_t)(ny + ty + i) * DM + kx] = (_Float16)(tile[tx][ty + i] * scale);
}

// tab[h][r] = log2(e) * table[bucket(r-2047)][h], r in [0,4095)
__global__ __launch_bounds__(256) void bias_tab_kernel(const float* __restrict__ table,
                                                       float* __restrict__ tab) {
  int i = blockIdx.x * 256 + threadIdx.x;
  if (i >= NH * 4095) return;
  int h = i / 4095, r = i - h * 4095;
  int rel = r - 2047;              // rel = k - q
  int bucket = rel > 0 ? 16 : 0;
  int a = rel < 0 ? -rel : rel;
  if (a < 8) {
    bucket += a;
  } else {
    int lg = 31 - __clz(a * a);    // floor(2*log2(a))
    int large = 8 + (lg - 6);
    bucket += (large < 15 ? large : 15);
  }
  tab[i] = table[bucket * NH + h] * 1.44269504f;
}

// ---------------- fp16 MFMA GEMM: C = A(MxK) @ Bt(NxK)^T ----------------
// MODE 0: scatter f16 into Q[b,h,s,d] | K[b,h,s,d] | V^T[b,h,d,s]; MODE 1: f32 row-major.
template <int MODE>
__global__ __launch_bounds__(256) void gemm_f16(const _Float16* __restrict__ A,
                                                const _Float16* __restrict__ Bt,
                                                void* __restrict__ Cout,
                                                int M, int N, int K) {
  __shared__ _Float16 As[128 * 32];  // swizzled (no pad; global_load_lds)
  __shared__ _Float16 Bs[128 * 32];
  const int t = threadIdx.x;
  const int m0 = blockIdx.y * 128, n0 = blockIdx.x * 128;
  const int w = t >> 6, lane = t & 63, l15 = lane & 15, quad = lane >> 4;
  const int wr = (w >> 1) * 64, wc = (w & 1) * 64;
  const int swz = (quad ^ (l15 & 3)) * 8;

  f32x4 acc[4][4];
#pragma unroll
  for (int i = 0; i < 4; i++)
#pragma unroll
    for (int j = 0; j < 4; j++) acc[i][j] = (f32x4){0.f, 0.f, 0.f, 0.f};

  for (int k0 = 0; k0 < K; k0 += 32) {
    __syncthreads();
#pragma unroll
    for (int i = 0; i < 2; i++) {
      int id = t + 256 * i;
      int row = id >> 2, c = id & 3;
      int cg = c ^ (row & 3);
      GLL(A + (size_t)(m0 + row) * K + k0 + cg * 8, (char*)As + id * 16);
      GLL(Bt + (size_t)(n0 + row) * K + k0 + cg * 8, (char*)Bs + id * 16);
    }
    __syncthreads();
    half8 af[4], bf[4];
#pragma unroll
    for (int i = 0; i < 4; i++) af[i] = *(const half8*)(As + (wr + i * 16 + l15) * 32 + swz);
#pragma unroll
    for (int i = 0; i < 4; i++) bf[i] = *(const half8*)(Bs + (wc + i * 16 + l15) * 32 + swz);
#pragma unroll
    for (int i = 0; i < 4; i++)
#pragma unroll
      for (int j = 0; j < 4; j++)
        acc[i][j] = __builtin_amdgcn_mfma_f32_16x16x32_f16(af[i], bf[j], acc[i][j], 0, 0, 0);
  }

#pragma unroll
  for (int i = 0; i < 4; i++)
#pragma unroll
    for (int j = 0; j < 4; j++) {
      int row0 = m0 + wr + i * 16 + quad * 4;   // C/D: row=(lane>>4)*4+reg
      int col = n0 + wc + j * 16 + l15;         //      col=lane&15
      if (MODE == 1) {
#pragma unroll
        for (int r = 0; r < 4; r++)
          ((float*)Cout)[(size_t)(row0 + r) * N + col] = acc[i][j][r];
      } else {
        int which = col >> 10, rem = col & 1023, hh = rem >> 6, dd = rem & 63;
        int bb = row0 >> 11, ss = row0 & 2047;
        _Float16* base = (_Float16*)Cout;
        if (which == 2) {  // V: transposed store [b,h,d,s], 4 consecutive s -> b64
          *(half4v*)(base + (size_t)2 * QKV_SZ +
                     ((size_t)((bb * NH + hh) * DK + dd)) * S_LEN + ss) = pack4(acc[i][j]);
        } else {
#pragma unroll
          for (int r = 0; r < 4; r++)
            base[(size_t)which * QKV_SZ +
                 ((size_t)((bb * NH + hh) * S_LEN) + ss + r) * DK + dd] = (_Float16)acc[i][j][r];
        }
      }
    }
}

// ---------------- flash attention (S^T formulation, high-TLP) ----------------
// grid (S/128, H, B) = 512 blocks, block 256 = 4 waves; wave w owns q in [Q0+32w, +32)
// (two 16-q MFMA B-groups u=0,1 per wave -> halves per-q LDS fragment traffic).
// K/V tiles double-buffered in LDS with counted vmcnt (2-phase pipeline, raw s_barrier).
// S^T = K Q^T (+bias), per-lane online softmax (q=lane&15, per u), O^T = V^T P^T.
__global__ __launch_bounds__(256, 2) void attn_kernel(
    const _Float16* __restrict__ Q, const _Float16* __restrict__ K,
    const _Float16* __restrict__ Vt, const float* __restrict__ btab,
    _Float16* __restrict__ attn_out) {
  __shared__ _Float16 Ks[2][4096];   // [buf][key][d] 64x64, 16B-XOR swizzled
  __shared__ _Float16 Vs[2][4096];   // [buf][d][key] 64x64, 16B-XOR swizzled
  __shared__ _Float16 Ps[4][2048];   // per-wave P [q(32)][key(64)], 16B-XOR swizzled
  __shared__ float slab[512];        // bias for rel in [-256,256), log2e-scaled

  const int t = threadIdx.x;
  const int Q0 = blockIdx.x * 128;
  const int h = blockIdx.y, b = blockIdx.z;
  const int w = t >> 6, lane = t & 63, l15 = lane & 15, quad = lane >> 4;
  const int qw0 = Q0 + w * 32;
  const int sw7 = l15 & 7;

  const _Float16* Qb = Q + (size_t)(b * NH + h) * S_LEN * DK;
  const _Float16* Kb = K + (size_t)(b * NH + h) * S_LEN * DK;
  const _Float16* Vb = Vt + (size_t)(b * NH + h) * S_LEN * DK;  // [d][s]

  // slab[i] = bias(rel = i-256): global r = rel+2047 -> btab offset 1791+i
  for (int i = t; i < 512; i += 256) slab[i] = btab[h * 4095 + 1791 + i];

  // Q B-fragments (B[k=d][n=q]): lane(n=l15,quad) holds d = dh*32+quad*8+j; two q-groups u
  half8 qf[2][2];
#pragma unroll
  for (int u = 0; u < 2; u++)
#pragma unroll
    for (int dh = 0; dh < 2; dh++)
      qf[dh][u] = *(const half8*)(Qb + (size_t)(qw0 + u * 16 + l15) * DK + dh * 32 + quad * 8);

  f32x4 o[4][2];
#pragma unroll
  for (int dt = 0; dt < 4; dt++)
#pragma unroll
    for (int u = 0; u < 2; u++) o[dt][u] = (f32x4){0.f, 0.f, 0.f, 0.f};
  float m_[2] = {-INFINITY, -INFINITY}, l_[2] = {0.f, 0.f};

  // stage one 64-key K/V tile into buffer bs (4 GLL / thread)
#define STAGE(bs, kk0)                                                           \
  do {                                                                           \
    _Pragma("unroll")                                                            \
    for (int i_ = 0; i_ < 2; i_++) {                                             \
      int id_ = t + 256 * i_;                                                    \
      int row_ = id_ >> 3, c_ = id_ & 7, cg_ = c_ ^ (row_ & 7);                  \
      GLL(Kb + (size_t)((kk0) + row_) * DK + cg_ * 8, (char*)Ks[bs] + id_ * 16); \
      GLL(Vb + (size_t)row_ * S_LEN + (kk0) + cg_ * 8, (char*)Vs[bs] + id_ * 16);\
    }                                                                            \
  } while (0)

  STAGE(0, 0);
  __asm__ volatile("s_waitcnt vmcnt(0) lgkmcnt(0)" ::: "memory");  // tile0 + slab + qf
  __builtin_amdgcn_s_barrier();

  int cur = 0;
  for (int k0 = 0; k0 < S_LEN; k0 += 64) {
    if (k0 + 64 < S_LEN) {
      STAGE(cur ^ 1, k0 + 64);                                // prefetch next tile
      __asm__ volatile("s_waitcnt vmcnt(4)" ::: "memory");    // drain current, keep next in flight
    } else {
      __asm__ volatile("s_waitcnt vmcnt(0)" ::: "memory");
    }
    __builtin_amdgcn_s_barrier();   // buf[cur] visible to all waves

    const _Float16* Kc = Ks[cur];
    const _Float16* Vc = Vs[cur];

    // K A-fragments
    half8 kf[4][2];
#pragma unroll
    for (int kt = 0; kt < 4; kt++)
#pragma unroll
      for (int dh = 0; dh < 2; dh++)
        kf[kt][dh] = *(const half8*)(&Kc[(kt * 16 + l15) * 64 + (((dh << 2) + quad) ^ sw7) * 8]);

    // S^T accumulators: init with bias (near) or zero (far; const bias via m-shift), per u
    f32x4 st[2][4];
    bool nearc[2];
    float cb[2];
#pragma unroll
    for (int u = 0; u < 2; u++) {
      const int dk0 = k0 - qw0 - u * 16;
      const bool farneg = (dk0 <= -191);   // all rel <= -128
      const bool farpos = (dk0 >= 143);    // all rel >= +128
      nearc[u] = !(farneg || farpos);
      cb[u] = farneg ? slab[128] : slab[384];
      if (nearc[u]) {
#pragma unroll
        for (int kt = 0; kt < 4; kt++) {
          int i0 = dk0 + kt * 16 + quad * 4 - l15 + 256;
          f32x4 v;
          v[0] = slab[i0]; v[1] = slab[i0 + 1]; v[2] = slab[i0 + 2]; v[3] = slab[i0 + 3];
          st[u][kt] = v;
        }
      } else {
#pragma unroll
        for (int kt = 0; kt < 4; kt++) st[u][kt] = (f32x4){0.f, 0.f, 0.f, 0.f};
      }
    }

#pragma unroll
    for (int kt = 0; kt < 4; kt++)
#pragma unroll
      for (int dh = 0; dh < 2; dh++)
#pragma unroll
        for (int u = 0; u < 2; u++)
          st[u][kt] =
              __builtin_amdgcn_mfma_f32_16x16x32_f16(kf[kt][dh], qf[dh][u], st[u][kt], 0, 0, 0);

    // online softmax (per-lane state, q = l15 within group u; quads hold disjoint keys)
#pragma unroll
    for (int u = 0; u < 2; u++) {
      float cm = fmaxf(fmaxf(st[u][0][0], st[u][0][1]), fmaxf(st[u][0][2], st[u][0][3]));
#pragma unroll
      for (int kt = 1; kt < 4; kt++)
        cm = fmaxf(cm, fmaxf(fmaxf(st[u][kt][0], st[u][kt][1]), fmaxf(st[u][kt][2], st[u][kt][3])));
      cm = fmaxf(cm, __shfl_xor(cm, 16));
      cm = fmaxf(cm, __shfl_xor(cm, 32));
      float mc = nearc[u] ? cm : cm + cb[u];
      if (__any(mc > m_[u])) {      // wave-uniform skip when running max unchanged
        float mnew = fmaxf(m_[u], mc);
        float alpha = __builtin_amdgcn_exp2f(m_[u] - mnew);
        m_[u] = mnew;
        l_[u] *= alpha;
#pragma unroll
        for (int dt = 0; dt < 4; dt++) o[dt][u] *= alpha;
      }
      float msub = nearc[u] ? m_[u] : m_[u] - cb[u];

      f32x4 lacc = (f32x4){0.f, 0.f, 0.f, 0.f};
#pragma unroll
      for (int kt = 0; kt < 4; kt++) {
        f32x4 p;
#pragma unroll
        for (int r = 0; r < 4; r++) p[r] = __builtin_amdgcn_exp2f(st[u][kt][r] - msub);
        lacc += p;
        // P[q][key=kt*16+quad*4 ..+4] -> b64, group16 swizzle g^=(l15&7)
        int g = 2 * kt + (quad >> 1);
        *(half4v*)(&Ps[w][(u * 16 + l15) * 64 + (g ^ sw7) * 8 + (quad & 1) * 4]) = pack4(p);
      }
      l_[u] += (lacc[0] + lacc[1]) + (lacc[2] + lacc[3]);
    }
    __asm__ volatile("s_waitcnt lgkmcnt(0)" ::: "memory");  // wave-local P RAW

    // O^T += V^T P^T : B-frag of P^T reads P[q][key] rows with swizzle
    half8 pf[2][2];
#pragma unroll
    for (int kh = 0; kh < 2; kh++)
#pragma unroll
      for (int u = 0; u < 2; u++)
        pf[kh][u] = *(const half8*)(&Ps[w][(u * 16 + l15) * 64 + (((kh << 2) + quad) ^ sw7) * 8]);

#pragma unroll
    for (int dt = 0; dt < 4; dt++)
#pragma unroll
      for (int kh = 0; kh < 2; kh++) {
        half8 vf = *(const half8*)(&Vc[(dt * 16 + l15) * 64 + (((kh << 2) + quad) ^ sw7) * 8]);
#pragma unroll
        for (int u = 0; u < 2; u++)
          o[dt][u] = __builtin_amdgcn_mfma_f32_16x16x32_f16(vf, pf[kh][u], o[dt][u], 0, 0, 0);
      }

    __builtin_amdgcn_s_barrier();   // all waves done reading buf[cur]; safe to restage
    cur ^= 1;
  }
#undef STAGE

  // finalize: reduce l over quads, normalize, store O^T (4 consecutive d -> b64)
#pragma unroll
  for (int u = 0; u < 2; u++) {
    float lf = l_[u];
    lf += __shfl_xor(lf, 16);
    lf += __shfl_xor(lf, 32);
    float inv = 1.0f / lf;
    int q = qw0 + u * 16 + l15;
#pragma unroll
    for (int dt = 0; dt < 4; dt++) {
      f32x4 ov = o[dt][u] * inv;
      *(half4v*)(attn_out + ((size_t)(b * S_LEN + q)) * DM + h * DK + dt * 16 + quad * 4) =
          pack4(ov);
    }
  }
}

// ---------------- launch ----------------
extern "C" void kernel_launch(void* const* d_in, const int* in_sizes, int n_in,
                              void* d_out, int out_size, void* d_ws, size_t ws_size,
                              hipStream_t stream) {
  const float* hs  = (const float*)d_in[0];
  const float* Wq  = (const float*)d_in[1];
  const float* Wk  = (const float*)d_in[2];
  const float* Wv  = (const float*)d_in[3];
  const float* Wo  = (const float*)d_in[4];
  const float* tbl = (const float*)d_in[5];
  float* out = (float*)d_out;
  char* ws = (char*)d_ws;

  _Float16* Xh    = (_Float16*)(ws);                    // 8 MB
  _Float16* Wqkvt = (_Float16*)(ws + (8u << 20));       // 6 MB (Wq|Wk|Wv transposed)
  _Float16* Wot   = (_Float16*)(ws + (14u << 20));      // 2 MB
  _Float16* Qd    = (_Float16*)(ws + (16u << 20));      // Q | K | V^T, 8 MB each
  _Float16* Kd    = Qd + (size_t)QKV_SZ;
  _Float16* Vd    = Qd + (size_t)2 * QKV_SZ;
  _Float16* Ah    = (_Float16*)(ws + (40u << 20));      // 8 MB attention out (b,s,h*d)
  float*    btab  = (float*)(ws + (48u << 20));         // 16*4095 f32

  conv_f32_f16<<<4096, 256, 0, stream>>>(hs, Xh, (NB * S_LEN * DM) / 4);
  transpose_conv4<<<dim3(32, 32, 4), dim3(32, 8), 0, stream>>>(Wq, Wk, Wv, Wo, Wqkvt, Wot);
  bias_tab_kernel<<<256, 256, 0, stream>>>(tbl, btab);

  gemm_f16<0><<<dim3(24, 32), 256, 0, stream>>>(Xh, Wqkvt, (void*)Qd, NB * S_LEN, 3 * DM, DM);
  attn_kernel<<<dim3(S_LEN / 128, NH, NB), 256, 0, stream>>>(Qd, Kd, Vd, btab, Ah);
  gemm_f16<1><<<dim3(8, 32), 256, 0, stream>>>(Ah, Wot, (void*)out, NB * S_LEN, DM, DM);
}

// Round 4
// 220.284 us; speedup vs baseline: 1.0247x; 1.0247x over previous
//
#include <hip/hip_runtime.h>
#include <hip/hip_fp16.h>

#define S_LEN 2048
#define NH 16
#define DK 64
#define DM 1024
#define NB 2
#define QKV_SZ (NB * NH * S_LEN * DK)  // 4194304 halfs per tensor

typedef _Float16 half8 __attribute__((ext_vector_type(8)));
typedef _Float16 half4v __attribute__((ext_vector_type(4)));
typedef __fp16 fp16x2 __attribute__((ext_vector_type(2)));
typedef float f32x4 __attribute__((ext_vector_type(4)));

// pack 4 f32 -> 4 f16 (rtz) as one 64-bit value
static __device__ __forceinline__ half4v pack4(const f32x4 v) {
  fp16x2 lo = __builtin_amdgcn_cvt_pkrtz(v[0], v[1]);
  fp16x2 hi = __builtin_amdgcn_cvt_pkrtz(v[2], v[3]);
  half4v r;
  ((fp16x2*)&r)[0] = lo;
  ((fp16x2*)&r)[1] = hi;
  return r;
}

#define GLL(gp, lp)                                                              \
  __builtin_amdgcn_global_load_lds(                                              \
      (const __attribute__((address_space(1))) unsigned int*)(gp),               \
      (__attribute__((address_space(3))) unsigned int*)(lp), 16, 0, 0)

// ---------------- conversion kernels ----------------

__global__ __launch_bounds__(256) void conv_f32_f16(const float* __restrict__ in,
                                                    _Float16* __restrict__ out, int n4) {
  int i = blockIdx.x * 256 + threadIdx.x;
  if (i >= n4) return;
  float4 v = ((const float4*)in)[i];
  half4v o;
  o[0] = (_Float16)v.x; o[1] = (_Float16)v.y; o[2] = (_Float16)v.z; o[3] = (_Float16)v.w;
  ((half4v*)out)[i] = o;
}

// All 4 weight transposes in one launch; z selects matrix.
// Wt[n][k] = (f16)(scale * W[k][n]), 1024x1024 each.
__global__ __launch_bounds__(256) void transpose_conv4(
    const float* __restrict__ Wq, const float* __restrict__ Wk,
    const float* __restrict__ Wv, const float* __restrict__ Wo,
    _Float16* __restrict__ Wqkvt, _Float16* __restrict__ Wot) {
  __shared__ float tile[32][33];
  int z = blockIdx.z;
  const float* W = (z == 0) ? Wq : (z == 1) ? Wk : (z == 2) ? Wv : Wo;
  _Float16* Wt = (z < 3) ? (Wqkvt + (size_t)z * 1048576) : Wot;
  float scale = (z == 0) ? 1.44269504f : 1.0f;  // fold log2(e) into Q path
  int tx = threadIdx.x, ty = threadIdx.y;
  int nx = blockIdx.x * 32 + tx;
  int ky = blockIdx.y * 32;
#pragma unroll
  for (int i = 0; i < 32; i += 8) tile[ty + i][tx] = W[(size_t)(ky + ty + i) * DM + nx];
  __syncthreads();
  int kx = ky + tx;
  int ny = blockIdx.x * 32;
#pragma unroll
  for (int i = 0; i < 32; i += 8)
    Wt[(size_t)(ny + ty + i) * DM + kx] = (_Float16)(tile[tx][ty + i] * scale);
}

// tab[h][r] = log2(e) * table[bucket(r-2047)][h], r in [0,4095)
__global__ __launch_bounds__(256) void bias_tab_kernel(const float* __restrict__ table,
                                                       float* __restrict__ tab) {
  int i = blockIdx.x * 256 + threadIdx.x;
  if (i >= NH * 4095) return;
  int h = i / 4095, r = i - h * 4095;
  int rel = r - 2047;              // rel = k - q
  int bucket = rel > 0 ? 16 : 0;
  int a = rel < 0 ? -rel : rel;
  if (a < 8) {
    bucket += a;
  } else {
    int lg = 31 - __clz(a * a);    // floor(2*log2(a))
    int large = 8 + (lg - 6);
    bucket += (large < 15 ? large : 15);
  }
  tab[i] = table[bucket * NH + h] * 1.44269504f;
}

// ---------------- fp16 MFMA GEMM: C = A(MxK) @ Bt(NxK)^T ----------------
// MODE 0: scatter f16 into Q[b,h,s,d] | K[b,h,s,d] | V^T[b,h,d,s]; MODE 1: f32 row-major.
template <int MODE>
__global__ __launch_bounds__(256) void gemm_f16(const _Float16* __restrict__ A,
                                                const _Float16* __restrict__ Bt,
                                                void* __restrict__ Cout,
                                                int M, int N, int K) {
  __shared__ _Float16 As[128 * 32];  // swizzled (no pad; global_load_lds)
  __shared__ _Float16 Bs[128 * 32];
  const int t = threadIdx.x;
  const int m0 = blockIdx.y * 128, n0 = blockIdx.x * 128;
  const int w = t >> 6, lane = t & 63, l15 = lane & 15, quad = lane >> 4;
  const int wr = (w >> 1) * 64, wc = (w & 1) * 64;
  const int swz = (quad ^ (l15 & 3)) * 8;

  f32x4 acc[4][4];
#pragma unroll
  for (int i = 0; i < 4; i++)
#pragma unroll
    for (int j = 0; j < 4; j++) acc[i][j] = (f32x4){0.f, 0.f, 0.f, 0.f};

  for (int k0 = 0; k0 < K; k0 += 32) {
    __syncthreads();
#pragma unroll
    for (int i = 0; i < 2; i++) {
      int id = t + 256 * i;
      int row = id >> 2, c = id & 3;
      int cg = c ^ (row & 3);
      GLL(A + (size_t)(m0 + row) * K + k0 + cg * 8, (char*)As + id * 16);
      GLL(Bt + (size_t)(n0 + row) * K + k0 + cg * 8, (char*)Bs + id * 16);
    }
    __syncthreads();
    half8 af[4], bf[4];
#pragma unroll
    for (int i = 0; i < 4; i++) af[i] = *(const half8*)(As + (wr + i * 16 + l15) * 32 + swz);
#pragma unroll
    for (int i = 0; i < 4; i++) bf[i] = *(const half8*)(Bs + (wc + i * 16 + l15) * 32 + swz);
#pragma unroll
    for (int i = 0; i < 4; i++)
#pragma unroll
      for (int j = 0; j < 4; j++)
        acc[i][j] = __builtin_amdgcn_mfma_f32_16x16x32_f16(af[i], bf[j], acc[i][j], 0, 0, 0);
  }

#pragma unroll
  for (int i = 0; i < 4; i++)
#pragma unroll
    for (int j = 0; j < 4; j++) {
      int row0 = m0 + wr + i * 16 + quad * 4;   // C/D: row=(lane>>4)*4+reg
      int col = n0 + wc + j * 16 + l15;         //      col=lane&15
      if (MODE == 1) {
#pragma unroll
        for (int r = 0; r < 4; r++)
          ((float*)Cout)[(size_t)(row0 + r) * N + col] = acc[i][j][r];
      } else {
        int which = col >> 10, rem = col & 1023, hh = rem >> 6, dd = rem & 63;
        int bb = row0 >> 11, ss = row0 & 2047;
        _Float16* base = (_Float16*)Cout;
        if (which == 2) {  // V: transposed store [b,h,d,s], 4 consecutive s -> b64
          *(half4v*)(base + (size_t)2 * QKV_SZ +
                     ((size_t)((bb * NH + hh) * DK + dd)) * S_LEN + ss) = pack4(acc[i][j]);
        } else {
#pragma unroll
          for (int r = 0; r < 4; r++)
            base[(size_t)which * QKV_SZ +
                 ((size_t)((bb * NH + hh) * S_LEN) + ss + r) * DK + dd] = (_Float16)acc[i][j][r];
        }
      }
    }
}

// ---------------- flash attention (S^T formulation, high-TLP) ----------------
// grid (S/64, H, B) = 1024 blocks (4/CU), block 256 = 4 waves; wave w owns q in [Q0+16w, +16).
// K/V double-buffered in LDS on the SAFE minimum 2-phase template: issue next-tile
// global_load_lds BEFORE compute (in flight under QK/softmax/PV), one __syncthreads()
// per tile (= vmcnt(0)+lgkmcnt(0)+barrier; no hand-rolled counted-vmcnt — R2/R3 raced).
// S^T = K Q^T (+bias) via 16x16x32; per-lane online softmax (q=lane&15).
// PV uses 16x16x16 MFMA: the S^T C/D layout (key=quad*4+r, q=l15) IS the 16x16x16
// B-fragment layout, so exp'd P feeds PV directly from registers — no LDS round-trip
// (numerics validated in R2's launch-once absmax = baseline 0.015625).
__global__ __launch_bounds__(256, 4) void attn_kernel(
    const _Float16* __restrict__ Q, const _Float16* __restrict__ K,
    const _Float16* __restrict__ Vt, const float* __restrict__ btab,
    _Float16* __restrict__ attn_out) {
  __shared__ _Float16 Ks[2][4096];   // [buf][key][d] 64x64, 16B-XOR swizzled
  __shared__ _Float16 Vs[2][4096];   // [buf][d][key] 64x64, 16B-XOR swizzled
  __shared__ float slab[512];        // bias for rel in [-256,256), log2e-scaled

  const int t = threadIdx.x;
  const int Q0 = blockIdx.x * 64;
  const int h = blockIdx.y, b = blockIdx.z;
  const int w = t >> 6, lane = t & 63, l15 = lane & 15, quad = lane >> 4;
  const int qw0 = Q0 + w * 16;
  const int sw7 = l15 & 7;

  const _Float16* Qb = Q + (size_t)(b * NH + h) * S_LEN * DK;
  const _Float16* Kb = K + (size_t)(b * NH + h) * S_LEN * DK;
  const _Float16* Vb = Vt + (size_t)(b * NH + h) * S_LEN * DK;  // [d][s]

  // slab[i] = bias(rel = i-256): global r = rel+2047 -> btab offset 1791+i
  for (int i = t; i < 512; i += 256) slab[i] = btab[h * 4095 + 1791 + i];

  // Q B-fragments (B[k=d][n=q]): lane(n=l15,quad) holds d = dh*32+quad*8+j
  half8 qf[2];
#pragma unroll
  for (int dh = 0; dh < 2; dh++)
    qf[dh] = *(const half8*)(Qb + (size_t)(qw0 + l15) * DK + dh * 32 + quad * 8);

  f32x4 o[4];
#pragma unroll
  for (int dt = 0; dt < 4; dt++) o[dt] = (f32x4){0.f, 0.f, 0.f, 0.f};
  float m_ = -INFINITY, l_ = 0.f;

  // stage one 64-key K/V tile into buffer bs (4 GLL / thread)
#define STAGE(bs, kk0)                                                           \
  do {                                                                           \
    _Pragma("unroll")                                                            \
    for (int i_ = 0; i_ < 2; i_++) {                                             \
      int id_ = t + 256 * i_;                                                    \
      int row_ = id_ >> 3, c_ = id_ & 7, cg_ = c_ ^ (row_ & 7);                  \
      GLL(Kb + (size_t)((kk0) + row_) * DK + cg_ * 8, (char*)Ks[bs] + id_ * 16); \
      GLL(Vb + (size_t)row_ * S_LEN + (kk0) + cg_ * 8, (char*)Vs[bs] + id_ * 16);\
    }                                                                            \
  } while (0)

  STAGE(0, 0);
  __syncthreads();   // drains tile0 GLL + slab; all waves see buf 0

  int cur = 0;
  for (int k0 = 0; k0 < S_LEN; k0 += 64) {
    if (k0 + 64 < S_LEN) STAGE(cur ^ 1, k0 + 64);  // prefetch: in flight under compute

    const _Float16* Kc = Ks[cur];
    const _Float16* Vc = Vs[cur];

    const int dk0 = k0 - qw0;
    const bool farneg = (dk0 <= -191);   // all rel <= -128
    const bool farpos = (dk0 >= 143);    // all rel >= +128
    const bool nearc = !(farneg || farpos);
    const float cb = farneg ? slab[128] : slab[384];

    // S^T accumulators: init with bias (near) or zero (far; const bias via m-shift)
    f32x4 st[4];
    if (nearc) {
#pragma unroll
      for (int kt = 0; kt < 4; kt++) {
        int i0 = dk0 + kt * 16 + quad * 4 - l15 + 256;
        f32x4 v;
        v[0] = slab[i0]; v[1] = slab[i0 + 1]; v[2] = slab[i0 + 2]; v[3] = slab[i0 + 3];
        st[kt] = v;
      }
    } else {
#pragma unroll
      for (int kt = 0; kt < 4; kt++) st[kt] = (f32x4){0.f, 0.f, 0.f, 0.f};
    }

    // K A-fragments
    half8 kf[4][2];
#pragma unroll
    for (int kt = 0; kt < 4; kt++)
#pragma unroll
      for (int dh = 0; dh < 2; dh++)
        kf[kt][dh] = *(const half8*)(&Kc[(kt * 16 + l15) * 64 + (((dh << 2) + quad) ^ sw7) * 8]);

#pragma unroll
    for (int kt = 0; kt < 4; kt++)
#pragma unroll
      for (int dh = 0; dh < 2; dh++)
        st[kt] = __builtin_amdgcn_mfma_f32_16x16x32_f16(kf[kt][dh], qf[dh], st[kt], 0, 0, 0);

    // online softmax (per-lane state, q = l15; quads hold disjoint keys)
    float cm = fmaxf(fmaxf(st[0][0], st[0][1]), fmaxf(st[0][2], st[0][3]));
#pragma unroll
    for (int kt = 1; kt < 4; kt++)
      cm = fmaxf(cm, fmaxf(fmaxf(st[kt][0], st[kt][1]), fmaxf(st[kt][2], st[kt][3])));
    cm = fmaxf(cm, __shfl_xor(cm, 16));
    cm = fmaxf(cm, __shfl_xor(cm, 32));
    float mc = nearc ? cm : cm + cb;
    if (__any(mc > m_)) {      // wave-uniform skip when running max unchanged
      float mnew = fmaxf(m_, mc);
      float alpha = __builtin_amdgcn_exp2f(m_ - mnew);
      m_ = mnew;
      l_ *= alpha;
#pragma unroll
      for (int dt = 0; dt < 4; dt++) o[dt] *= alpha;
    }
    float msub = nearc ? m_ : m_ - cb;

    // P stays in registers: pack4(exp(st[kt])) IS the 16x16x16 B-fragment
    // (B[k][n]: n=l15=q, k=quad*4+i = key within kt-block).
    half4v p16[4];
    f32x4 lacc = (f32x4){0.f, 0.f, 0.f, 0.f};
#pragma unroll
    for (int kt = 0; kt < 4; kt++) {
      f32x4 p;
#pragma unroll
      for (int r = 0; r < 4; r++) p[r] = __builtin_amdgcn_exp2f(st[kt][r] - msub);
      lacc += p;
      p16[kt] = pack4(p);
    }
    l_ += (lacc[0] + lacc[1]) + (lacc[2] + lacc[3]);

    // O^T += V^T P^T via 16x16x16: A-frag vf = V^T[d=dt*16+l15][key=kt*16+quad*4+i]
    // (b64 reads; XOR swizzle spreads rows -> 2 lanes/bank = free)
#pragma unroll
    for (int dt = 0; dt < 4; dt++) {
      half4v vf[4];
#pragma unroll
      for (int kt = 0; kt < 4; kt++)
        vf[kt] = *(const half4v*)(&Vc[(dt * 16 + l15) * 64 +
                                      ((2 * kt + (quad >> 1)) ^ sw7) * 8 + (quad & 1) * 4]);
#pragma unroll
      for (int kt = 0; kt < 4; kt++)
        o[dt] = __builtin_amdgcn_mfma_f32_16x16x16f16(vf[kt], p16[kt], o[dt], 0, 0, 0);
    }

    __syncthreads();   // drains prefetch GLL (vmcnt 0) + all LDS reads; swap safe
    cur ^= 1;
  }
#undef STAGE

  // finalize: reduce l over quads, normalize, store O^T (4 consecutive d -> b64)
  float lf = l_;
  lf += __shfl_xor(lf, 16);
  lf += __shfl_xor(lf, 32);
  float inv = 1.0f / lf;
  int q = qw0 + l15;
#pragma unroll
  for (int dt = 0; dt < 4; dt++) {
    f32x4 ov = o[dt] * inv;
    *(half4v*)(attn_out + ((size_t)(b * S_LEN + q)) * DM + h * DK + dt * 16 + quad * 4) =
        pack4(ov);
  }
}

// ---------------- launch ----------------
extern "C" void kernel_launch(void* const* d_in, const int* in_sizes, int n_in,
                              void* d_out, int out_size, void* d_ws, size_t ws_size,
                              hipStream_t stream) {
  const float* hs  = (const float*)d_in[0];
  const float* Wq  = (const float*)d_in[1];
  const float* Wk  = (const float*)d_in[2];
  const float* Wv  = (const float*)d_in[3];
  const float* Wo  = (const float*)d_in[4];
  const float* tbl = (const float*)d_in[5];
  float* out = (float*)d_out;
  char* ws = (char*)d_ws;

  _Float16* Xh    = (_Float16*)(ws);                    // 8 MB
  _Float16* Wqkvt = (_Float16*)(ws + (8u << 20));       // 6 MB (Wq|Wk|Wv transposed)
  _Float16* Wot   = (_Float16*)(ws + (14u << 20));      // 2 MB
  _Float16* Qd    = (_Float16*)(ws + (16u << 20));      // Q | K | V^T, 8 MB each
  _Float16* Kd    = Qd + (size_t)QKV_SZ;
  _Float16* Vd    = Qd + (size_t)2 * QKV_SZ;
  _Float16* Ah    = (_Float16*)(ws + (40u << 20));      // 8 MB attention out (b,s,h*d)
  float*    btab  = (float*)(ws + (48u << 20));         // 16*4095 f32

  conv_f32_f16<<<4096, 256, 0, stream>>>(hs, Xh, (NB * S_LEN * DM) / 4);
  transpose_conv4<<<dim3(32, 32, 4), dim3(32, 8), 0, stream>>>(Wq, Wk, Wv, Wo, Wqkvt, Wot);
  bias_tab_kernel<<<256, 256, 0, stream>>>(tbl, btab);

  gemm_f16<0><<<dim3(24, 32), 256, 0, stream>>>(Xh, Wqkvt, (void*)Qd, NB * S_LEN, 3 * DM, DM);
  attn_kernel<<<dim3(S_LEN / 64, NH, NB), 256, 0, stream>>>(Qd, Kd, Vd, btab, Ah);
  gemm_f16<1><<<dim3(8, 32), 256, 0, stream>>>(Ah, Wot, (void*)out, NB * S_LEN, DM, DM);
}

// Round 5
// 218.563 us; speedup vs baseline: 1.0328x; 1.0079x over previous
//
#include <hip/hip_runtime.h>
#include <hip/hip_fp16.h>

#define S_LEN 2048
#define NH 16
#define DK 64
#define DM 1024
#define NB 2
#define QKV_SZ (NB * NH * S_LEN * DK)  // 4194304 halfs per tensor

typedef _Float16 half8 __attribute__((ext_vector_type(8)));
typedef _Float16 half4v __attribute__((ext_vector_type(4)));
typedef __fp16 fp16x2 __attribute__((ext_vector_type(2)));
typedef float f32x4 __attribute__((ext_vector_type(4)));

// pack 4 f32 -> 4 f16 (rtz) as one 64-bit value
static __device__ __forceinline__ half4v pack4(const f32x4 v) {
  fp16x2 lo = __builtin_amdgcn_cvt_pkrtz(v[0], v[1]);
  fp16x2 hi = __builtin_amdgcn_cvt_pkrtz(v[2], v[3]);
  half4v r;
  ((fp16x2*)&r)[0] = lo;
  ((fp16x2*)&r)[1] = hi;
  return r;
}

#define GLL(gp, lp)                                                              \
  __builtin_amdgcn_global_load_lds(                                              \
      (const __attribute__((address_space(1))) unsigned int*)(gp),               \
      (__attribute__((address_space(3))) unsigned int*)(lp), 16, 0, 0)

// ---------------- conversion kernels ----------------

__global__ __launch_bounds__(256) void conv_f32_f16(const float* __restrict__ in,
                                                    _Float16* __restrict__ out, int n4) {
  int i = blockIdx.x * 256 + threadIdx.x;
  if (i >= n4) return;
  float4 v = ((const float4*)in)[i];
  half4v o;
  o[0] = (_Float16)v.x; o[1] = (_Float16)v.y; o[2] = (_Float16)v.z; o[3] = (_Float16)v.w;
  ((half4v*)out)[i] = o;
}

// All 4 weight transposes in one launch; z selects matrix.
// Wt[n][k] = (f16)(scale * W[k][n]), 1024x1024 each.
__global__ __launch_bounds__(256) void transpose_conv4(
    const float* __restrict__ Wq, const float* __restrict__ Wk,
    const float* __restrict__ Wv, const float* __restrict__ Wo,
    _Float16* __restrict__ Wqkvt, _Float16* __restrict__ Wot) {
  __shared__ float tile[32][33];
  int z = blockIdx.z;
  const float* W = (z == 0) ? Wq : (z == 1) ? Wk : (z == 2) ? Wv : Wo;
  _Float16* Wt = (z < 3) ? (Wqkvt + (size_t)z * 1048576) : Wot;
  float scale = (z == 0) ? 1.44269504f : 1.0f;  // fold log2(e) into Q path
  int tx = threadIdx.x, ty = threadIdx.y;
  int nx = blockIdx.x * 32 + tx;
  int ky = blockIdx.y * 32;
#pragma unroll
  for (int i = 0; i < 32; i += 8) tile[ty + i][tx] = W[(size_t)(ky + ty + i) * DM + nx];
  __syncthreads();
  int kx = ky + tx;
  int ny = blockIdx.x * 32;
#pragma unroll
  for (int i = 0; i < 32; i += 8)
    Wt[(size_t)(ny + ty + i) * DM + kx] = (_Float16)(tile[tx][ty + i] * scale);
}

// tab[h][r] = log2(e) * table[bucket(r-2047)][h], r in [0,4095)
__global__ __launch_bounds__(256) void bias_tab_kernel(const float* __restrict__ table,
                                                       float* __restrict__ tab) {
  int i = blockIdx.x * 256 + threadIdx.x;
  if (i >= NH * 4095) return;
  int h = i / 4095, r = i - h * 4095;
  int rel = r - 2047;              // rel = k - q
  int bucket = rel > 0 ? 16 : 0;
  int a = rel < 0 ? -rel : rel;
  if (a < 8) {
    bucket += a;
  } else {
    int lg = 31 - __clz(a * a);    // floor(2*log2(a))
    int large = 8 + (lg - 6);
    bucket += (large < 15 ? large : 15);
  }
  tab[i] = table[bucket * NH + h] * 1.44269504f;
}

// ---------------- fp16 MFMA GEMM: C = A(MxK) @ Bt(NxK)^T ----------------
// MODE 0: scatter f16 into Q[b,h,s,d] | K[b,h,s,d] | V^T[b,h,d,s]; MODE 1: f32 row-major.
template <int MODE>
__global__ __launch_bounds__(256) void gemm_f16(const _Float16* __restrict__ A,
                                                const _Float16* __restrict__ Bt,
                                                void* __restrict__ Cout,
                                                int M, int N, int K) {
  __shared__ _Float16 As[128 * 32];  // swizzled (no pad; global_load_lds)
  __shared__ _Float16 Bs[128 * 32];
  const int t = threadIdx.x;
  const int m0 = blockIdx.y * 128, n0 = blockIdx.x * 128;
  const int w = t >> 6, lane = t & 63, l15 = lane & 15, quad = lane >> 4;
  const int wr = (w >> 1) * 64, wc = (w & 1) * 64;
  const int swz = (quad ^ (l15 & 3)) * 8;

  f32x4 acc[4][4];
#pragma unroll
  for (int i = 0; i < 4; i++)
#pragma unroll
    for (int j = 0; j < 4; j++) acc[i][j] = (f32x4){0.f, 0.f, 0.f, 0.f};

  for (int k0 = 0; k0 < K; k0 += 32) {
    __syncthreads();
#pragma unroll
    for (int i = 0; i < 2; i++) {
      int id = t + 256 * i;
      int row = id >> 2, c = id & 3;
      int cg = c ^ (row & 3);
      GLL(A + (size_t)(m0 + row) * K + k0 + cg * 8, (char*)As + id * 16);
      GLL(Bt + (size_t)(n0 + row) * K + k0 + cg * 8, (char*)Bs + id * 16);
    }
    __syncthreads();
    half8 af[4], bf[4];
#pragma unroll
    for (int i = 0; i < 4; i++) af[i] = *(const half8*)(As + (wr + i * 16 + l15) * 32 + swz);
#pragma unroll
    for (int i = 0; i < 4; i++) bf[i] = *(const half8*)(Bs + (wc + i * 16 + l15) * 32 + swz);
#pragma unroll
    for (int i = 0; i < 4; i++)
#pragma unroll
      for (int j = 0; j < 4; j++)
        acc[i][j] = __builtin_amdgcn_mfma_f32_16x16x32_f16(af[i], bf[j], acc[i][j], 0, 0, 0);
  }

#pragma unroll
  for (int i = 0; i < 4; i++)
#pragma unroll
    for (int j = 0; j < 4; j++) {
      int row0 = m0 + wr + i * 16 + quad * 4;   // C/D: row=(lane>>4)*4+reg
      int col = n0 + wc + j * 16 + l15;         //      col=lane&15
      if (MODE == 1) {
#pragma unroll
        for (int r = 0; r < 4; r++)
          ((float*)Cout)[(size_t)(row0 + r) * N + col] = acc[i][j][r];
      } else {
        int which = col >> 10, rem = col & 1023, hh = rem >> 6, dd = rem & 63;
        int bb = row0 >> 11, ss = row0 & 2047;
        _Float16* base = (_Float16*)Cout;
        if (which == 2) {  // V: transposed store [b,h,d,s], 4 consecutive s -> b64
          *(half4v*)(base + (size_t)2 * QKV_SZ +
                     ((size_t)((bb * NH + hh) * DK + dd)) * S_LEN + ss) = pack4(acc[i][j]);
        } else {
#pragma unroll
          for (int r = 0; r < 4; r++)
            base[(size_t)which * QKV_SZ +
                 ((size_t)((bb * NH + hh) * S_LEN) + ss + r) * DK + dd] = (_Float16)acc[i][j][r];
        }
      }
    }
}

// ---------------- flash attention (S^T formulation, high-TLP) ----------------
// grid (S/64, H, B) = 1024 blocks (4/CU), block 256 = 4 waves; wave w owns q in [Q0+16w, +16).
// Safe 2-phase staging: issue next-tile GLL before compute, one __syncthreads per tile.
// KEY PERMUTATION (R5): Ks row p holds key sigma(p), sigma(half*16+quad*4+j) =
// quad*8+half*4+j per 32-key superblock. Then lane(quad)'s 8 P-values span keys
// s*32+quad*8..+7 (contiguous!), so the PV V^T read is ONE conflict-free b128 per
// (dt, superblock) whose compile-time register halves feed two 16x16x16 MFMAs
// (B-frags p16[2s], p16[2s+1]) — no b64 4-way-conflict reads (R4's 8.4M cycles),
// no LDS P round-trip (R0). Softmax is key-permutation-invariant; bias reindexed.
__global__ __launch_bounds__(256, 4) void attn_kernel(
    const _Float16* __restrict__ Q, const _Float16* __restrict__ K,
    const _Float16* __restrict__ Vt, const float* __restrict__ btab,
    _Float16* __restrict__ attn_out) {
  __shared__ _Float16 Ks[2][4096];   // [buf][pos][d] 64x64, 16B-XOR swizzled, keys sigma-permuted
  __shared__ _Float16 Vs[2][4096];   // [buf][d][key] 64x64, 16B-XOR swizzled, natural keys
  __shared__ float slab[512];        // bias for rel in [-256,256), log2e-scaled

  const int t = threadIdx.x;
  const int Q0 = blockIdx.x * 64;
  const int h = blockIdx.y, b = blockIdx.z;
  const int w = t >> 6, lane = t & 63, l15 = lane & 15, quad = lane >> 4;
  const int qw0 = Q0 + w * 16;
  const int sw7 = l15 & 7;

  const _Float16* Qb = Q + (size_t)(b * NH + h) * S_LEN * DK;
  const _Float16* Kb = K + (size_t)(b * NH + h) * S_LEN * DK;
  const _Float16* Vb = Vt + (size_t)(b * NH + h) * S_LEN * DK;  // [d][s]

  // slab[i] = bias(rel = i-256): global r = rel+2047 -> btab offset 1791+i
  for (int i = t; i < 512; i += 256) slab[i] = btab[h * 4095 + 1791 + i];

  // Q B-fragments (B[k=d][n=q]): lane(n=l15,quad) holds d = dh*32+quad*8+j
  half8 qf[2];
#pragma unroll
  for (int dh = 0; dh < 2; dh++)
    qf[dh] = *(const half8*)(Qb + (size_t)(qw0 + l15) * DK + dh * 32 + quad * 8);

  f32x4 o[4];
#pragma unroll
  for (int dt = 0; dt < 4; dt++) o[dt] = (f32x4){0.f, 0.f, 0.f, 0.f};
  float m_ = -INFINITY, l_ = 0.f;

  // stage one 64-key K/V tile into buffer bs (4 GLL / thread).
  // K rows are sigma-permuted: LDS pos row_ <- global key sr_.
#define STAGE(bs, kk0)                                                           \
  do {                                                                           \
    _Pragma("unroll")                                                            \
    for (int i_ = 0; i_ < 2; i_++) {                                             \
      int id_ = t + 256 * i_;                                                    \
      int row_ = id_ >> 3, c_ = id_ & 7, cg_ = c_ ^ (row_ & 7);                  \
      int p_ = row_ & 31;                                                        \
      int sr_ = (row_ & 32) | (((p_ >> 2) & 3) << 3) | ((p_ >> 4) << 2) | (p_ & 3);\
      GLL(Kb + (size_t)((kk0) + sr_) * DK + cg_ * 8, (char*)Ks[bs] + id_ * 16);  \
      GLL(Vb + (size_t)row_ * S_LEN + (kk0) + cg_ * 8, (char*)Vs[bs] + id_ * 16);\
    }                                                                            \
  } while (0)

  STAGE(0, 0);
  __syncthreads();   // drains tile0 GLL + slab; all waves see buf 0

  int cur = 0;
  for (int k0 = 0; k0 < S_LEN; k0 += 64) {
    if (k0 + 64 < S_LEN) STAGE(cur ^ 1, k0 + 64);  // prefetch: in flight under compute

    const _Float16* Kc = Ks[cur];
    const _Float16* Vc = Vs[cur];

    const int dk0 = k0 - qw0;
    const bool farneg = (dk0 <= -191);   // all rel <= -128
    const bool farpos = (dk0 >= 143);    // all rel >= +128
    const bool nearc = !(farneg || farpos);
    const float cb = farneg ? slab[128] : slab[384];

    // S^T accumulators: init with bias (near) or zero (far; const bias via m-shift).
    // st[kt] reg r <-> key = (kt>>1)*32 + quad*8 + (kt&1)*4 + r  (sigma applied)
    f32x4 st[4];
    if (nearc) {
#pragma unroll
      for (int kt = 0; kt < 4; kt++) {
        int i0 = dk0 + (kt >> 1) * 32 + quad * 8 + (kt & 1) * 4 - l15 + 256;
        f32x4 v;
        v[0] = slab[i0]; v[1] = slab[i0 + 1]; v[2] = slab[i0 + 2]; v[3] = slab[i0 + 3];
        st[kt] = v;
      }
    } else {
#pragma unroll
      for (int kt = 0; kt < 4; kt++) st[kt] = (f32x4){0.f, 0.f, 0.f, 0.f};
    }

    // K A-fragments (position-indexed; content is sigma-permuted keys)
    half8 kf[4][2];
#pragma unroll
    for (int kt = 0; kt < 4; kt++)
#pragma unroll
      for (int dh = 0; dh < 2; dh++)
        kf[kt][dh] = *(const half8*)(&Kc[(kt * 16 + l15) * 64 + (((dh << 2) + quad) ^ sw7) * 8]);

#pragma unroll
    for (int kt = 0; kt < 4; kt++)
#pragma unroll
      for (int dh = 0; dh < 2; dh++)
        st[kt] = __builtin_amdgcn_mfma_f32_16x16x32_f16(kf[kt][dh], qf[dh], st[kt], 0, 0, 0);

    // online softmax (per-lane state, q = l15; permutation-invariant reductions)
    float cm = fmaxf(fmaxf(st[0][0], st[0][1]), fmaxf(st[0][2], st[0][3]));
#pragma unroll
    for (int kt = 1; kt < 4; kt++)
      cm = fmaxf(cm, fmaxf(fmaxf(st[kt][0], st[kt][1]), fmaxf(st[kt][2], st[kt][3])));
    cm = fmaxf(cm, __shfl_xor(cm, 16));
    cm = fmaxf(cm, __shfl_xor(cm, 32));
    float mc = nearc ? cm : cm + cb;
    if (__any(mc > m_)) {      // wave-uniform skip when running max unchanged
      float mnew = fmaxf(m_, mc);
      float alpha = __builtin_amdgcn_exp2f(m_ - mnew);
      m_ = mnew;
      l_ *= alpha;
#pragma unroll
      for (int dt = 0; dt < 4; dt++) o[dt] *= alpha;
    }
    float msub = nearc ? m_ : m_ - cb;

    // P in registers: p16[2s+b][r] = P[key = s*32 + quad*8 + b*4 + r], the
    // 16x16x16 B-fragment for PV block (s,b).
    half4v p16[4];
    f32x4 lacc = (f32x4){0.f, 0.f, 0.f, 0.f};
#pragma unroll
    for (int kt = 0; kt < 4; kt++) {
      f32x4 p;
#pragma unroll
      for (int r = 0; r < 4; r++) p[r] = __builtin_amdgcn_exp2f(st[kt][r] - msub);
      lacc += p;
      p16[kt] = pack4(p);
    }
    l_ += (lacc[0] + lacc[1]) + (lacc[2] + lacc[3]);

    // O^T += V^T P^T via 16x16x16. One b128 per (dt, superblock s): keys
    // s*32+quad*8..+7 at row dt*16+l15 (octet s*4+quad, conflict-free like K reads).
    // Compile-time halves = A-frags for blocks (s,0),(s,1) matching p16[2s],p16[2s+1].
#pragma unroll
    for (int dt = 0; dt < 4; dt++) {
      half8 vf8[2];
#pragma unroll
      for (int s = 0; s < 2; s++)
        vf8[s] = *(const half8*)(&Vc[(dt * 16 + l15) * 64 + ((s * 4 + quad) ^ sw7) * 8]);
#pragma unroll
      for (int s = 0; s < 2; s++) {
        half4v vlo = {vf8[s][0], vf8[s][1], vf8[s][2], vf8[s][3]};
        half4v vhi = {vf8[s][4], vf8[s][5], vf8[s][6], vf8[s][7]};
        o[dt] = __builtin_amdgcn_mfma_f32_16x16x16f16(vlo, p16[2 * s], o[dt], 0, 0, 0);
        o[dt] = __builtin_amdgcn_mfma_f32_16x16x16f16(vhi, p16[2 * s + 1], o[dt], 0, 0, 0);
      }
    }

    __syncthreads();   // drains prefetch GLL (vmcnt 0) + all LDS reads; swap safe
    cur ^= 1;
  }
#undef STAGE

  // finalize: reduce l over quads, normalize, store O^T (4 consecutive d -> b64)
  float lf = l_;
  lf += __shfl_xor(lf, 16);
  lf += __shfl_xor(lf, 32);
  float inv = 1.0f / lf;
  int q = qw0 + l15;
#pragma unroll
  for (int dt = 0; dt < 4; dt++) {
    f32x4 ov = o[dt] * inv;
    *(half4v*)(attn_out + ((size_t)(b * S_LEN + q)) * DM + h * DK + dt * 16 + quad * 4) =
        pack4(ov);
  }
}

// ---------------- launch ----------------
extern "C" void kernel_launch(void* const* d_in, const int* in_sizes, int n_in,
                              void* d_out, int out_size, void* d_ws, size_t ws_size,
                              hipStream_t stream) {
  const float* hs  = (const float*)d_in[0];
  const float* Wq  = (const float*)d_in[1];
  const float* Wk  = (const float*)d_in[2];
  const float* Wv  = (const float*)d_in[3];
  const float* Wo  = (const float*)d_in[4];
  const float* tbl = (const float*)d_in[5];
  float* out = (float*)d_out;
  char* ws = (char*)d_ws;

  _Float16* Xh    = (_Float16*)(ws);                    // 8 MB
  _Float16* Wqkvt = (_Float16*)(ws + (8u << 20));       // 6 MB (Wq|Wk|Wv transposed)
  _Float16* Wot   = (_Float16*)(ws + (14u << 20));      // 2 MB
  _Float16* Qd    = (_Float16*)(ws + (16u << 20));      // Q | K | V^T, 8 MB each
  _Float16* Kd    = Qd + (size_t)QKV_SZ;
  _Float16* Vd    = Qd + (size_t)2 * QKV_SZ;
  _Float16* Ah    = (_Float16*)(ws + (40u << 20));      // 8 MB attention out (b,s,h*d)
  float*    btab  = (float*)(ws + (48u << 20));         // 16*4095 f32

  conv_f32_f16<<<4096, 256, 0, stream>>>(hs, Xh, (NB * S_LEN * DM) / 4);
  transpose_conv4<<<dim3(32, 32, 4), dim3(32, 8), 0, stream>>>(Wq, Wk, Wv, Wo, Wqkvt, Wot);
  bias_tab_kernel<<<256, 256, 0, stream>>>(tbl, btab);

  gemm_f16<0><<<dim3(24, 32), 256, 0, stream>>>(Xh, Wqkvt, (void*)Qd, NB * S_LEN, 3 * DM, DM);
  attn_kernel<<<dim3(S_LEN / 64, NH, NB), 256, 0, stream>>>(Qd, Kd, Vd, btab, Ah);
  gemm_f16<1><<<dim3(8, 32), 256, 0, stream>>>(Ah, Wot, (void*)out, NB * S_LEN, DM, DM);
}

// Round 6
// 215.743 us; speedup vs baseline: 1.0463x; 1.0131x over previous
//
#include <hip/hip_runtime.h>
#include <hip/hip_fp16.h>

#define S_LEN 2048
#define NH 16
#define DK 64
#define DM 1024
#define NB 2
#define QKV_SZ (NB * NH * S_LEN * DK)  // 4194304 halfs per tensor

typedef _Float16 half8 __attribute__((ext_vector_type(8)));
typedef _Float16 half4v __attribute__((ext_vector_type(4)));
typedef __fp16 fp16x2 __attribute__((ext_vector_type(2)));
typedef float f32x4 __attribute__((ext_vector_type(4)));

// pack 4 f32 -> 4 f16 (rtz) as one 64-bit value
static __device__ __forceinline__ half4v pack4(const f32x4 v) {
  fp16x2 lo = __builtin_amdgcn_cvt_pkrtz(v[0], v[1]);
  fp16x2 hi = __builtin_amdgcn_cvt_pkrtz(v[2], v[3]);
  half4v r;
  ((fp16x2*)&r)[0] = lo;
  ((fp16x2*)&r)[1] = hi;
  return r;
}

#define GLL(gp, lp)                                                              \
  __builtin_amdgcn_global_load_lds(                                              \
      (const __attribute__((address_space(1))) unsigned int*)(gp),               \
      (__attribute__((address_space(3))) unsigned int*)(lp), 16, 0, 0)

// ---------------- conversion kernels ----------------

__global__ __launch_bounds__(256) void conv_f32_f16(const float* __restrict__ in,
                                                    _Float16* __restrict__ out, int n4) {
  int i = blockIdx.x * 256 + threadIdx.x;
  if (i >= n4) return;
  float4 v = ((const float4*)in)[i];
  half4v o;
  o[0] = (_Float16)v.x; o[1] = (_Float16)v.y; o[2] = (_Float16)v.z; o[3] = (_Float16)v.w;
  ((half4v*)out)[i] = o;
}

// All 4 weight transposes in one launch; z selects matrix.
// Wt[n][k] = (f16)(scale * W[k][n]), 1024x1024 each.
__global__ __launch_bounds__(256) void transpose_conv4(
    const float* __restrict__ Wq, const float* __restrict__ Wk,
    const float* __restrict__ Wv, const float* __restrict__ Wo,
    _Float16* __restrict__ Wqkvt, _Float16* __restrict__ Wot) {
  __shared__ float tile[32][33];
  int z = blockIdx.z;
  const float* W = (z == 0) ? Wq : (z == 1) ? Wk : (z == 2) ? Wv : Wo;
  _Float16* Wt = (z < 3) ? (Wqkvt + (size_t)z * 1048576) : Wot;
  float scale = (z == 0) ? 1.44269504f : 1.0f;  // fold log2(e) into Q path
  int tx = threadIdx.x, ty = threadIdx.y;
  int nx = blockIdx.x * 32 + tx;
  int ky = blockIdx.y * 32;
#pragma unroll
  for (int i = 0; i < 32; i += 8) tile[ty + i][tx] = W[(size_t)(ky + ty + i) * DM + nx];
  __syncthreads();
  int kx = ky + tx;
  int ny = blockIdx.x * 32;
#pragma unroll
  for (int i = 0; i < 32; i += 8)
    Wt[(size_t)(ny + ty + i) * DM + kx] = (_Float16)(tile[tx][ty + i] * scale);
}

// tab[h][r] = log2(e) * table[bucket(r-2047)][h], r in [0,4095)
__global__ __launch_bounds__(256) void bias_tab_kernel(const float* __restrict__ table,
                                                       float* __restrict__ tab) {
  int i = blockIdx.x * 256 + threadIdx.x;
  if (i >= NH * 4095) return;
  int h = i / 4095, r = i - h * 4095;
  int rel = r - 2047;              // rel = k - q
  int bucket = rel > 0 ? 16 : 0;
  int a = rel < 0 ? -rel : rel;
  if (a < 8) {
    bucket += a;
  } else {
    int lg = 31 - __clz(a * a);    // floor(2*log2(a))
    int large = 8 + (lg - 6);
    bucket += (large < 15 ? large : 15);
  }
  tab[i] = table[bucket * NH + h] * 1.44269504f;
}

// ---------------- fp16 MFMA GEMM: C = A(MxK) @ Bt(NxK)^T ----------------
// MODE 0: scatter f16 into Q[b,h,s,d] | K[b,h,s,d] | V^T[b,h,d,s]; MODE 1: f32 row-major.
template <int MODE>
__global__ __launch_bounds__(256) void gemm_f16(const _Float16* __restrict__ A,
                                                const _Float16* __restrict__ Bt,
                                                void* __restrict__ Cout,
                                                int M, int N, int K) {
  __shared__ _Float16 As[128 * 32];  // swizzled (no pad; global_load_lds)
  __shared__ _Float16 Bs[128 * 32];
  const int t = threadIdx.x;
  const int m0 = blockIdx.y * 128, n0 = blockIdx.x * 128;
  const int w = t >> 6, lane = t & 63, l15 = lane & 15, quad = lane >> 4;
  const int wr = (w >> 1) * 64, wc = (w & 1) * 64;
  const int swz = (quad ^ (l15 & 3)) * 8;

  f32x4 acc[4][4];
#pragma unroll
  for (int i = 0; i < 4; i++)
#pragma unroll
    for (int j = 0; j < 4; j++) acc[i][j] = (f32x4){0.f, 0.f, 0.f, 0.f};

  for (int k0 = 0; k0 < K; k0 += 32) {
    __syncthreads();
#pragma unroll
    for (int i = 0; i < 2; i++) {
      int id = t + 256 * i;
      int row = id >> 2, c = id & 3;
      int cg = c ^ (row & 3);
      GLL(A + (size_t)(m0 + row) * K + k0 + cg * 8, (char*)As + id * 16);
      GLL(Bt + (size_t)(n0 + row) * K + k0 + cg * 8, (char*)Bs + id * 16);
    }
    __syncthreads();
    half8 af[4], bf[4];
#pragma unroll
    for (int i = 0; i < 4; i++) af[i] = *(const half8*)(As + (wr + i * 16 + l15) * 32 + swz);
#pragma unroll
    for (int i = 0; i < 4; i++) bf[i] = *(const half8*)(Bs + (wc + i * 16 + l15) * 32 + swz);
#pragma unroll
    for (int i = 0; i < 4; i++)
#pragma unroll
      for (int j = 0; j < 4; j++)
        acc[i][j] = __builtin_amdgcn_mfma_f32_16x16x32_f16(af[i], bf[j], acc[i][j], 0, 0, 0);
  }

#pragma unroll
  for (int i = 0; i < 4; i++)
#pragma unroll
    for (int j = 0; j < 4; j++) {
      int row0 = m0 + wr + i * 16 + quad * 4;   // C/D: row=(lane>>4)*4+reg
      int col = n0 + wc + j * 16 + l15;         //      col=lane&15
      if (MODE == 1) {
#pragma unroll
        for (int r = 0; r < 4; r++)
          ((float*)Cout)[(size_t)(row0 + r) * N + col] = acc[i][j][r];
      } else {
        int which = col >> 10, rem = col & 1023, hh = rem >> 6, dd = rem & 63;
        int bb = row0 >> 11, ss = row0 & 2047;
        _Float16* base = (_Float16*)Cout;
        if (which == 2) {  // V: transposed store [b,h,d,s], 4 consecutive s -> b64
          *(half4v*)(base + (size_t)2 * QKV_SZ +
                     ((size_t)((bb * NH + hh) * DK + dd)) * S_LEN + ss) = pack4(acc[i][j]);
        } else {
#pragma unroll
          for (int r = 0; r < 4; r++)
            base[(size_t)which * QKV_SZ +
                 ((size_t)((bb * NH + hh) * S_LEN) + ss + r) * DK + dd] = (_Float16)acc[i][j][r];
        }
      }
    }
}

// ---------------- flash attention (S^T formulation, high-TLP) ----------------
// grid (S/64, H, B) = 1024 blocks (4/CU), block 256 = 4 waves; wave w owns q in [Q0+16w, +16).
// Safe 2-phase staging (R4): issue next-tile GLL before compute, one __syncthreads per tile.
// sigma key-permutation (R5): conflict-free b128 LDS reads everywhere; P stays in registers
// feeding 16x16x16 PV MFMAs directly.
// R6 VALU diet: loop unrolled x2 (buffer index literal -> immediate-offset ds_reads),
// staging addresses fully hoisted (saddr+invariant voffset), l-sum via MFMA with A=ones
// (kills 19 VALU adds/tile + final shfl-reduce), max3-shaped fmax tree, cb in registers,
// s_setprio around MFMA clusters (cross-block phase diversity, m191 regime).
__global__ __launch_bounds__(256, 4) void attn_kernel(
    const _Float16* __restrict__ Q, const _Float16* __restrict__ K,
    const _Float16* __restrict__ Vt, const float* __restrict__ btab,
    _Float16* __restrict__ attn_out) {
  __shared__ _Float16 Ks[2][4096];   // [buf][pos][d] 64x64, 16B-XOR swizzled, sigma-permuted keys
  __shared__ _Float16 Vs[2][4096];   // [buf][d][key] 64x64, 16B-XOR swizzled, natural keys
  __shared__ float slab[512];        // bias for rel in [-256,256), log2e-scaled

  const int t = threadIdx.x;
  const int Q0 = blockIdx.x * 64;
  const int h = blockIdx.y, b = blockIdx.z;
  const int w = t >> 6, lane = t & 63, l15 = lane & 15, quad = lane >> 4;
  const int qw0 = Q0 + w * 16;
  const int sw7 = l15 & 7;

  const _Float16* Qb = Q + (size_t)(b * NH + h) * S_LEN * DK;
  const _Float16* Kb = K + (size_t)(b * NH + h) * S_LEN * DK;
  const _Float16* Vb = Vt + (size_t)(b * NH + h) * S_LEN * DK;  // [d][s]

  // slab[i] = bias(rel = i-256): global r = rel+2047 -> btab offset 1791+i
  for (int i = t; i < 512; i += 256) slab[i] = btab[h * 4095 + 1791 + i];
  const float cbn = btab[h * 4095 + 1791 + 128];  // bias(rel<=-128), uniform per h
  const float cbp = btab[h * 4095 + 1791 + 384];  // bias(rel>=+128)

  // ---- loop-invariant staging offsets (per-thread) ----
  const int id0 = t, id1 = t + 256;
  const int r0_ = id0 >> 3, cg0 = (id0 & 7) ^ (r0_ & 7), p0 = r0_ & 31;
  const int sr0 = (r0_ & 32) | (((p0 >> 2) & 3) << 3) | ((p0 >> 4) << 2) | (p0 & 3);
  const int r1_ = id1 >> 3, cg1 = (id1 & 7) ^ (r1_ & 7), p1 = r1_ & 31;
  const int sr1 = (r1_ & 32) | (((p1 >> 2) & 3) << 3) | ((p1 >> 4) << 2) | (p1 & 3);
  const int kofa = sr0 * DK + cg0 * 8, kofb = sr1 * DK + cg1 * 8;
  const int vofa = r0_ * S_LEN + cg0 * 8, vofb = r1_ * S_LEN + cg1 * 8;
  const int lda = id0 * 16, ldb = id1 * 16;  // LDS byte offsets (linear, GLL order)

#define STAGE(bs, kk0)                                   \
  do {                                                   \
    const _Float16* kp_ = Kb + (size_t)(kk0) * DK;       \
    const _Float16* vp_ = Vb + (kk0);                    \
    GLL(kp_ + kofa, (char*)Ks[bs] + lda);                \
    GLL(kp_ + kofb, (char*)Ks[bs] + ldb);                \
    GLL(vp_ + vofa, (char*)Vs[bs] + lda);                \
    GLL(vp_ + vofb, (char*)Vs[bs] + ldb);                \
  } while (0)

  // Q B-fragments (B[k=d][n=q]): lane(n=l15,quad) holds d = dh*32+quad*8+j
  half8 qf[2];
#pragma unroll
  for (int dh = 0; dh < 2; dh++)
    qf[dh] = *(const half8*)(Qb + (size_t)(qw0 + l15) * DK + dh * 32 + quad * 8);

  f32x4 o[4];
#pragma unroll
  for (int dt = 0; dt < 4; dt++) o[dt] = (f32x4){0.f, 0.f, 0.f, 0.f};
  f32x4 lac = (f32x4){0.f, 0.f, 0.f, 0.f};   // l-sum accumulator (MFMA ones-trick)
  float m_ = -INFINITY;
  const half4v ones = {(_Float16)1.f, (_Float16)1.f, (_Float16)1.f, (_Float16)1.f};

  // loop-invariant LDS read offsets (half-index): rd1 = rd0 ^ 32 (the dh/s=1 XOR lane)
  const int rd0 = l15 * 64 + (quad ^ sw7) * 8;
  const int rd1 = rd0 ^ 32;

  STAGE(0, 0);
  __syncthreads();   // drains tile0 GLL + slab; all waves see buf 0

  // ---- one 64-key tile; c is a literal so all ds_reads are base+immediate ----
#define TILE(c, kk, stage_ok)                                                         \
  do {                                                                                \
    if (stage_ok) STAGE((c) ^ 1, (kk) + 64);  /* prefetch: in flight under compute */ \
    const int dk0 = (kk) - qw0;                                                       \
    const bool farneg = (dk0 <= -191);                                                \
    const bool farpos = (dk0 >= 143);                                                 \
    const bool nearc = !(farneg || farpos);                                           \
    const float cb = farneg ? cbn : cbp;                                              \
    f32x4 st[4];                                                                      \
    if (nearc) {                                                                      \
      _Pragma("unroll") for (int kt = 0; kt < 4; kt++) {                              \
        int i0 = dk0 + (kt >> 1) * 32 + quad * 8 + (kt & 1) * 4 - l15 + 256;          \
        f32x4 v_;                                                                     \
        v_[0] = slab[i0]; v_[1] = slab[i0 + 1];                                       \
        v_[2] = slab[i0 + 2]; v_[3] = slab[i0 + 3];                                   \
        st[kt] = v_;                                                                  \
      }                                                                               \
    } else {                                                                          \
      _Pragma("unroll") for (int kt = 0; kt < 4; kt++)                                \
          st[kt] = (f32x4){0.f, 0.f, 0.f, 0.f};                                       \
    }                                                                                 \
    half8 kf0[4], kf1[4];                                                             \
    _Pragma("unroll") for (int kt = 0; kt < 4; kt++) {                                \
      kf0[kt] = *(const half8*)(&Ks[c][rd0 + kt * 1024]);                             \
      kf1[kt] = *(const half8*)(&Ks[c][rd1 + kt * 1024]);                             \
    }                                                                                 \
    __builtin_amdgcn_s_setprio(1);                                                    \
    _Pragma("unroll") for (int kt = 0; kt < 4; kt++) {                                \
      st[kt] = __builtin_amdgcn_mfma_f32_16x16x32_f16(kf0[kt], qf[0], st[kt], 0, 0, 0); \
      st[kt] = __builtin_amdgcn_mfma_f32_16x16x32_f16(kf1[kt], qf[1], st[kt], 0, 0, 0); \
    }                                                                                 \
    __builtin_amdgcn_s_setprio(0);                                                    \
    /* max tree (max3-fusable) */                                                     \
    float x0 = fmaxf(fmaxf(st[0][0], st[0][1]), st[0][2]);                            \
    float x1 = fmaxf(fmaxf(st[0][3], st[1][0]), st[1][1]);                            \
    float x2 = fmaxf(fmaxf(st[1][2], st[1][3]), st[2][0]);                            \
    float x3 = fmaxf(fmaxf(st[2][1], st[2][2]), st[2][3]);                            \
    float x4 = fmaxf(fmaxf(st[3][0], st[3][1]), st[3][2]);                            \
    float cm = fmaxf(fmaxf(fmaxf(x0, x1), fmaxf(x2, x3)), fmaxf(x4, st[3][3]));       \
    cm = fmaxf(cm, __shfl_xor(cm, 16));                                               \
    cm = fmaxf(cm, __shfl_xor(cm, 32));                                               \
    float mc = nearc ? cm : cm + cb;                                                  \
    if (__any(mc > m_)) {      /* wave-uniform skip when running max unchanged */     \
      float mnew = fmaxf(m_, mc);                                                     \
      float alpha = __builtin_amdgcn_exp2f(m_ - mnew);                                \
      m_ = mnew;                                                                      \
      lac *= alpha;                                                                   \
      _Pragma("unroll") for (int dt = 0; dt < 4; dt++) o[dt] *= alpha;                \
    }                                                                                 \
    float msub = nearc ? m_ : m_ - cb;                                                \
    half4v p16[4];                                                                    \
    _Pragma("unroll") for (int kt = 0; kt < 4; kt++) {                                \
      f32x4 p_;                                                                       \
      _Pragma("unroll") for (int r = 0; r < 4; r++)                                   \
          p_[r] = __builtin_amdgcn_exp2f(st[kt][r] - msub);                           \
      p16[kt] = pack4(p_);                                                            \
    }                                                                                 \
    __builtin_amdgcn_s_setprio(1);                                                    \
    /* l-sum via MFMA: A=ones -> every acc reg += full 16-key sum of P (per q=l15) */ \
    _Pragma("unroll") for (int kt = 0; kt < 4; kt++)                                  \
        lac = __builtin_amdgcn_mfma_f32_16x16x16f16(ones, p16[kt], lac, 0, 0, 0);     \
    _Pragma("unroll") for (int dt = 0; dt < 4; dt++) {                                \
      half8 va_ = *(const half8*)(&Vs[c][rd0 + dt * 1024]);                           \
      half8 vb_ = *(const half8*)(&Vs[c][rd1 + dt * 1024]);                           \
      half4v alo = {va_[0], va_[1], va_[2], va_[3]};                                  \
      half4v ahi = {va_[4], va_[5], va_[6], va_[7]};                                  \
      half4v blo = {vb_[0], vb_[1], vb_[2], vb_[3]};                                  \
      half4v bhi = {vb_[4], vb_[5], vb_[6], vb_[7]};                                  \
      o[dt] = __builtin_amdgcn_mfma_f32_16x16x16f16(alo, p16[0], o[dt], 0, 0, 0);     \
      o[dt] = __builtin_amdgcn_mfma_f32_16x16x16f16(ahi, p16[1], o[dt], 0, 0, 0);     \
      o[dt] = __builtin_amdgcn_mfma_f32_16x16x16f16(blo, p16[2], o[dt], 0, 0, 0);     \
      o[dt] = __builtin_amdgcn_mfma_f32_16x16x16f16(bhi, p16[3], o[dt], 0, 0, 0);     \
    }                                                                                 \
    __builtin_amdgcn_s_setprio(0);                                                    \
    __syncthreads();   /* drains prefetch GLL + all LDS reads; swap safe */           \
  } while (0)

  for (int k0 = 0; k0 < S_LEN; k0 += 128) {
    TILE(0, k0, 1);                              // stage for k0+64 (always valid)
    TILE(1, k0 + 64, (k0 + 128 < S_LEN));        // stage for k0+128 (skip on last)
  }
#undef TILE
#undef STAGE

  // finalize: lac already holds full l in every reg/lane (ones-MFMA sums all quads)
  float inv = 1.0f / lac[0];
  int q = qw0 + l15;
#pragma unroll
  for (int dt = 0; dt < 4; dt++) {
    f32x4 ov = o[dt] * inv;
    *(half4v*)(attn_out + ((size_t)(b * S_LEN + q)) * DM + h * DK + dt * 16 + quad * 4) =
        pack4(ov);
  }
}

// ---------------- launch ----------------
extern "C" void kernel_launch(void* const* d_in, const int* in_sizes, int n_in,
                              void* d_out, int out_size, void* d_ws, size_t ws_size,
                              hipStream_t stream) {
  const float* hs  = (const float*)d_in[0];
  const float* Wq  = (const float*)d_in[1];
  const float* Wk  = (const float*)d_in[2];
  const float* Wv  = (const float*)d_in[3];
  const float* Wo  = (const float*)d_in[4];
  const float* tbl = (const float*)d_in[5];
  float* out = (float*)d_out;
  char* ws = (char*)d_ws;

  _Float16* Xh    = (_Float16*)(ws);                    // 8 MB
  _Float16* Wqkvt = (_Float16*)(ws + (8u << 20));       // 6 MB (Wq|Wk|Wv transposed)
  _Float16* Wot   = (_Float16*)(ws + (14u << 20));      // 2 MB
  _Float16* Qd    = (_Float16*)(ws + (16u << 20));      // Q | K | V^T, 8 MB each
  _Float16* Kd    = Qd + (size_t)QKV_SZ;
  _Float16* Vd    = Qd + (size_t)2 * QKV_SZ;
  _Float16* Ah    = (_Float16*)(ws + (40u << 20));      // 8 MB attention out (b,s,h*d)
  float*    btab  = (float*)(ws + (48u << 20));         // 16*4095 f32

  conv_f32_f16<<<4096, 256, 0, stream>>>(hs, Xh, (NB * S_LEN * DM) / 4);
  transpose_conv4<<<dim3(32, 32, 4), dim3(32, 8), 0, stream>>>(Wq, Wk, Wv, Wo, Wqkvt, Wot);
  bias_tab_kernel<<<256, 256, 0, stream>>>(tbl, btab);

  gemm_f16<0><<<dim3(24, 32), 256, 0, stream>>>(Xh, Wqkvt, (void*)Qd, NB * S_LEN, 3 * DM, DM);
  attn_kernel<<<dim3(S_LEN / 64, NH, NB), 256, 0, stream>>>(Qd, Kd, Vd, btab, Ah);
  gemm_f16<1><<<dim3(8, 32), 256, 0, stream>>>(Ah, Wot, (void*)out, NB * S_LEN, DM, DM);
}

// Round 7
// 210.368 us; speedup vs baseline: 1.0730x; 1.0255x over previous
//
#include <hip/hip_runtime.h>
#include <hip/hip_fp16.h>

#define S_LEN 2048
#define NH 16
#define DK 64
#define DM 1024
#define NB 2
#define QKV_SZ (NB * NH * S_LEN * DK)  // 4194304 halfs per tensor

typedef _Float16 half8 __attribute__((ext_vector_type(8)));
typedef _Float16 half4v __attribute__((ext_vector_type(4)));
typedef __fp16 fp16x2 __attribute__((ext_vector_type(2)));
typedef float f32x4 __attribute__((ext_vector_type(4)));

// pack 4 f32 -> 4 f16 (rtz) as one 64-bit value
static __device__ __forceinline__ half4v pack4(const f32x4 v) {
  fp16x2 lo = __builtin_amdgcn_cvt_pkrtz(v[0], v[1]);
  fp16x2 hi = __builtin_amdgcn_cvt_pkrtz(v[2], v[3]);
  half4v r;
  ((fp16x2*)&r)[0] = lo;
  ((fp16x2*)&r)[1] = hi;
  return r;
}

#define GLL(gp, lp)                                                              \
  __builtin_amdgcn_global_load_lds(                                              \
      (const __attribute__((address_space(1))) unsigned int*)(gp),               \
      (__attribute__((address_space(3))) unsigned int*)(lp), 16, 0, 0)

// ---------------- conversion kernels ----------------

__global__ __launch_bounds__(256) void conv_f32_f16(const float* __restrict__ in,
                                                    _Float16* __restrict__ out, int n4) {
  int i = blockIdx.x * 256 + threadIdx.x;
  if (i >= n4) return;
  float4 v = ((const float4*)in)[i];
  half4v o;
  o[0] = (_Float16)v.x; o[1] = (_Float16)v.y; o[2] = (_Float16)v.z; o[3] = (_Float16)v.w;
  ((half4v*)out)[i] = o;
}

// All 4 weight transposes in one launch; z selects matrix.
// Wt[n][k] = (f16)(scale * W[k][n]), 1024x1024 each.
__global__ __launch_bounds__(256) void transpose_conv4(
    const float* __restrict__ Wq, const float* __restrict__ Wk,
    const float* __restrict__ Wv, const float* __restrict__ Wo,
    _Float16* __restrict__ Wqkvt, _Float16* __restrict__ Wot) {
  __shared__ float tile[32][33];
  int z = blockIdx.z;
  const float* W = (z == 0) ? Wq : (z == 1) ? Wk : (z == 2) ? Wv : Wo;
  _Float16* Wt = (z < 3) ? (Wqkvt + (size_t)z * 1048576) : Wot;
  float scale = (z == 0) ? 1.44269504f : 1.0f;  // fold log2(e) into Q path
  int tx = threadIdx.x, ty = threadIdx.y;
  int nx = blockIdx.x * 32 + tx;
  int ky = blockIdx.y * 32;
#pragma unroll
  for (int i = 0; i < 32; i += 8) tile[ty + i][tx] = W[(size_t)(ky + ty + i) * DM + nx];
  __syncthreads();
  int kx = ky + tx;
  int ny = blockIdx.x * 32;
#pragma unroll
  for (int i = 0; i < 32; i += 8)
    Wt[(size_t)(ny + ty + i) * DM + kx] = (_Float16)(tile[tx][ty + i] * scale);
}

// tab[h][r] = log2(e) * table[bucket(r-2047)][h], r in [0,4095)
__global__ __launch_bounds__(256) void bias_tab_kernel(const float* __restrict__ table,
                                                       float* __restrict__ tab) {
  int i = blockIdx.x * 256 + threadIdx.x;
  if (i >= NH * 4095) return;
  int h = i / 4095, r = i - h * 4095;
  int rel = r - 2047;              // rel = k - q
  int bucket = rel > 0 ? 16 : 0;
  int a = rel < 0 ? -rel : rel;
  if (a < 8) {
    bucket += a;
  } else {
    int lg = 31 - __clz(a * a);    // floor(2*log2(a))
    int large = 8 + (lg - 6);
    bucket += (large < 15 ? large : 15);
  }
  tab[i] = table[bucket * NH + h] * 1.44269504f;
}

// ---------------- fp16 MFMA GEMM: C = A(MxK) @ Bt(NxK)^T ----------------
// MODE 0: scatter f16 into Q[b,h,s,d] | K[b,h,s,d] | V^T[b,h,d,s]; MODE 1: f32 row-major.
template <int MODE>
__global__ __launch_bounds__(256) void gemm_f16(const _Float16* __restrict__ A,
                                                const _Float16* __restrict__ Bt,
                                                void* __restrict__ Cout,
                                                int M, int N, int K) {
  __shared__ _Float16 As[128 * 32];  // swizzled (no pad; global_load_lds)
  __shared__ _Float16 Bs[128 * 32];
  const int t = threadIdx.x;
  const int m0 = blockIdx.y * 128, n0 = blockIdx.x * 128;
  const int w = t >> 6, lane = t & 63, l15 = lane & 15, quad = lane >> 4;
  const int wr = (w >> 1) * 64, wc = (w & 1) * 64;
  const int swz = (quad ^ (l15 & 3)) * 8;

  f32x4 acc[4][4];
#pragma unroll
  for (int i = 0; i < 4; i++)
#pragma unroll
    for (int j = 0; j < 4; j++) acc[i][j] = (f32x4){0.f, 0.f, 0.f, 0.f};

  for (int k0 = 0; k0 < K; k0 += 32) {
    __syncthreads();
#pragma unroll
    for (int i = 0; i < 2; i++) {
      int id = t + 256 * i;
      int row = id >> 2, c = id & 3;
      int cg = c ^ (row & 3);
      GLL(A + (size_t)(m0 + row) * K + k0 + cg * 8, (char*)As + id * 16);
      GLL(Bt + (size_t)(n0 + row) * K + k0 + cg * 8, (char*)Bs + id * 16);
    }
    __syncthreads();
    half8 af[4], bf[4];
#pragma unroll
    for (int i = 0; i < 4; i++) af[i] = *(const half8*)(As + (wr + i * 16 + l15) * 32 + swz);
#pragma unroll
    for (int i = 0; i < 4; i++) bf[i] = *(const half8*)(Bs + (wc + i * 16 + l15) * 32 + swz);
#pragma unroll
    for (int i = 0; i < 4; i++)
#pragma unroll
      for (int j = 0; j < 4; j++)
        acc[i][j] = __builtin_amdgcn_mfma_f32_16x16x32_f16(af[i], bf[j], acc[i][j], 0, 0, 0);
  }

#pragma unroll
  for (int i = 0; i < 4; i++)
#pragma unroll
    for (int j = 0; j < 4; j++) {
      int row0 = m0 + wr + i * 16 + quad * 4;   // C/D: row=(lane>>4)*4+reg
      int col = n0 + wc + j * 16 + l15;         //      col=lane&15
      if (MODE == 1) {
#pragma unroll
        for (int r = 0; r < 4; r++)
          ((float*)Cout)[(size_t)(row0 + r) * N + col] = acc[i][j][r];
      } else {
        int which = col >> 10, rem = col & 1023, hh = rem >> 6, dd = rem & 63;
        int bb = row0 >> 11, ss = row0 & 2047;
        _Float16* base = (_Float16*)Cout;
        if (which == 2) {  // V: transposed store [b,h,d,s], 4 consecutive s -> b64
          *(half4v*)(base + (size_t)2 * QKV_SZ +
                     ((size_t)((bb * NH + hh) * DK + dd)) * S_LEN + ss) = pack4(acc[i][j]);
        } else {
#pragma unroll
          for (int r = 0; r < 4; r++)
            base[(size_t)which * QKV_SZ +
                 ((size_t)((bb * NH + hh) * S_LEN) + ss + r) * DK + dd] = (_Float16)acc[i][j][r];
        }
      }
    }
}

// ---------------- 128x64-tile fp16 GEMM (f32 out) for the N=1024 output proj ----
// Same staging/swizzle/fragment pattern as gemm_f16, but BN=64 -> grid 16x32 =
// 512 blocks = 2 blocks/CU (the 128x128 version had 256 blocks = 1/CU: occupancy-
// starved, nothing hides the 2-barrier loop latency).
__global__ __launch_bounds__(256) void gemm_f16_n64(const _Float16* __restrict__ A,
                                                    const _Float16* __restrict__ Bt,
                                                    float* __restrict__ C,
                                                    int M, int N, int K) {
  __shared__ _Float16 As[128 * 32];
  __shared__ _Float16 Bs[64 * 32];
  const int t = threadIdx.x;
  const int m0 = blockIdx.y * 128, n0 = blockIdx.x * 64;
  const int w = t >> 6, lane = t & 63, l15 = lane & 15, quad = lane >> 4;
  const int wr = (w >> 1) * 64, wc = (w & 1) * 32;   // 2x2 waves, each 64x32
  const int swz = (quad ^ (l15 & 3)) * 8;

  f32x4 acc[4][2];
#pragma unroll
  for (int i = 0; i < 4; i++)
#pragma unroll
    for (int j = 0; j < 2; j++) acc[i][j] = (f32x4){0.f, 0.f, 0.f, 0.f};

  for (int k0 = 0; k0 < K; k0 += 32) {
    __syncthreads();
#pragma unroll
    for (int i = 0; i < 2; i++) {
      int id = t + 256 * i;
      int row = id >> 2, c = id & 3;
      int cg = c ^ (row & 3);
      GLL(A + (size_t)(m0 + row) * K + k0 + cg * 8, (char*)As + id * 16);
    }
    {
      int row = t >> 2, c = t & 3;
      int cg = c ^ (row & 3);
      GLL(Bt + (size_t)(n0 + row) * K + k0 + cg * 8, (char*)Bs + t * 16);
    }
    __syncthreads();
    half8 af[4], bf[2];
#pragma unroll
    for (int i = 0; i < 4; i++) af[i] = *(const half8*)(As + (wr + i * 16 + l15) * 32 + swz);
#pragma unroll
    for (int j = 0; j < 2; j++) bf[j] = *(const half8*)(Bs + (wc + j * 16 + l15) * 32 + swz);
#pragma unroll
    for (int i = 0; i < 4; i++)
#pragma unroll
      for (int j = 0; j < 2; j++)
        acc[i][j] = __builtin_amdgcn_mfma_f32_16x16x32_f16(af[i], bf[j], acc[i][j], 0, 0, 0);
  }

#pragma unroll
  for (int i = 0; i < 4; i++)
#pragma unroll
    for (int j = 0; j < 2; j++) {
      int row0 = m0 + wr + i * 16 + quad * 4;   // C/D: row=(lane>>4)*4+reg
      int col = n0 + wc + j * 16 + l15;         //      col=lane&15
#pragma unroll
      for (int r = 0; r < 4; r++)
        C[(size_t)(row0 + r) * N + col] = acc[i][j][r];
    }
}

// ---------------- flash attention (S^T formulation, high-TLP) ----------------
// grid (S/64, H, B) = 1024 blocks (4/CU), block 256 = 4 waves; wave w owns q in [Q0+16w, +16).
// Safe 2-phase staging (R4): issue next-tile GLL before compute, one __syncthreads per tile.
// sigma key-permutation (R5): conflict-free b128 LDS reads everywhere; P stays in registers
// feeding 16x16x16 PV MFMAs directly.
// R6 VALU diet: loop unrolled x2, staging addresses hoisted, l-sum via ones-MFMA,
// max3 tree, cb in registers, s_setprio around MFMA clusters.
// R7: T13 defer-max (threshold 8 in log2 units): skip the o/lac rescale unless the
// running max grew by >8 -> P bounded by 2^8 (f16-safe), rescale pass nearly always skipped.
__global__ __launch_bounds__(256, 4) void attn_kernel(
    const _Float16* __restrict__ Q, const _Float16* __restrict__ K,
    const _Float16* __restrict__ Vt, const float* __restrict__ btab,
    _Float16* __restrict__ attn_out) {
  __shared__ _Float16 Ks[2][4096];   // [buf][pos][d] 64x64, 16B-XOR swizzled, sigma-permuted keys
  __shared__ _Float16 Vs[2][4096];   // [buf][d][key] 64x64, 16B-XOR swizzled, natural keys
  __shared__ float slab[512];        // bias for rel in [-256,256), log2e-scaled

  const int t = threadIdx.x;
  const int Q0 = blockIdx.x * 64;
  const int h = blockIdx.y, b = blockIdx.z;
  const int w = t >> 6, lane = t & 63, l15 = lane & 15, quad = lane >> 4;
  const int qw0 = Q0 + w * 16;
  const int sw7 = l15 & 7;

  const _Float16* Qb = Q + (size_t)(b * NH + h) * S_LEN * DK;
  const _Float16* Kb = K + (size_t)(b * NH + h) * S_LEN * DK;
  const _Float16* Vb = Vt + (size_t)(b * NH + h) * S_LEN * DK;  // [d][s]

  // slab[i] = bias(rel = i-256): global r = rel+2047 -> btab offset 1791+i
  for (int i = t; i < 512; i += 256) slab[i] = btab[h * 4095 + 1791 + i];
  const float cbn = btab[h * 4095 + 1791 + 128];  // bias(rel<=-128), uniform per h
  const float cbp = btab[h * 4095 + 1791 + 384];  // bias(rel>=+128)

  // ---- loop-invariant staging offsets (per-thread) ----
  const int id0 = t, id1 = t + 256;
  const int r0_ = id0 >> 3, cg0 = (id0 & 7) ^ (r0_ & 7), p0 = r0_ & 31;
  const int sr0 = (r0_ & 32) | (((p0 >> 2) & 3) << 3) | ((p0 >> 4) << 2) | (p0 & 3);
  const int r1_ = id1 >> 3, cg1 = (id1 & 7) ^ (r1_ & 7), p1 = r1_ & 31;
  const int sr1 = (r1_ & 32) | (((p1 >> 2) & 3) << 3) | ((p1 >> 4) << 2) | (p1 & 3);
  const int kofa = sr0 * DK + cg0 * 8, kofb = sr1 * DK + cg1 * 8;
  const int vofa = r0_ * S_LEN + cg0 * 8, vofb = r1_ * S_LEN + cg1 * 8;
  const int lda = id0 * 16, ldb = id1 * 16;  // LDS byte offsets (linear, GLL order)

#define STAGE(bs, kk0)                                   \
  do {                                                   \
    const _Float16* kp_ = Kb + (size_t)(kk0) * DK;       \
    const _Float16* vp_ = Vb + (kk0);                    \
    GLL(kp_ + kofa, (char*)Ks[bs] + lda);                \
    GLL(kp_ + kofb, (char*)Ks[bs] + ldb);                \
    GLL(vp_ + vofa, (char*)Vs[bs] + lda);                \
    GLL(vp_ + vofb, (char*)Vs[bs] + ldb);                \
  } while (0)

  // Q B-fragments (B[k=d][n=q]): lane(n=l15,quad) holds d = dh*32+quad*8+j
  half8 qf[2];
#pragma unroll
  for (int dh = 0; dh < 2; dh++)
    qf[dh] = *(const half8*)(Qb + (size_t)(qw0 + l15) * DK + dh * 32 + quad * 8);

  f32x4 o[4];
#pragma unroll
  for (int dt = 0; dt < 4; dt++) o[dt] = (f32x4){0.f, 0.f, 0.f, 0.f};
  f32x4 lac = (f32x4){0.f, 0.f, 0.f, 0.f};   // l-sum accumulator (MFMA ones-trick)
  float m_ = -INFINITY;
  const half4v ones = {(_Float16)1.f, (_Float16)1.f, (_Float16)1.f, (_Float16)1.f};

  // loop-invariant LDS read offsets (half-index): rd1 = rd0 ^ 32 (the dh/s=1 XOR lane)
  const int rd0 = l15 * 64 + (quad ^ sw7) * 8;
  const int rd1 = rd0 ^ 32;

  STAGE(0, 0);
  __syncthreads();   // drains tile0 GLL + slab; all waves see buf 0

  // ---- one 64-key tile; c is a literal so all ds_reads are base+immediate ----
#define TILE(c, kk, stage_ok)                                                         \
  do {                                                                                \
    if (stage_ok) STAGE((c) ^ 1, (kk) + 64);  /* prefetch: in flight under compute */ \
    const int dk0 = (kk) - qw0;                                                       \
    const bool farneg = (dk0 <= -191);                                                \
    const bool farpos = (dk0 >= 143);                                                 \
    const bool nearc = !(farneg || farpos);                                           \
    const float cb = farneg ? cbn : cbp;                                              \
    f32x4 st[4];                                                                      \
    if (nearc) {                                                                      \
      _Pragma("unroll") for (int kt = 0; kt < 4; kt++) {                              \
        int i0 = dk0 + (kt >> 1) * 32 + quad * 8 + (kt & 1) * 4 - l15 + 256;          \
        f32x4 v_;                                                                     \
        v_[0] = slab[i0]; v_[1] = slab[i0 + 1];                                       \
        v_[2] = slab[i0 + 2]; v_[3] = slab[i0 + 3];                                   \
        st[kt] = v_;                                                                  \
      }                                                                               \
    } else {                                                                          \
      _Pragma("unroll") for (int kt = 0; kt < 4; kt++)                                \
          st[kt] = (f32x4){0.f, 0.f, 0.f, 0.f};                                       \
    }                                                                                 \
    half8 kf0[4], kf1[4];                                                             \
    _Pragma("unroll") for (int kt = 0; kt < 4; kt++) {                                \
      kf0[kt] = *(const half8*)(&Ks[c][rd0 + kt * 1024]);                             \
      kf1[kt] = *(const half8*)(&Ks[c][rd1 + kt * 1024]);                             \
    }                                                                                 \
    __builtin_amdgcn_s_setprio(1);                                                    \
    _Pragma("unroll") for (int kt = 0; kt < 4; kt++) {                                \
      st[kt] = __builtin_amdgcn_mfma_f32_16x16x32_f16(kf0[kt], qf[0], st[kt], 0, 0, 0); \
      st[kt] = __builtin_amdgcn_mfma_f32_16x16x32_f16(kf1[kt], qf[1], st[kt], 0, 0, 0); \
    }                                                                                 \
    __builtin_amdgcn_s_setprio(0);                                                    \
    /* max tree (max3-fusable) */                                                     \
    float x0 = fmaxf(fmaxf(st[0][0], st[0][1]), st[0][2]);                            \
    float x1 = fmaxf(fmaxf(st[0][3], st[1][0]), st[1][1]);                            \
    float x2 = fmaxf(fmaxf(st[1][2], st[1][3]), st[2][0]);                            \
    float x3 = fmaxf(fmaxf(st[2][1], st[2][2]), st[2][3]);                            \
    float x4 = fmaxf(fmaxf(st[3][0], st[3][1]), st[3][2]);                            \
    float cm = fmaxf(fmaxf(fmaxf(x0, x1), fmaxf(x2, x3)), fmaxf(x4, st[3][3]));       \
    cm = fmaxf(cm, __shfl_xor(cm, 16));                                               \
    cm = fmaxf(cm, __shfl_xor(cm, 32));                                               \
    float mc = nearc ? cm : cm + cb;                                                  \
    if (__any(mc > m_ + 8.f)) {  /* T13: rescale only when max grew by >8 (log2) */   \
      float mnew = fmaxf(m_, mc);                                                     \
      float alpha = __builtin_amdgcn_exp2f(m_ - mnew);                                \
      m_ = mnew;                                                                      \
      lac *= alpha;                                                                   \
      _Pragma("unroll") for (int dt = 0; dt < 4; dt++) o[dt] *= alpha;                \
    }                                                                                 \
    float msub = nearc ? m_ : m_ - cb;                                                \
    half4v p16[4];                                                                    \
    _Pragma("unroll") for (int kt = 0; kt < 4; kt++) {                                \
      f32x4 p_;                                                                       \
      _Pragma("unroll") for (int r = 0; r < 4; r++)                                   \
          p_[r] = __builtin_amdgcn_exp2f(st[kt][r] - msub);                           \
      p16[kt] = pack4(p_);                                                            \
    }                                                                                 \
    __builtin_amdgcn_s_setprio(1);                                                    \
    /* l-sum via MFMA: A=ones -> every acc reg += full 16-key sum of P (per q=l15) */ \
    _Pragma("unroll") for (int kt = 0; kt < 4; kt++)                                  \
        lac = __builtin_amdgcn_mfma_f32_16x16x16f16(ones, p16[kt], lac, 0, 0, 0);     \
    _Pragma("unroll") for (int dt = 0; dt < 4; dt++) {                                \
      half8 va_ = *(const half8*)(&Vs[c][rd0 + dt * 1024]);                           \
      half8 vb_ = *(const half8*)(&Vs[c][rd1 + dt * 1024]);                           \
      half4v alo = {va_[0], va_[1], va_[2], va_[3]};                                  \
      half4v ahi = {va_[4], va_[5], va_[6], va_[7]};                                  \
      half4v blo = {vb_[0], vb_[1], vb_[2], vb_[3]};                                  \
      half4v bhi = {vb_[4], vb_[5], vb_[6], vb_[7]};                                  \
      o[dt] = __builtin_amdgcn_mfma_f32_16x16x16f16(alo, p16[0], o[dt], 0, 0, 0);     \
      o[dt] = __builtin_amdgcn_mfma_f32_16x16x16f16(ahi, p16[1], o[dt], 0, 0, 0);     \
      o[dt] = __builtin_amdgcn_mfma_f32_16x16x16f16(blo, p16[2], o[dt], 0, 0, 0);     \
      o[dt] = __builtin_amdgcn_mfma_f32_16x16x16f16(bhi, p16[3], o[dt], 0, 0, 0);     \
    }                                                                                 \
    __builtin_amdgcn_s_setprio(0);                                                    \
    __syncthreads();   /* drains prefetch GLL + all LDS reads; swap safe */           \
  } while (0)

  for (int k0 = 0; k0 < S_LEN; k0 += 128) {
    TILE(0, k0, 1);                              // stage for k0+64 (always valid)
    TILE(1, k0 + 64, (k0 + 128 < S_LEN));        // stage for k0+128 (skip on last)
  }
#undef TILE
#undef STAGE

  // finalize: lac already holds full l in every reg/lane (ones-MFMA sums all quads)
  float inv = 1.0f / lac[0];
  int q = qw0 + l15;
#pragma unroll
  for (int dt = 0; dt < 4; dt++) {
    f32x4 ov = o[dt] * inv;
    *(half4v*)(attn_out + ((size_t)(b * S_LEN + q)) * DM + h * DK + dt * 16 + quad * 4) =
        pack4(ov);
  }
}

// ---------------- launch ----------------
extern "C" void kernel_launch(void* const* d_in, const int* in_sizes, int n_in,
                              void* d_out, int out_size, void* d_ws, size_t ws_size,
                              hipStream_t stream) {
  const float* hs  = (const float*)d_in[0];
  const float* Wq  = (const float*)d_in[1];
  const float* Wk  = (const float*)d_in[2];
  const float* Wv  = (const float*)d_in[3];
  const float* Wo  = (const float*)d_in[4];
  const float* tbl = (const float*)d_in[5];
  float* out = (float*)d_out;
  char* ws = (char*)d_ws;

  _Float16* Xh    = (_Float16*)(ws);                    // 8 MB
  _Float16* Wqkvt = (_Float16*)(ws + (8u << 20));       // 6 MB (Wq|Wk|Wv transposed)
  _Float16* Wot   = (_Float16*)(ws + (14u << 20));      // 2 MB
  _Float16* Qd    = (_Float16*)(ws + (16u << 20));      // Q | K | V^T, 8 MB each
  _Float16* Kd    = Qd + (size_t)QKV_SZ;
  _Float16* Vd    = Qd + (size_t)2 * QKV_SZ;
  _Float16* Ah    = (_Float16*)(ws + (40u << 20));      // 8 MB attention out (b,s,h*d)
  float*    btab  = (float*)(ws + (48u << 20));         // 16*4095 f32

  conv_f32_f16<<<4096, 256, 0, stream>>>(hs, Xh, (NB * S_LEN * DM) / 4);
  transpose_conv4<<<dim3(32, 32, 4), dim3(32, 8), 0, stream>>>(Wq, Wk, Wv, Wo, Wqkvt, Wot);
  bias_tab_kernel<<<256, 256, 0, stream>>>(tbl, btab);

  gemm_f16<0><<<dim3(24, 32), 256, 0, stream>>>(Xh, Wqkvt, (void*)Qd, NB * S_LEN, 3 * DM, DM);
  attn_kernel<<<dim3(S_LEN / 64, NH, NB), 256, 0, stream>>>(Qd, Kd, Vd, btab, Ah);
  gemm_f16_n64<<<dim3(16, 32), 256, 0, stream>>>(Ah, Wot, out, NB * S_LEN, DM, DM);
}

// Round 8
// 208.323 us; speedup vs baseline: 1.0836x; 1.0098x over previous
//
#include <hip/hip_runtime.h>
#include <hip/hip_fp16.h>

#define S_LEN 2048
#define NH 16
#define DK 64
#define DM 1024
#define NB 2
#define QKV_SZ (NB * NH * S_LEN * DK)  // 4194304 halfs per tensor

typedef _Float16 half8 __attribute__((ext_vector_type(8)));
typedef _Float16 half4v __attribute__((ext_vector_type(4)));
typedef __fp16 fp16x2 __attribute__((ext_vector_type(2)));
typedef float f32x4 __attribute__((ext_vector_type(4)));

// pack 4 f32 -> 4 f16 (rtz) as one 64-bit value
static __device__ __forceinline__ half4v pack4(const f32x4 v) {
  fp16x2 lo = __builtin_amdgcn_cvt_pkrtz(v[0], v[1]);
  fp16x2 hi = __builtin_amdgcn_cvt_pkrtz(v[2], v[3]);
  half4v r;
  ((fp16x2*)&r)[0] = lo;
  ((fp16x2*)&r)[1] = hi;
  return r;
}

#define GLL(gp, lp)                                                              \
  __builtin_amdgcn_global_load_lds(                                              \
      (const __attribute__((address_space(1))) unsigned int*)(gp),               \
      (__attribute__((address_space(3))) unsigned int*)(lp), 16, 0, 0)

// ---------------- conversion kernels ----------------

__global__ __launch_bounds__(256) void conv_f32_f16(const float* __restrict__ in,
                                                    _Float16* __restrict__ out, int n4) {
  int i = blockIdx.x * 256 + threadIdx.x;
  if (i >= n4) return;
  float4 v = ((const float4*)in)[i];
  half4v o;
  o[0] = (_Float16)v.x; o[1] = (_Float16)v.y; o[2] = (_Float16)v.z; o[3] = (_Float16)v.w;
  ((half4v*)out)[i] = o;
}

// All 4 weight transposes in one launch; z selects matrix.
// Wt[n][k] = (f16)(scale * W[k][n]), 1024x1024 each.
__global__ __launch_bounds__(256) void transpose_conv4(
    const float* __restrict__ Wq, const float* __restrict__ Wk,
    const float* __restrict__ Wv, const float* __restrict__ Wo,
    _Float16* __restrict__ Wqkvt, _Float16* __restrict__ Wot) {
  __shared__ float tile[32][33];
  int z = blockIdx.z;
  const float* W = (z == 0) ? Wq : (z == 1) ? Wk : (z == 2) ? Wv : Wo;
  _Float16* Wt = (z < 3) ? (Wqkvt + (size_t)z * 1048576) : Wot;
  float scale = (z == 0) ? 1.44269504f : 1.0f;  // fold log2(e) into Q path
  int tx = threadIdx.x, ty = threadIdx.y;
  int nx = blockIdx.x * 32 + tx;
  int ky = blockIdx.y * 32;
#pragma unroll
  for (int i = 0; i < 32; i += 8) tile[ty + i][tx] = W[(size_t)(ky + ty + i) * DM + nx];
  __syncthreads();
  int kx = ky + tx;
  int ny = blockIdx.x * 32;
#pragma unroll
  for (int i = 0; i < 32; i += 8)
    Wt[(size_t)(ny + ty + i) * DM + kx] = (_Float16)(tile[tx][ty + i] * scale);
}

// tab[h][r] = log2(e) * table[bucket(r-2047)][h], r in [0,4095)
__global__ __launch_bounds__(256) void bias_tab_kernel(const float* __restrict__ table,
                                                       float* __restrict__ tab) {
  int i = blockIdx.x * 256 + threadIdx.x;
  if (i >= NH * 4095) return;
  int h = i / 4095, r = i - h * 4095;
  int rel = r - 2047;              // rel = k - q
  int bucket = rel > 0 ? 16 : 0;
  int a = rel < 0 ? -rel : rel;
  if (a < 8) {
    bucket += a;
  } else {
    int lg = 31 - __clz(a * a);    // floor(2*log2(a))
    int large = 8 + (lg - 6);
    bucket += (large < 15 ? large : 15);
  }
  tab[i] = table[bucket * NH + h] * 1.44269504f;
}

// ---------------- fp16 MFMA GEMM: C = A(MxK) @ Bt(NxK)^T ----------------
// MODE 0: scatter f16 into Q[b,h,s,d] | K[b,h,s,d] | V^T[b,h,d,s]; MODE 1: f32 row-major.
// T1 XCD swizzle: contiguous work chunk per XCD (nwg%8==0 -> bijective, m204).
template <int MODE>
__global__ __launch_bounds__(256) void gemm_f16(const _Float16* __restrict__ A,
                                                const _Float16* __restrict__ Bt,
                                                void* __restrict__ Cout,
                                                int M, int N, int K) {
  __shared__ _Float16 As[128 * 32];  // swizzled (no pad; global_load_lds)
  __shared__ _Float16 Bs[128 * 32];
  const int t = threadIdx.x;
  const int gx = gridDim.x;
  const int nwg = gx * gridDim.y;
  const int orig = blockIdx.x + gx * blockIdx.y;
  const int wg = (orig & 7) * (nwg >> 3) + (orig >> 3);
  const int m0 = (wg / gx) * 128, n0 = (wg % gx) * 128;
  const int w = t >> 6, lane = t & 63, l15 = lane & 15, quad = lane >> 4;
  const int wr = (w >> 1) * 64, wc = (w & 1) * 64;
  const int swz = (quad ^ (l15 & 3)) * 8;

  f32x4 acc[4][4];
#pragma unroll
  for (int i = 0; i < 4; i++)
#pragma unroll
    for (int j = 0; j < 4; j++) acc[i][j] = (f32x4){0.f, 0.f, 0.f, 0.f};

  for (int k0 = 0; k0 < K; k0 += 32) {
    __syncthreads();
#pragma unroll
    for (int i = 0; i < 2; i++) {
      int id = t + 256 * i;
      int row = id >> 2, c = id & 3;
      int cg = c ^ (row & 3);
      GLL(A + (size_t)(m0 + row) * K + k0 + cg * 8, (char*)As + id * 16);
      GLL(Bt + (size_t)(n0 + row) * K + k0 + cg * 8, (char*)Bs + id * 16);
    }
    __syncthreads();
    half8 af[4], bf[4];
#pragma unroll
    for (int i = 0; i < 4; i++) af[i] = *(const half8*)(As + (wr + i * 16 + l15) * 32 + swz);
#pragma unroll
    for (int i = 0; i < 4; i++) bf[i] = *(const half8*)(Bs + (wc + i * 16 + l15) * 32 + swz);
#pragma unroll
    for (int i = 0; i < 4; i++)
#pragma unroll
      for (int j = 0; j < 4; j++)
        acc[i][j] = __builtin_amdgcn_mfma_f32_16x16x32_f16(af[i], bf[j], acc[i][j], 0, 0, 0);
  }

#pragma unroll
  for (int i = 0; i < 4; i++)
#pragma unroll
    for (int j = 0; j < 4; j++) {
      int row0 = m0 + wr + i * 16 + quad * 4;   // C/D: row=(lane>>4)*4+reg
      int col = n0 + wc + j * 16 + l15;         //      col=lane&15
      if (MODE == 1) {
#pragma unroll
        for (int r = 0; r < 4; r++)
          ((float*)Cout)[(size_t)(row0 + r) * N + col] = acc[i][j][r];
      } else {
        int which = col >> 10, rem = col & 1023, hh = rem >> 6, dd = rem & 63;
        int bb = row0 >> 11, ss = row0 & 2047;
        _Float16* base = (_Float16*)Cout;
        if (which == 2) {  // V: transposed store [b,h,d,s], 4 consecutive s -> b64
          *(half4v*)(base + (size_t)2 * QKV_SZ +
                     ((size_t)((bb * NH + hh) * DK + dd)) * S_LEN + ss) = pack4(acc[i][j]);
        } else {
#pragma unroll
          for (int r = 0; r < 4; r++)
            base[(size_t)which * QKV_SZ +
                 ((size_t)((bb * NH + hh) * S_LEN) + ss + r) * DK + dd] = (_Float16)acc[i][j][r];
        }
      }
    }
}

// ---------------- 128x64-tile fp16 GEMM (f32 out) for the N=1024 output proj ----
// BN=64 -> 512 blocks = 2 blocks/CU (128x128 was 1/CU: occupancy-starved).
// T1 XCD swizzle: contiguous chunk per XCD (512%8==0).
__global__ __launch_bounds__(256) void gemm_f16_n64(const _Float16* __restrict__ A,
                                                    const _Float16* __restrict__ Bt,
                                                    float* __restrict__ C,
                                                    int M, int N, int K) {
  __shared__ _Float16 As[128 * 32];
  __shared__ _Float16 Bs[64 * 32];
  const int t = threadIdx.x;
  const int gx = gridDim.x;
  const int nwg = gx * gridDim.y;
  const int orig = blockIdx.x + gx * blockIdx.y;
  const int wg = (orig & 7) * (nwg >> 3) + (orig >> 3);
  const int m0 = (wg / gx) * 128, n0 = (wg % gx) * 64;
  const int w = t >> 6, lane = t & 63, l15 = lane & 15, quad = lane >> 4;
  const int wr = (w >> 1) * 64, wc = (w & 1) * 32;   // 2x2 waves, each 64x32
  const int swz = (quad ^ (l15 & 3)) * 8;

  f32x4 acc[4][2];
#pragma unroll
  for (int i = 0; i < 4; i++)
#pragma unroll
    for (int j = 0; j < 2; j++) acc[i][j] = (f32x4){0.f, 0.f, 0.f, 0.f};

  for (int k0 = 0; k0 < K; k0 += 32) {
    __syncthreads();
#pragma unroll
    for (int i = 0; i < 2; i++) {
      int id = t + 256 * i;
      int row = id >> 2, c = id & 3;
      int cg = c ^ (row & 3);
      GLL(A + (size_t)(m0 + row) * K + k0 + cg * 8, (char*)As + id * 16);
    }
    {
      int row = t >> 2, c = t & 3;
      int cg = c ^ (row & 3);
      GLL(Bt + (size_t)(n0 + row) * K + k0 + cg * 8, (char*)Bs + t * 16);
    }
    __syncthreads();
    half8 af[4], bf[2];
#pragma unroll
    for (int i = 0; i < 4; i++) af[i] = *(const half8*)(As + (wr + i * 16 + l15) * 32 + swz);
#pragma unroll
    for (int j = 0; j < 2; j++) bf[j] = *(const half8*)(Bs + (wc + j * 16 + l15) * 32 + swz);
#pragma unroll
    for (int i = 0; i < 4; i++)
#pragma unroll
      for (int j = 0; j < 2; j++)
        acc[i][j] = __builtin_amdgcn_mfma_f32_16x16x32_f16(af[i], bf[j], acc[i][j], 0, 0, 0);
  }

#pragma unroll
  for (int i = 0; i < 4; i++)
#pragma unroll
    for (int j = 0; j < 2; j++) {
      int row0 = m0 + wr + i * 16 + quad * 4;   // C/D: row=(lane>>4)*4+reg
      int col = n0 + wc + j * 16 + l15;         //      col=lane&15
#pragma unroll
      for (int r = 0; r < 4; r++)
        C[(size_t)(row0 + r) * N + col] = acc[i][j][r];
    }
}

// ---------------- flash attention (S^T formulation, high-TLP) ----------------
// grid (S/64, H, B) = 1024 blocks (4/CU), block 256 = 4 waves; wave w owns q in [Q0+16w, +16).
// Safe 2-phase staging (R4); sigma key-permutation (R5, conflict-free b128 LDS);
// R6 VALU diet; R7 T13 defer-max.
// R8: T1 XCD swizzle — each XCD owns 4 contiguous (b,h) groups so its K/V panels
// (512KB each) stay L2-resident instead of being refetched by all 8 XCDs
// (FETCH_SIZE was 69.8MB vs ~24MB ideal).
__global__ __launch_bounds__(256, 4) void attn_kernel(
    const _Float16* __restrict__ Q, const _Float16* __restrict__ K,
    const _Float16* __restrict__ Vt, const float* __restrict__ btab,
    _Float16* __restrict__ attn_out) {
  __shared__ _Float16 Ks[2][4096];   // [buf][pos][d] 64x64, 16B-XOR swizzled, sigma-permuted keys
  __shared__ _Float16 Vs[2][4096];   // [buf][d][key] 64x64, 16B-XOR swizzled, natural keys
  __shared__ float slab[512];        // bias for rel in [-256,256), log2e-scaled

  const int t = threadIdx.x;
  // T1: orig = x + 32*h + 512*b (x fastest); chunked remap, nwg=1024, q=128
  const int orig = blockIdx.x + (blockIdx.y << 5) + (blockIdx.z << 9);
  const int wg = (orig & 7) * 128 + (orig >> 3);
  const int Q0 = (wg & 31) * 64;
  const int h = (wg >> 5) & 15, b = wg >> 9;
  const int w = t >> 6, lane = t & 63, l15 = lane & 15, quad = lane >> 4;
  const int qw0 = Q0 + w * 16;
  const int sw7 = l15 & 7;

  const _Float16* Qb = Q + (size_t)(b * NH + h) * S_LEN * DK;
  const _Float16* Kb = K + (size_t)(b * NH + h) * S_LEN * DK;
  const _Float16* Vb = Vt + (size_t)(b * NH + h) * S_LEN * DK;  // [d][s]

  // slab[i] = bias(rel = i-256): global r = rel+2047 -> btab offset 1791+i
  for (int i = t; i < 512; i += 256) slab[i] = btab[h * 4095 + 1791 + i];
  const float cbn = btab[h * 4095 + 1791 + 128];  // bias(rel<=-128), uniform per h
  const float cbp = btab[h * 4095 + 1791 + 384];  // bias(rel>=+128)

  // ---- loop-invariant staging offsets (per-thread) ----
  const int id0 = t, id1 = t + 256;
  const int r0_ = id0 >> 3, cg0 = (id0 & 7) ^ (r0_ & 7), p0 = r0_ & 31;
  const int sr0 = (r0_ & 32) | (((p0 >> 2) & 3) << 3) | ((p0 >> 4) << 2) | (p0 & 3);
  const int r1_ = id1 >> 3, cg1 = (id1 & 7) ^ (r1_ & 7), p1 = r1_ & 31;
  const int sr1 = (r1_ & 32) | (((p1 >> 2) & 3) << 3) | ((p1 >> 4) << 2) | (p1 & 3);
  const int kofa = sr0 * DK + cg0 * 8, kofb = sr1 * DK + cg1 * 8;
  const int vofa = r0_ * S_LEN + cg0 * 8, vofb = r1_ * S_LEN + cg1 * 8;
  const int lda = id0 * 16, ldb = id1 * 16;  // LDS byte offsets (linear, GLL order)

#define STAGE(bs, kk0)                                   \
  do {                                                   \
    const _Float16* kp_ = Kb + (size_t)(kk0) * DK;       \
    const _Float16* vp_ = Vb + (kk0);                    \
    GLL(kp_ + kofa, (char*)Ks[bs] + lda);                \
    GLL(kp_ + kofb, (char*)Ks[bs] + ldb);                \
    GLL(vp_ + vofa, (char*)Vs[bs] + lda);                \
    GLL(vp_ + vofb, (char*)Vs[bs] + ldb);                \
  } while (0)

  // Q B-fragments (B[k=d][n=q]): lane(n=l15,quad) holds d = dh*32+quad*8+j
  half8 qf[2];
#pragma unroll
  for (int dh = 0; dh < 2; dh++)
    qf[dh] = *(const half8*)(Qb + (size_t)(qw0 + l15) * DK + dh * 32 + quad * 8);

  f32x4 o[4];
#pragma unroll
  for (int dt = 0; dt < 4; dt++) o[dt] = (f32x4){0.f, 0.f, 0.f, 0.f};
  f32x4 lac = (f32x4){0.f, 0.f, 0.f, 0.f};   // l-sum accumulator (MFMA ones-trick)
  float m_ = -INFINITY;
  const half4v ones = {(_Float16)1.f, (_Float16)1.f, (_Float16)1.f, (_Float16)1.f};

  // loop-invariant LDS read offsets (half-index): rd1 = rd0 ^ 32 (the dh/s=1 XOR lane)
  const int rd0 = l15 * 64 + (quad ^ sw7) * 8;
  const int rd1 = rd0 ^ 32;

  STAGE(0, 0);
  __syncthreads();   // drains tile0 GLL + slab; all waves see buf 0

  // ---- one 64-key tile; c is a literal so all ds_reads are base+immediate ----
#define TILE(c, kk, stage_ok)                                                         \
  do {                                                                                \
    if (stage_ok) STAGE((c) ^ 1, (kk) + 64);  /* prefetch: in flight under compute */ \
    const int dk0 = (kk) - qw0;                                                       \
    const bool farneg = (dk0 <= -191);                                                \
    const bool farpos = (dk0 >= 143);                                                 \
    const bool nearc = !(farneg || farpos);                                           \
    const float cb = farneg ? cbn : cbp;                                              \
    f32x4 st[4];                                                                      \
    if (nearc) {                                                                      \
      _Pragma("unroll") for (int kt = 0; kt < 4; kt++) {                              \
        int i0 = dk0 + (kt >> 1) * 32 + quad * 8 + (kt & 1) * 4 - l15 + 256;          \
        f32x4 v_;                                                                     \
        v_[0] = slab[i0]; v_[1] = slab[i0 + 1];                                       \
        v_[2] = slab[i0 + 2]; v_[3] = slab[i0 + 3];                                   \
        st[kt] = v_;                                                                  \
      }                                                                               \
    } else {                                                                          \
      _Pragma("unroll") for (int kt = 0; kt < 4; kt++)                                \
          st[kt] = (f32x4){0.f, 0.f, 0.f, 0.f};                                       \
    }                                                                                 \
    half8 kf0[4], kf1[4];                                                             \
    _Pragma("unroll") for (int kt = 0; kt < 4; kt++) {                                \
      kf0[kt] = *(const half8*)(&Ks[c][rd0 + kt * 1024]);                             \
      kf1[kt] = *(const half8*)(&Ks[c][rd1 + kt * 1024]);                             \
    }                                                                                 \
    __builtin_amdgcn_s_setprio(1);                                                    \
    _Pragma("unroll") for (int kt = 0; kt < 4; kt++) {                                \
      st[kt] = __builtin_amdgcn_mfma_f32_16x16x32_f16(kf0[kt], qf[0], st[kt], 0, 0, 0); \
      st[kt] = __builtin_amdgcn_mfma_f32_16x16x32_f16(kf1[kt], qf[1], st[kt], 0, 0, 0); \
    }                                                                                 \
    __builtin_amdgcn_s_setprio(0);                                                    \
    /* max tree (max3-fusable) */                                                     \
    float x0 = fmaxf(fmaxf(st[0][0], st[0][1]), st[0][2]);                            \
    float x1 = fmaxf(fmaxf(st[0][3], st[1][0]), st[1][1]);                            \
    float x2 = fmaxf(fmaxf(st[1][2], st[1][3]), st[2][0]);                            \
    float x3 = fmaxf(fmaxf(st[2][1], st[2][2]), st[2][3]);                            \
    float x4 = fmaxf(fmaxf(st[3][0], st[3][1]), st[3][2]);                            \
    float cm = fmaxf(fmaxf(fmaxf(x0, x1), fmaxf(x2, x3)), fmaxf(x4, st[3][3]));       \
    cm = fmaxf(cm, __shfl_xor(cm, 16));                                               \
    cm = fmaxf(cm, __shfl_xor(cm, 32));                                               \
    float mc = nearc ? cm : cm + cb;                                                  \
    if (__any(mc > m_ + 8.f)) {  /* T13: rescale only when max grew by >8 (log2) */   \
      float mnew = fmaxf(m_, mc);                                                     \
      float alpha = __builtin_amdgcn_exp2f(m_ - mnew);                                \
      m_ = mnew;                                                                      \
      lac *= alpha;                                                                   \
      _Pragma("unroll") for (int dt = 0; dt < 4; dt++) o[dt] *= alpha;                \
    }                                                                                 \
    float msub = nearc ? m_ : m_ - cb;                                                \
    half4v p16[4];                                                                    \
    _Pragma("unroll") for (int kt = 0; kt < 4; kt++) {                                \
      f32x4 p_;                                                                       \
      _Pragma("unroll") for (int r = 0; r < 4; r++)                                   \
          p_[r] = __builtin_amdgcn_exp2f(st[kt][r] - msub);                           \
      p16[kt] = pack4(p_);                                                            \
    }                                                                                 \
    __builtin_amdgcn_s_setprio(1);                                                    \
    /* l-sum via MFMA: A=ones -> every acc reg += full 16-key sum of P (per q=l15) */ \
    _Pragma("unroll") for (int kt = 0; kt < 4; kt++)                                  \
        lac = __builtin_amdgcn_mfma_f32_16x16x16f16(ones, p16[kt], lac, 0, 0, 0);     \
    _Pragma("unroll") for (int dt = 0; dt < 4; dt++) {                                \
      half8 va_ = *(const half8*)(&Vs[c][rd0 + dt * 1024]);                           \
      half8 vb_ = *(const half8*)(&Vs[c][rd1 + dt * 1024]);                           \
      half4v alo = {va_[0], va_[1], va_[2], va_[3]};                                  \
      half4v ahi = {va_[4], va_[5], va_[6], va_[7]};                                  \
      half4v blo = {vb_[0], vb_[1], vb_[2], vb_[3]};                                  \
      half4v bhi = {vb_[4], vb_[5], vb_[6], vb_[7]};                                  \
      o[dt] = __builtin_amdgcn_mfma_f32_16x16x16f16(alo, p16[0], o[dt], 0, 0, 0);     \
      o[dt] = __builtin_amdgcn_mfma_f32_16x16x16f16(ahi, p16[1], o[dt], 0, 0, 0);     \
      o[dt] = __builtin_amdgcn_mfma_f32_16x16x16f16(blo, p16[2], o[dt], 0, 0, 0);     \
      o[dt] = __builtin_amdgcn_mfma_f32_16x16x16f16(bhi, p16[3], o[dt], 0, 0, 0);     \
    }                                                                                 \
    __builtin_amdgcn_s_setprio(0);                                                    \
    __syncthreads();   /* drains prefetch GLL + all LDS reads; swap safe */           \
  } while (0)

  for (int k0 = 0; k0 < S_LEN; k0 += 128) {
    TILE(0, k0, 1);                              // stage for k0+64 (always valid)
    TILE(1, k0 + 64, (k0 + 128 < S_LEN));        // stage for k0+128 (skip on last)
  }
#undef TILE
#undef STAGE

  // finalize: lac already holds full l in every reg/lane (ones-MFMA sums all quads)
  float inv = 1.0f / lac[0];
  int q = qw0 + l15;
#pragma unroll
  for (int dt = 0; dt < 4; dt++) {
    f32x4 ov = o[dt] * inv;
    *(half4v*)(attn_out + ((size_t)(b * S_LEN + q)) * DM + h * DK + dt * 16 + quad * 4) =
        pack4(ov);
  }
}

// ---------------- launch ----------------
extern "C" void kernel_launch(void* const* d_in, const int* in_sizes, int n_in,
                              void* d_out, int out_size, void* d_ws, size_t ws_size,
                              hipStream_t stream) {
  const float* hs  = (const float*)d_in[0];
  const float* Wq  = (const float*)d_in[1];
  const float* Wk  = (const float*)d_in[2];
  const float* Wv  = (const float*)d_in[3];
  const float* Wo  = (const float*)d_in[4];
  const float* tbl = (const float*)d_in[5];
  float* out = (float*)d_out;
  char* ws = (char*)d_ws;

  _Float16* Xh    = (_Float16*)(ws);                    // 8 MB
  _Float16* Wqkvt = (_Float16*)(ws + (8u << 20));       // 6 MB (Wq|Wk|Wv transposed)
  _Float16* Wot   = (_Float16*)(ws + (14u << 20));      // 2 MB
  _Float16* Qd    = (_Float16*)(ws + (16u << 20));      // Q | K | V^T, 8 MB each
  _Float16* Kd    = Qd + (size_t)QKV_SZ;
  _Float16* Vd    = Qd + (size_t)2 * QKV_SZ;
  _Float16* Ah    = (_Float16*)(ws + (40u << 20));      // 8 MB attention out (b,s,h*d)
  float*    btab  = (float*)(ws + (48u << 20));         // 16*4095 f32

  conv_f32_f16<<<4096, 256, 0, stream>>>(hs, Xh, (NB * S_LEN * DM) / 4);
  transpose_conv4<<<dim3(32, 32, 4), dim3(32, 8), 0, stream>>>(Wq, Wk, Wv, Wo, Wqkvt, Wot);
  bias_tab_kernel<<<256, 256, 0, stream>>>(tbl, btab);

  gemm_f16<0><<<dim3(24, 32), 256, 0, stream>>>(Xh, Wqkvt, (void*)Qd, NB * S_LEN, 3 * DM, DM);
  attn_kernel<<<dim3(S_LEN / 64, NH, NB), 256, 0, stream>>>(Qd, Kd, Vd, btab, Ah);
  gemm_f16_n64<<<dim3(16, 32), 256, 0, stream>>>(Ah, Wot, out, NB * S_LEN, DM, DM);
}

// Round 9
// 202.244 us; speedup vs baseline: 1.1161x; 1.0301x over previous
//
#include <hip/hip_runtime.h>
#include <hip/hip_fp16.h>

#define S_LEN 2048
#define NH 16
#define DK 64
#define DM 1024
#define NB 2
#define QKV_SZ (NB * NH * S_LEN * DK)  // 4194304 halfs per tensor

typedef _Float16 half8 __attribute__((ext_vector_type(8)));
typedef _Float16 half4v __attribute__((ext_vector_type(4)));
typedef __fp16 fp16x2 __attribute__((ext_vector_type(2)));
typedef float f32x4 __attribute__((ext_vector_type(4)));

// pack 4 f32 -> 4 f16 (rtz) as one 64-bit value
static __device__ __forceinline__ half4v pack4(const f32x4 v) {
  fp16x2 lo = __builtin_amdgcn_cvt_pkrtz(v[0], v[1]);
  fp16x2 hi = __builtin_amdgcn_cvt_pkrtz(v[2], v[3]);
  half4v r;
  ((fp16x2*)&r)[0] = lo;
  ((fp16x2*)&r)[1] = hi;
  return r;
}

#define GLL(gp, lp)                                                              \
  __builtin_amdgcn_global_load_lds(                                              \
      (const __attribute__((address_space(1))) unsigned int*)(gp),               \
      (__attribute__((address_space(3))) unsigned int*)(lp), 16, 0, 0)

// ---------------- conversion kernels ----------------

__global__ __launch_bounds__(256) void conv_f32_f16(const float* __restrict__ in,
                                                    _Float16* __restrict__ out, int n4) {
  int i = blockIdx.x * 256 + threadIdx.x;
  if (i >= n4) return;
  float4 v = ((const float4*)in)[i];
  half4v o;
  o[0] = (_Float16)v.x; o[1] = (_Float16)v.y; o[2] = (_Float16)v.z; o[3] = (_Float16)v.w;
  ((half4v*)out)[i] = o;
}

// All 4 weight transposes in one launch; z selects matrix.
// Wt[n][k] = (f16)(scale * W[k][n]), 1024x1024 each.
__global__ __launch_bounds__(256) void transpose_conv4(
    const float* __restrict__ Wq, const float* __restrict__ Wk,
    const float* __restrict__ Wv, const float* __restrict__ Wo,
    _Float16* __restrict__ Wqkvt, _Float16* __restrict__ Wot) {
  __shared__ float tile[32][33];
  int z = blockIdx.z;
  const float* W = (z == 0) ? Wq : (z == 1) ? Wk : (z == 2) ? Wv : Wo;
  _Float16* Wt = (z < 3) ? (Wqkvt + (size_t)z * 1048576) : Wot;
  float scale = (z == 0) ? 1.44269504f : 1.0f;  // fold log2(e) into Q path
  int tx = threadIdx.x, ty = threadIdx.y;
  int nx = blockIdx.x * 32 + tx;
  int ky = blockIdx.y * 32;
#pragma unroll
  for (int i = 0; i < 32; i += 8) tile[ty + i][tx] = W[(size_t)(ky + ty + i) * DM + nx];
  __syncthreads();
  int kx = ky + tx;
  int ny = blockIdx.x * 32;
#pragma unroll
  for (int i = 0; i < 32; i += 8)
    Wt[(size_t)(ny + ty + i) * DM + kx] = (_Float16)(tile[tx][ty + i] * scale);
}

// tab[h][r] = log2(e) * table[bucket(r-2047)][h], r in [0,4095)
__global__ __launch_bounds__(256) void bias_tab_kernel(const float* __restrict__ table,
                                                       float* __restrict__ tab) {
  int i = blockIdx.x * 256 + threadIdx.x;
  if (i >= NH * 4095) return;
  int h = i / 4095, r = i - h * 4095;
  int rel = r - 2047;              // rel = k - q
  int bucket = rel > 0 ? 16 : 0;
  int a = rel < 0 ? -rel : rel;
  if (a < 8) {
    bucket += a;
  } else {
    int lg = 31 - __clz(a * a);    // floor(2*log2(a))
    int large = 8 + (lg - 6);
    bucket += (large < 15 ? large : 15);
  }
  tab[i] = table[bucket * NH + h] * 1.44269504f;
}

// ---------------- fp16 MFMA GEMM: C = A(MxK) @ Bt(NxK)^T ----------------
// MODE 0: scatter f16 into Q[b,h,s,d] | K[b,h,s,d] | V^T[b,h,d,s]; MODE 1: f32 row-major.
// T1 XCD swizzle: contiguous work chunk per XCD (nwg%8==0 -> bijective, m204).
// R9: double-buffered LDS + 2-phase prefetch (R4-verified pattern): issue next-tile
// GLL BEFORE compute, ONE __syncthreads per K-step (was 2 + exposed GLL latency).
template <int MODE>
__global__ __launch_bounds__(256) void gemm_f16(const _Float16* __restrict__ A,
                                                const _Float16* __restrict__ Bt,
                                                void* __restrict__ Cout,
                                                int M, int N, int K) {
  __shared__ _Float16 As[2][128 * 32];
  __shared__ _Float16 Bs[2][128 * 32];
  const int t = threadIdx.x;
  const int gx = gridDim.x;
  const int nwg = gx * gridDim.y;
  const int orig = blockIdx.x + gx * blockIdx.y;
  const int wg = (orig & 7) * (nwg >> 3) + (orig >> 3);
  const int m0 = (wg / gx) * 128, n0 = (wg % gx) * 128;
  const int w = t >> 6, lane = t & 63, l15 = lane & 15, quad = lane >> 4;
  const int wr = (w >> 1) * 64, wc = (w & 1) * 64;
  const int swz = (quad ^ (l15 & 3)) * 8;

  // loop-invariant staging offsets
  const int row0_ = t >> 2, cg0 = (t & 3) ^ (row0_ & 3);
  const int row1_ = (t + 256) >> 2, cg1 = ((t + 256) & 3) ^ (row1_ & 3);
  const int aof0 = row0_ * K + cg0 * 8, aof1 = row1_ * K + cg1 * 8;
  const int lda = t * 16, ldb = (t + 256) * 16;

  f32x4 acc[4][4];
#pragma unroll
  for (int i = 0; i < 4; i++)
#pragma unroll
    for (int j = 0; j < 4; j++) acc[i][j] = (f32x4){0.f, 0.f, 0.f, 0.f};

#define GSTAGE(bs, kk)                                                     \
  do {                                                                     \
    const _Float16* ap_ = A + (size_t)m0 * K + (kk);                       \
    const _Float16* bp_ = Bt + (size_t)n0 * K + (kk);                      \
    GLL(ap_ + aof0, (char*)As[bs] + lda);                                  \
    GLL(ap_ + aof1, (char*)As[bs] + ldb);                                  \
    GLL(bp_ + aof0, (char*)Bs[bs] + lda);                                  \
    GLL(bp_ + aof1, (char*)Bs[bs] + ldb);                                  \
  } while (0)

  GSTAGE(0, 0);
  __syncthreads();

#define GTILE(c, kk)                                                          \
  do {                                                                        \
    if ((kk) + 32 < K) GSTAGE((c) ^ 1, (kk) + 32);                            \
    half8 af[4], bf[4];                                                       \
    _Pragma("unroll") for (int i = 0; i < 4; i++)                             \
        af[i] = *(const half8*)(As[c] + (wr + i * 16 + l15) * 32 + swz);      \
    _Pragma("unroll") for (int i = 0; i < 4; i++)                             \
        bf[i] = *(const half8*)(Bs[c] + (wc + i * 16 + l15) * 32 + swz);      \
    _Pragma("unroll") for (int i = 0; i < 4; i++)                             \
        _Pragma("unroll") for (int j = 0; j < 4; j++)                         \
            acc[i][j] =                                                       \
                __builtin_amdgcn_mfma_f32_16x16x32_f16(af[i], bf[j], acc[i][j], 0, 0, 0); \
    __syncthreads();                                                          \
  } while (0)

  for (int k0 = 0; k0 < K; k0 += 64) {
    GTILE(0, k0);
    GTILE(1, k0 + 32);
  }
#undef GTILE
#undef GSTAGE

#pragma unroll
  for (int i = 0; i < 4; i++)
#pragma unroll
    for (int j = 0; j < 4; j++) {
      int row0 = m0 + wr + i * 16 + quad * 4;   // C/D: row=(lane>>4)*4+reg
      int col = n0 + wc + j * 16 + l15;         //      col=lane&15
      if (MODE == 1) {
#pragma unroll
        for (int r = 0; r < 4; r++)
          ((float*)Cout)[(size_t)(row0 + r) * N + col] = acc[i][j][r];
      } else {
        int which = col >> 10, rem = col & 1023, hh = rem >> 6, dd = rem & 63;
        int bb = row0 >> 11, ss = row0 & 2047;
        _Float16* base = (_Float16*)Cout;
        if (which == 2) {  // V: transposed store [b,h,d,s], 4 consecutive s -> b64
          *(half4v*)(base + (size_t)2 * QKV_SZ +
                     ((size_t)((bb * NH + hh) * DK + dd)) * S_LEN + ss) = pack4(acc[i][j]);
        } else {
#pragma unroll
          for (int r = 0; r < 4; r++)
            base[(size_t)which * QKV_SZ +
                 ((size_t)((bb * NH + hh) * S_LEN) + ss + r) * DK + dd] = (_Float16)acc[i][j][r];
        }
      }
    }
}

// ---------------- 128x64-tile fp16 GEMM (f32 out) for the N=1024 output proj ----
// BN=64 -> 512 blocks = 2 blocks/CU. T1 XCD swizzle. R9: same double-buffered
// 2-phase prefetch as gemm_f16 (one barrier per K-step, GLL hidden under MFMA).
__global__ __launch_bounds__(256) void gemm_f16_n64(const _Float16* __restrict__ A,
                                                    const _Float16* __restrict__ Bt,
                                                    float* __restrict__ C,
                                                    int M, int N, int K) {
  __shared__ _Float16 As[2][128 * 32];
  __shared__ _Float16 Bs[2][64 * 32];
  const int t = threadIdx.x;
  const int gx = gridDim.x;
  const int nwg = gx * gridDim.y;
  const int orig = blockIdx.x + gx * blockIdx.y;
  const int wg = (orig & 7) * (nwg >> 3) + (orig >> 3);
  const int m0 = (wg / gx) * 128, n0 = (wg % gx) * 64;
  const int w = t >> 6, lane = t & 63, l15 = lane & 15, quad = lane >> 4;
  const int wr = (w >> 1) * 64, wc = (w & 1) * 32;   // 2x2 waves, each 64x32
  const int swz = (quad ^ (l15 & 3)) * 8;

  const int row0_ = t >> 2, cg0 = (t & 3) ^ (row0_ & 3);
  const int row1_ = (t + 256) >> 2, cg1 = ((t + 256) & 3) ^ (row1_ & 3);
  const int aof0 = row0_ * K + cg0 * 8, aof1 = row1_ * K + cg1 * 8;
  const int lda = t * 16, ldb = (t + 256) * 16;

  f32x4 acc[4][2];
#pragma unroll
  for (int i = 0; i < 4; i++)
#pragma unroll
    for (int j = 0; j < 2; j++) acc[i][j] = (f32x4){0.f, 0.f, 0.f, 0.f};

#define GSTAGE(bs, kk)                                                     \
  do {                                                                     \
    const _Float16* ap_ = A + (size_t)m0 * K + (kk);                       \
    const _Float16* bp_ = Bt + (size_t)n0 * K + (kk);                      \
    GLL(ap_ + aof0, (char*)As[bs] + lda);                                  \
    GLL(ap_ + aof1, (char*)As[bs] + ldb);                                  \
    GLL(bp_ + aof0, (char*)Bs[bs] + lda);                                  \
  } while (0)

  GSTAGE(0, 0);
  __syncthreads();

#define GTILE(c, kk)                                                          \
  do {                                                                        \
    if ((kk) + 32 < K) GSTAGE((c) ^ 1, (kk) + 32);                            \
    half8 af[4], bf[2];                                                       \
    _Pragma("unroll") for (int i = 0; i < 4; i++)                             \
        af[i] = *(const half8*)(As[c] + (wr + i * 16 + l15) * 32 + swz);      \
    _Pragma("unroll") for (int j = 0; j < 2; j++)                             \
        bf[j] = *(const half8*)(Bs[c] + (wc + j * 16 + l15) * 32 + swz);      \
    _Pragma("unroll") for (int i = 0; i < 4; i++)                             \
        _Pragma("unroll") for (int j = 0; j < 2; j++)                         \
            acc[i][j] =                                                       \
                __builtin_amdgcn_mfma_f32_16x16x32_f16(af[i], bf[j], acc[i][j], 0, 0, 0); \
    __syncthreads();                                                          \
  } while (0)

  for (int k0 = 0; k0 < K; k0 += 64) {
    GTILE(0, k0);
    GTILE(1, k0 + 32);
  }
#undef GTILE
#undef GSTAGE

#pragma unroll
  for (int i = 0; i < 4; i++)
#pragma unroll
    for (int j = 0; j < 2; j++) {
      int row0 = m0 + wr + i * 16 + quad * 4;   // C/D: row=(lane>>4)*4+reg
      int col = n0 + wc + j * 16 + l15;         //      col=lane&15
#pragma unroll
      for (int r = 0; r < 4; r++)
        C[(size_t)(row0 + r) * N + col] = acc[i][j][r];
    }
}

// ---------------- flash attention (S^T formulation, high-TLP) ----------------
// grid (S/64, H, B) = 1024 blocks (4/CU), block 256 = 4 waves; wave w owns q in [Q0+16w, +16).
// Safe 2-phase staging (R4); sigma key-permutation (R5, conflict-free b128 LDS);
// R6 VALU diet; R7 T13 defer-max; R8 T1 XCD swizzle (FETCH 69.8->12.4MB).
__global__ __launch_bounds__(256, 4) void attn_kernel(
    const _Float16* __restrict__ Q, const _Float16* __restrict__ K,
    const _Float16* __restrict__ Vt, const float* __restrict__ btab,
    _Float16* __restrict__ attn_out) {
  __shared__ _Float16 Ks[2][4096];   // [buf][pos][d] 64x64, 16B-XOR swizzled, sigma-permuted keys
  __shared__ _Float16 Vs[2][4096];   // [buf][d][key] 64x64, 16B-XOR swizzled, natural keys
  __shared__ float slab[512];        // bias for rel in [-256,256), log2e-scaled

  const int t = threadIdx.x;
  // T1: orig = x + 32*h + 512*b (x fastest); chunked remap, nwg=1024, q=128
  const int orig = blockIdx.x + (blockIdx.y << 5) + (blockIdx.z << 9);
  const int wg = (orig & 7) * 128 + (orig >> 3);
  const int Q0 = (wg & 31) * 64;
  const int h = (wg >> 5) & 15, b = wg >> 9;
  const int w = t >> 6, lane = t & 63, l15 = lane & 15, quad = lane >> 4;
  const int qw0 = Q0 + w * 16;
  const int sw7 = l15 & 7;

  const _Float16* Qb = Q + (size_t)(b * NH + h) * S_LEN * DK;
  const _Float16* Kb = K + (size_t)(b * NH + h) * S_LEN * DK;
  const _Float16* Vb = Vt + (size_t)(b * NH + h) * S_LEN * DK;  // [d][s]

  // slab[i] = bias(rel = i-256): global r = rel+2047 -> btab offset 1791+i
  for (int i = t; i < 512; i += 256) slab[i] = btab[h * 4095 + 1791 + i];
  const float cbn = btab[h * 4095 + 1791 + 128];  // bias(rel<=-128), uniform per h
  const float cbp = btab[h * 4095 + 1791 + 384];  // bias(rel>=+128)

  // ---- loop-invariant staging offsets (per-thread) ----
  const int id0 = t, id1 = t + 256;
  const int r0_ = id0 >> 3, cg0 = (id0 & 7) ^ (r0_ & 7), p0 = r0_ & 31;
  const int sr0 = (r0_ & 32) | (((p0 >> 2) & 3) << 3) | ((p0 >> 4) << 2) | (p0 & 3);
  const int r1_ = id1 >> 3, cg1 = (id1 & 7) ^ (r1_ & 7), p1 = r1_ & 31;
  const int sr1 = (r1_ & 32) | (((p1 >> 2) & 3) << 3) | ((p1 >> 4) << 2) | (p1 & 3);
  const int kofa = sr0 * DK + cg0 * 8, kofb = sr1 * DK + cg1 * 8;
  const int vofa = r0_ * S_LEN + cg0 * 8, vofb = r1_ * S_LEN + cg1 * 8;
  const int lda = id0 * 16, ldb = id1 * 16;  // LDS byte offsets (linear, GLL order)

#define STAGE(bs, kk0)                                   \
  do {                                                   \
    const _Float16* kp_ = Kb + (size_t)(kk0) * DK;       \
    const _Float16* vp_ = Vb + (kk0);                    \
    GLL(kp_ + kofa, (char*)Ks[bs] + lda);                \
    GLL(kp_ + kofb, (char*)Ks[bs] + ldb);                \
    GLL(vp_ + vofa, (char*)Vs[bs] + lda);                \
    GLL(vp_ + vofb, (char*)Vs[bs] + ldb);                \
  } while (0)

  // Q B-fragments (B[k=d][n=q]): lane(n=l15,quad) holds d = dh*32+quad*8+j
  half8 qf[2];
#pragma unroll
  for (int dh = 0; dh < 2; dh++)
    qf[dh] = *(const half8*)(Qb + (size_t)(qw0 + l15) * DK + dh * 32 + quad * 8);

  f32x4 o[4];
#pragma unroll
  for (int dt = 0; dt < 4; dt++) o[dt] = (f32x4){0.f, 0.f, 0.f, 0.f};
  f32x4 lac = (f32x4){0.f, 0.f, 0.f, 0.f};   // l-sum accumulator (MFMA ones-trick)
  float m_ = -INFINITY;
  const half4v ones = {(_Float16)1.f, (_Float16)1.f, (_Float16)1.f, (_Float16)1.f};

  // loop-invariant LDS read offsets (half-index): rd1 = rd0 ^ 32 (the dh/s=1 XOR lane)
  const int rd0 = l15 * 64 + (quad ^ sw7) * 8;
  const int rd1 = rd0 ^ 32;

  STAGE(0, 0);
  __syncthreads();   // drains tile0 GLL + slab; all waves see buf 0

  // ---- one 64-key tile; c is a literal so all ds_reads are base+immediate ----
#define TILE(c, kk, stage_ok)                                                         \
  do {                                                                                \
    if (stage_ok) STAGE((c) ^ 1, (kk) + 64);  /* prefetch: in flight under compute */ \
    const int dk0 = (kk) - qw0;                                                       \
    const bool farneg = (dk0 <= -191);                                                \
    const bool farpos = (dk0 >= 143);                                                 \
    const bool nearc = !(farneg || farpos);                                           \
    const float cb = farneg ? cbn : cbp;                                              \
    f32x4 st[4];                                                                      \
    if (nearc) {                                                                      \
      _Pragma("unroll") for (int kt = 0; kt < 4; kt++) {                              \
        int i0 = dk0 + (kt >> 1) * 32 + quad * 8 + (kt & 1) * 4 - l15 + 256;          \
        f32x4 v_;                                                                     \
        v_[0] = slab[i0]; v_[1] = slab[i0 + 1];                                       \
        v_[2] = slab[i0 + 2]; v_[3] = slab[i0 + 3];                                   \
        st[kt] = v_;                                                                  \
      }                                                                               \
    } else {                                                                          \
      _Pragma("unroll") for (int kt = 0; kt < 4; kt++)                                \
          st[kt] = (f32x4){0.f, 0.f, 0.f, 0.f};                                       \
    }                                                                                 \
    half8 kf0[4], kf1[4];                                                             \
    _Pragma("unroll") for (int kt = 0; kt < 4; kt++) {                                \
      kf0[kt] = *(const half8*)(&Ks[c][rd0 + kt * 1024]);                             \
      kf1[kt] = *(const half8*)(&Ks[c][rd1 + kt * 1024]);                             \
    }                                                                                 \
    __builtin_amdgcn_s_setprio(1);                                                    \
    _Pragma("unroll") for (int kt = 0; kt < 4; kt++) {                                \
      st[kt] = __builtin_amdgcn_mfma_f32_16x16x32_f16(kf0[kt], qf[0], st[kt], 0, 0, 0); \
      st[kt] = __builtin_amdgcn_mfma_f32_16x16x32_f16(kf1[kt], qf[1], st[kt], 0, 0, 0); \
    }                                                                                 \
    __builtin_amdgcn_s_setprio(0);                                                    \
    /* max tree (max3-fusable) */                                                     \
    float x0 = fmaxf(fmaxf(st[0][0], st[0][1]), st[0][2]);                            \
    float x1 = fmaxf(fmaxf(st[0][3], st[1][0]), st[1][1]);                            \
    float x2 = fmaxf(fmaxf(st[1][2], st[1][3]), st[2][0]);                            \
    float x3 = fmaxf(fmaxf(st[2][1], st[2][2]), st[2][3]);                            \
    float x4 = fmaxf(fmaxf(st[3][0], st[3][1]), st[3][2]);                            \
    float cm = fmaxf(fmaxf(fmaxf(x0, x1), fmaxf(x2, x3)), fmaxf(x4, st[3][3]));       \
    cm = fmaxf(cm, __shfl_xor(cm, 16));                                               \
    cm = fmaxf(cm, __shfl_xor(cm, 32));                                               \
    float mc = nearc ? cm : cm + cb;                                                  \
    if (__any(mc > m_ + 8.f)) {  /* T13: rescale only when max grew by >8 (log2) */   \
      float mnew = fmaxf(m_, mc);                                                     \
      float alpha = __builtin_amdgcn_exp2f(m_ - mnew);                                \
      m_ = mnew;                                                                      \
      lac *= alpha;                                                                   \
      _Pragma("unroll") for (int dt = 0; dt < 4; dt++) o[dt] *= alpha;                \
    }                                                                                 \
    float msub = nearc ? m_ : m_ - cb;                                                \
    half4v p16[4];                                                                    \
    _Pragma("unroll") for (int kt = 0; kt < 4; kt++) {                                \
      f32x4 p_;                                                                       \
      _Pragma("unroll") for (int r = 0; r < 4; r++)                                   \
          p_[r] = __builtin_amdgcn_exp2f(st[kt][r] - msub);                           \
      p16[kt] = pack4(p_);                                                            \
    }                                                                                 \
    __builtin_amdgcn_s_setprio(1);                                                    \
    /* l-sum via MFMA: A=ones -> every acc reg += full 16-key sum of P (per q=l15) */ \
    _Pragma("unroll") for (int kt = 0; kt < 4; kt++)                                  \
        lac = __builtin_amdgcn_mfma_f32_16x16x16f16(ones, p16[kt], lac, 0, 0, 0);     \
    _Pragma("unroll") for (int dt = 0; dt < 4; dt++) {                                \
      half8 va_ = *(const half8*)(&Vs[c][rd0 + dt * 1024]);                           \
      half8 vb_ = *(const half8*)(&Vs[c][rd1 + dt * 1024]);                           \
      half4v alo = {va_[0], va_[1], va_[2], va_[3]};                                  \
      half4v ahi = {va_[4], va_[5], va_[6], va_[7]};                                  \
      half4v blo = {vb_[0], vb_[1], vb_[2], vb_[3]};                                  \
      half4v bhi = {vb_[4], vb_[5], vb_[6], vb_[7]};                                  \
      o[dt] = __builtin_amdgcn_mfma_f32_16x16x16f16(alo, p16[0], o[dt], 0, 0, 0);     \
      o[dt] = __builtin_amdgcn_mfma_f32_16x16x16f16(ahi, p16[1], o[dt], 0, 0, 0);     \
      o[dt] = __builtin_amdgcn_mfma_f32_16x16x16f16(blo, p16[2], o[dt], 0, 0, 0);     \
      o[dt] = __builtin_amdgcn_mfma_f32_16x16x16f16(bhi, p16[3], o[dt], 0, 0, 0);     \
    }                                                                                 \
    __builtin_amdgcn_s_setprio(0);                                                    \
    __syncthreads();   /* drains prefetch GLL + all LDS reads; swap safe */           \
  } while (0)

  for (int k0 = 0; k0 < S_LEN; k0 += 128) {
    TILE(0, k0, 1);                              // stage for k0+64 (always valid)
    TILE(1, k0 + 64, (k0 + 128 < S_LEN));        // stage for k0+128 (skip on last)
  }
#undef TILE
#undef STAGE

  // finalize: lac already holds full l in every reg/lane (ones-MFMA sums all quads)
  float inv = 1.0f / lac[0];
  int q = qw0 + l15;
#pragma unroll
  for (int dt = 0; dt < 4; dt++) {
    f32x4 ov = o[dt] * inv;
    *(half4v*)(attn_out + ((size_t)(b * S_LEN + q)) * DM + h * DK + dt * 16 + quad * 4) =
        pack4(ov);
  }
}

// ---------------- launch ----------------
extern "C" void kernel_launch(void* const* d_in, const int* in_sizes, int n_in,
                              void* d_out, int out_size, void* d_ws, size_t ws_size,
                              hipStream_t stream) {
  const float* hs  = (const float*)d_in[0];
  const float* Wq  = (const float*)d_in[1];
  const float* Wk  = (const float*)d_in[2];
  const float* Wv  = (const float*)d_in[3];
  const float* Wo  = (const float*)d_in[4];
  const float* tbl = (const float*)d_in[5];
  float* out = (float*)d_out;
  char* ws = (char*)d_ws;

  _Float16* Xh    = (_Float16*)(ws);                    // 8 MB
  _Float16* Wqkvt = (_Float16*)(ws + (8u << 20));       // 6 MB (Wq|Wk|Wv transposed)
  _Float16* Wot   = (_Float16*)(ws + (14u << 20));      // 2 MB
  _Float16* Qd    = (_Float16*)(ws + (16u << 20));      // Q | K | V^T, 8 MB each
  _Float16* Kd    = Qd + (size_t)QKV_SZ;
  _Float16* Vd    = Qd + (size_t)2 * QKV_SZ;
  _Float16* Ah    = (_Float16*)(ws + (40u << 20));      // 8 MB attention out (b,s,h*d)
  float*    btab  = (float*)(ws + (48u << 20));         // 16*4095 f32

  conv_f32_f16<<<4096, 256, 0, stream>>>(hs, Xh, (NB * S_LEN * DM) / 4);
  transpose_conv4<<<dim3(32, 32, 4), dim3(32, 8), 0, stream>>>(Wq, Wk, Wv, Wo, Wqkvt, Wot);
  bias_tab_kernel<<<256, 256, 0, stream>>>(tbl, btab);

  gemm_f16<0><<<dim3(24, 32), 256, 0, stream>>>(Xh, Wqkvt, (void*)Qd, NB * S_LEN, 3 * DM, DM);
  attn_kernel<<<dim3(S_LEN / 64, NH, NB), 256, 0, stream>>>(Qd, Kd, Vd, btab, Ah);
  gemm_f16_n64<<<dim3(16, 32), 256, 0, stream>>>(Ah, Wot, out, NB * S_LEN, DM, DM);
}

// Round 11
// 195.261 us; speedup vs baseline: 1.1561x; 1.0358x over previous
//
#include <hip/hip_runtime.h>
#include <hip/hip_fp16.h>

#define S_LEN 2048
#define NH 16
#define DK 64
#define DM 1024
#define NB 2
#define QKV_SZ (NB * NH * S_LEN * DK)  // 4194304 halfs per tensor

typedef _Float16 half8 __attribute__((ext_vector_type(8)));
typedef _Float16 half4v __attribute__((ext_vector_type(4)));
typedef __fp16 fp16x2 __attribute__((ext_vector_type(2)));
typedef float f32x4 __attribute__((ext_vector_type(4)));

// pack 4 f32 -> 4 f16 (rtz) as one 64-bit value
static __device__ __forceinline__ half4v pack4(const f32x4 v) {
  fp16x2 lo = __builtin_amdgcn_cvt_pkrtz(v[0], v[1]);
  fp16x2 hi = __builtin_amdgcn_cvt_pkrtz(v[2], v[3]);
  half4v r;
  ((fp16x2*)&r)[0] = lo;
  ((fp16x2*)&r)[1] = hi;
  return r;
}

#define GLL(gp, lp)                                                              \
  __builtin_amdgcn_global_load_lds(                                              \
      (const __attribute__((address_space(1))) unsigned int*)(gp),               \
      (__attribute__((address_space(3))) unsigned int*)(lp), 16, 0, 0)

// ---------------- fused prep: 4 weight transposes + hs conversion (1 launch) ----
// z<4: Wt[n][k] = (f16)(scale * W[k][n]); z==4: f32->f16 conv of hidden_states
// (grid-stride over 1M float4 with 1024 virtual blocks).
__global__ __launch_bounds__(256) void prep_kernel(
    const float* __restrict__ hs, const float* __restrict__ Wq,
    const float* __restrict__ Wk, const float* __restrict__ Wv,
    const float* __restrict__ Wo, _Float16* __restrict__ Xh,
    _Float16* __restrict__ Wqkvt, _Float16* __restrict__ Wot) {
  const int z = blockIdx.z;
  const int t = threadIdx.x;
  if (z < 4) {
    __shared__ float tile[32][33];
    const float* W = (z == 0) ? Wq : (z == 1) ? Wk : (z == 2) ? Wv : Wo;
    _Float16* Wt = (z < 3) ? (Wqkvt + (size_t)z * 1048576) : Wot;
    float scale = (z == 0) ? 1.44269504f : 1.0f;  // fold log2(e) into Q path
    int tx = t & 31, ty = t >> 5;                  // 32x8
    int nx = blockIdx.x * 32 + tx;
    int ky = blockIdx.y * 32;
#pragma unroll
    for (int i = 0; i < 32; i += 8) tile[ty + i][tx] = W[(size_t)(ky + ty + i) * DM + nx];
    __syncthreads();
    int kx = ky + tx;
    int ny = blockIdx.x * 32;
#pragma unroll
    for (int i = 0; i < 32; i += 8)
      Wt[(size_t)(ny + ty + i) * DM + kx] = (_Float16)(tile[tx][ty + i] * scale);
  } else {
    const int blk = blockIdx.x + (blockIdx.y << 5);  // 0..1023
    const int n4 = (NB * S_LEN * DM) / 4;            // 1048576
    for (int i = blk * 256 + t; i < n4; i += 1024 * 256) {
      float4 v = ((const float4*)hs)[i];
      half4v o;
      o[0] = (_Float16)v.x; o[1] = (_Float16)v.y; o[2] = (_Float16)v.z; o[3] = (_Float16)v.w;
      ((half4v*)Xh)[i] = o;
    }
  }
}

// ---------------- fp16 MFMA GEMM: C = A(MxK) @ Bt(NxK)^T ----------------
// MODE 0: scatter f16 into Q[b,h,s,d] | K[b,h,s,d] | V^T[b,h,d,s]; MODE 1: f32 row-major.
// T1 XCD swizzle: contiguous work chunk per XCD (nwg%8==0 -> bijective, m204).
// R9: double-buffered LDS + 2-phase prefetch: issue next-tile GLL BEFORE compute,
// ONE __syncthreads per K-step.
template <int MODE>
__global__ __launch_bounds__(256) void gemm_f16(const _Float16* __restrict__ A,
                                                const _Float16* __restrict__ Bt,
                                                void* __restrict__ Cout,
                                                int M, int N, int K) {
  __shared__ _Float16 As[2][128 * 32];
  __shared__ _Float16 Bs[2][128 * 32];
  const int t = threadIdx.x;
  const int gx = gridDim.x;
  const int nwg = gx * gridDim.y;
  const int orig = blockIdx.x + gx * blockIdx.y;
  const int wg = (orig & 7) * (nwg >> 3) + (orig >> 3);
  const int m0 = (wg / gx) * 128, n0 = (wg % gx) * 128;
  const int w = t >> 6, lane = t & 63, l15 = lane & 15, quad = lane >> 4;
  const int wr = (w >> 1) * 64, wc = (w & 1) * 64;
  const int swz = (quad ^ (l15 & 3)) * 8;

  // loop-invariant staging offsets
  const int row0_ = t >> 2, cg0 = (t & 3) ^ (row0_ & 3);
  const int row1_ = (t + 256) >> 2, cg1 = ((t + 256) & 3) ^ (row1_ & 3);
  const int aof0 = row0_ * K + cg0 * 8, aof1 = row1_ * K + cg1 * 8;
  const int lda = t * 16, ldb = (t + 256) * 16;

  f32x4 acc[4][4];
#pragma unroll
  for (int i = 0; i < 4; i++)
#pragma unroll
    for (int j = 0; j < 4; j++) acc[i][j] = (f32x4){0.f, 0.f, 0.f, 0.f};

#define GSTAGE(bs, kk)                                                     \
  do {                                                                     \
    const _Float16* ap_ = A + (size_t)m0 * K + (kk);                       \
    const _Float16* bp_ = Bt + (size_t)n0 * K + (kk);                      \
    GLL(ap_ + aof0, (char*)As[bs] + lda);                                  \
    GLL(ap_ + aof1, (char*)As[bs] + ldb);                                  \
    GLL(bp_ + aof0, (char*)Bs[bs] + lda);                                  \
    GLL(bp_ + aof1, (char*)Bs[bs] + ldb);                                  \
  } while (0)

  GSTAGE(0, 0);
  __syncthreads();

#define GTILE(c, kk)                                                          \
  do {                                                                        \
    if ((kk) + 32 < K) GSTAGE((c) ^ 1, (kk) + 32);                            \
    half8 af[4], bf[4];                                                       \
    _Pragma("unroll") for (int i = 0; i < 4; i++)                             \
        af[i] = *(const half8*)(As[c] + (wr + i * 16 + l15) * 32 + swz);      \
    _Pragma("unroll") for (int i = 0; i < 4; i++)                             \
        bf[i] = *(const half8*)(Bs[c] + (wc + i * 16 + l15) * 32 + swz);      \
    _Pragma("unroll") for (int i = 0; i < 4; i++)                             \
        _Pragma("unroll") for (int j = 0; j < 4; j++)                         \
            acc[i][j] =                                                       \
                __builtin_amdgcn_mfma_f32_16x16x32_f16(af[i], bf[j], acc[i][j], 0, 0, 0); \
    __syncthreads();                                                          \
  } while (0)

  for (int k0 = 0; k0 < K; k0 += 64) {
    GTILE(0, k0);
    GTILE(1, k0 + 32);
  }
#undef GTILE
#undef GSTAGE

#pragma unroll
  for (int i = 0; i < 4; i++)
#pragma unroll
    for (int j = 0; j < 4; j++) {
      int row0 = m0 + wr + i * 16 + quad * 4;   // C/D: row=(lane>>4)*4+reg
      int col = n0 + wc + j * 16 + l15;         //      col=lane&15
      if (MODE == 1) {
#pragma unroll
        for (int r = 0; r < 4; r++)
          ((float*)Cout)[(size_t)(row0 + r) * N + col] = acc[i][j][r];
      } else {
        int which = col >> 10, rem = col & 1023, hh = rem >> 6, dd = rem & 63;
        int bb = row0 >> 11, ss = row0 & 2047;
        _Float16* base = (_Float16*)Cout;
        if (which == 2) {  // V: transposed store [b,h,d,s], 4 consecutive s -> b64
          *(half4v*)(base + (size_t)2 * QKV_SZ +
                     ((size_t)((bb * NH + hh) * DK + dd)) * S_LEN + ss) = pack4(acc[i][j]);
        } else {
#pragma unroll
          for (int r = 0; r < 4; r++)
            base[(size_t)which * QKV_SZ +
                 ((size_t)((bb * NH + hh) * S_LEN) + ss + r) * DK + dd] = (_Float16)acc[i][j][r];
        }
      }
    }
}

// ---------------- 128x64-tile fp16 GEMM (f32 out) for the N=1024 output proj ----
// BN=64 -> 512 blocks = 2 blocks/CU. T1 XCD swizzle. R9 double-buffered 2-phase.
__global__ __launch_bounds__(256) void gemm_f16_n64(const _Float16* __restrict__ A,
                                                    const _Float16* __restrict__ Bt,
                                                    float* __restrict__ C,
                                                    int M, int N, int K) {
  __shared__ _Float16 As[2][128 * 32];
  __shared__ _Float16 Bs[2][64 * 32];
  const int t = threadIdx.x;
  const int gx = gridDim.x;
  const int nwg = gx * gridDim.y;
  const int orig = blockIdx.x + gx * blockIdx.y;
  const int wg = (orig & 7) * (nwg >> 3) + (orig >> 3);
  const int m0 = (wg / gx) * 128, n0 = (wg % gx) * 64;
  const int w = t >> 6, lane = t & 63, l15 = lane & 15, quad = lane >> 4;
  const int wr = (w >> 1) * 64, wc = (w & 1) * 32;   // 2x2 waves, each 64x32
  const int swz = (quad ^ (l15 & 3)) * 8;

  const int row0_ = t >> 2, cg0 = (t & 3) ^ (row0_ & 3);
  const int row1_ = (t + 256) >> 2, cg1 = ((t + 256) & 3) ^ (row1_ & 3);
  const int aof0 = row0_ * K + cg0 * 8, aof1 = row1_ * K + cg1 * 8;
  const int lda = t * 16, ldb = (t + 256) * 16;

  f32x4 acc[4][2];
#pragma unroll
  for (int i = 0; i < 4; i++)
#pragma unroll
    for (int j = 0; j < 2; j++) acc[i][j] = (f32x4){0.f, 0.f, 0.f, 0.f};

#define GSTAGE(bs, kk)                                                     \
  do {                                                                     \
    const _Float16* ap_ = A + (size_t)m0 * K + (kk);                       \
    const _Float16* bp_ = Bt + (size_t)n0 * K + (kk);                      \
    GLL(ap_ + aof0, (char*)As[bs] + lda);                                  \
    GLL(ap_ + aof1, (char*)As[bs] + ldb);                                  \
    GLL(bp_ + aof0, (char*)Bs[bs] + lda);                                  \
  } while (0)

  GSTAGE(0, 0);
  __syncthreads();

#define GTILE(c, kk)                                                          \
  do {                                                                        \
    if ((kk) + 32 < K) GSTAGE((c) ^ 1, (kk) + 32);                            \
    half8 af[4], bf[2];                                                       \
    _Pragma("unroll") for (int i = 0; i < 4; i++)                             \
        af[i] = *(const half8*)(As[c] + (wr + i * 16 + l15) * 32 + swz);      \
    _Pragma("unroll") for (int j = 0; j < 2; j++)                             \
        bf[j] = *(const half8*)(Bs[c] + (wc + j * 16 + l15) * 32 + swz);      \
    _Pragma("unroll") for (int i = 0; i < 4; i++)                             \
        _Pragma("unroll") for (int j = 0; j < 2; j++)                         \
            acc[i][j] =                                                       \
                __builtin_amdgcn_mfma_f32_16x16x32_f16(af[i], bf[j], acc[i][j], 0, 0, 0); \
    __syncthreads();                                                          \
  } while (0)

  for (int k0 = 0; k0 < K; k0 += 64) {
    GTILE(0, k0);
    GTILE(1, k0 + 32);
  }
#undef GTILE
#undef GSTAGE

#pragma unroll
  for (int i = 0; i < 4; i++)
#pragma unroll
    for (int j = 0; j < 2; j++) {
      int row0 = m0 + wr + i * 16 + quad * 4;   // C/D: row=(lane>>4)*4+reg
      int col = n0 + wc + j * 16 + l15;         //      col=lane&15
#pragma unroll
      for (int r = 0; r < 4; r++)
        C[(size_t)(row0 + r) * N + col] = acc[i][j][r];
    }
}

// ---------------- flash attention (S^T formulation, high-TLP) ----------------
// grid (S/64, H, B) = 1024 blocks (4/CU), block 256 = 4 waves; wave w owns q in [Q0+16w, +16).
// Safe 2-phase staging (R4); sigma key-permutation (R5, conflict-free b128 LDS);
// R6 VALU diet; R7 T13 defer-max; R8 T1 XCD swizzle (FETCH 69.8->12.4MB).
// R10: bias slab computed in-block directly from rel_bias_table (bias_tab kernel
// + btab HBM round-trip eliminated). Buckets for |rel|>=128 saturate: 15 / 31.
__global__ __launch_bounds__(256, 4) void attn_kernel(
    const _Float16* __restrict__ Q, const _Float16* __restrict__ K,
    const _Float16* __restrict__ Vt, const float* __restrict__ tbl,
    _Float16* __restrict__ attn_out) {
  __shared__ _Float16 Ks[2][4096];   // [buf][pos][d] 64x64, 16B-XOR swizzled, sigma-permuted keys
  __shared__ _Float16 Vs[2][4096];   // [buf][d][key] 64x64, 16B-XOR swizzled, natural keys
  __shared__ float slab[512];        // bias for rel in [-256,256), log2e-scaled

  const int t = threadIdx.x;
  // T1: orig = x + 32*h + 512*b (x fastest); chunked remap, nwg=1024, q=128
  const int orig = blockIdx.x + (blockIdx.y << 5) + (blockIdx.z << 9);
  const int wg = (orig & 7) * 128 + (orig >> 3);
  const int Q0 = (wg & 31) * 64;
  const int h = (wg >> 5) & 15, b = wg >> 9;
  const int w = t >> 6, lane = t & 63, l15 = lane & 15, quad = lane >> 4;
  const int qw0 = Q0 + w * 16;
  const int sw7 = l15 & 7;

  const _Float16* Qb = Q + (size_t)(b * NH + h) * S_LEN * DK;
  const _Float16* Kb = K + (size_t)(b * NH + h) * S_LEN * DK;
  const _Float16* Vb = Vt + (size_t)(b * NH + h) * S_LEN * DK;  // [d][s]

  // slab[i] = log2(e) * table[bucket(i-256)][h]  (T5 bidirectional bucketing)
  for (int i = t; i < 512; i += 256) {
    int rel = i - 256;  // rel = k - q
    int bucket = rel > 0 ? 16 : 0;
    int a = rel < 0 ? -rel : rel;
    if (a < 8) {
      bucket += a;
    } else {
      int lg = 31 - __clz(a * a);    // floor(2*log2(a))
      int large = 8 + (lg - 6);
      bucket += (large < 15 ? large : 15);
    }
    slab[i] = tbl[bucket * NH + h] * 1.44269504f;
  }
  const float cbn = tbl[15 * NH + h] * 1.44269504f;  // bias(rel<=-128): bucket 15
  const float cbp = tbl[31 * NH + h] * 1.44269504f;  // bias(rel>=+128): bucket 16+15

  // ---- loop-invariant staging offsets (per-thread) ----
  const int id0 = t, id1 = t + 256;
  const int r0_ = id0 >> 3, cg0 = (id0 & 7) ^ (r0_ & 7), p0 = r0_ & 31;
  const int sr0 = (r0_ & 32) | (((p0 >> 2) & 3) << 3) | ((p0 >> 4) << 2) | (p0 & 3);
  const int r1_ = id1 >> 3, cg1 = (id1 & 7) ^ (r1_ & 7), p1 = r1_ & 31;
  const int sr1 = (r1_ & 32) | (((p1 >> 2) & 3) << 3) | ((p1 >> 4) << 2) | (p1 & 3);
  const int kofa = sr0 * DK + cg0 * 8, kofb = sr1 * DK + cg1 * 8;
  const int vofa = r0_ * S_LEN + cg0 * 8, vofb = r1_ * S_LEN + cg1 * 8;
  const int lda = id0 * 16, ldb = id1 * 16;  // LDS byte offsets (linear, GLL order)

#define STAGE(bs, kk0)                                   \
  do {                                                   \
    const _Float16* kp_ = Kb + (size_t)(kk0) * DK;       \
    const _Float16* vp_ = Vb + (kk0);                    \
    GLL(kp_ + kofa, (char*)Ks[bs] + lda);                \
    GLL(kp_ + kofb, (char*)Ks[bs] + ldb);                \
    GLL(vp_ + vofa, (char*)Vs[bs] + lda);                \
    GLL(vp_ + vofb, (char*)Vs[bs] + ldb);                \
  } while (0)

  // Q B-fragments (B[k=d][n=q]): lane(n=l15,quad) holds d = dh*32+quad*8+j
  half8 qf[2];
#pragma unroll
  for (int dh = 0; dh < 2; dh++)
    qf[dh] = *(const half8*)(Qb + (size_t)(qw0 + l15) * DK + dh * 32 + quad * 8);

  f32x4 o[4];
#pragma unroll
  for (int dt = 0; dt < 4; dt++) o[dt] = (f32x4){0.f, 0.f, 0.f, 0.f};
  f32x4 lac = (f32x4){0.f, 0.f, 0.f, 0.f};   // l-sum accumulator (MFMA ones-trick)
  float m_ = -INFINITY;
  const half4v ones = {(_Float16)1.f, (_Float16)1.f, (_Float16)1.f, (_Float16)1.f};

  // loop-invariant LDS read offsets (half-index): rd1 = rd0 ^ 32 (the dh/s=1 XOR lane)
  const int rd0 = l15 * 64 + (quad ^ sw7) * 8;
  const int rd1 = rd0 ^ 32;

  STAGE(0, 0);
  __syncthreads();   // drains tile0 GLL + slab writes; all waves see buf 0

  // ---- one 64-key tile; c is a literal so all ds_reads are base+immediate ----
#define TILE(c, kk, stage_ok)                                                         \
  do {                                                                                \
    if (stage_ok) STAGE((c) ^ 1, (kk) + 64);  /* prefetch: in flight under compute */ \
    const int dk0 = (kk) - qw0;                                                       \
    const bool farneg = (dk0 <= -191);                                                \
    const bool farpos = (dk0 >= 143);                                                 \
    const bool nearc = !(farneg || farpos);                                           \
    const float cb = farneg ? cbn : cbp;                                              \
    f32x4 st[4];                                                                      \
    if (nearc) {                                                                      \
      _Pragma("unroll") for (int kt = 0; kt < 4; kt++) {                              \
        int i0 = dk0 + (kt >> 1) * 32 + quad * 8 + (kt & 1) * 4 - l15 + 256;          \
        f32x4 v_;                                                                     \
        v_[0] = slab[i0]; v_[1] = slab[i0 + 1];                                       \
        v_[2] = slab[i0 + 2]; v_[3] = slab[i0 + 3];                                   \
        st[kt] = v_;                                                                  \
      }                                                                               \
    } else {                                                                          \
      _Pragma("unroll") for (int kt = 0; kt < 4; kt++)                                \
          st[kt] = (f32x4){0.f, 0.f, 0.f, 0.f};                                       \
    }                                                                                 \
    half8 kf0[4], kf1[4];                                                             \
    _Pragma("unroll") for (int kt = 0; kt < 4; kt++) {                                \
      kf0[kt] = *(const half8*)(&Ks[c][rd0 + kt * 1024]);                             \
      kf1[kt] = *(const half8*)(&Ks[c][rd1 + kt * 1024]);                             \
    }                                                                                 \
    __builtin_amdgcn_s_setprio(1);                                                    \
    _Pragma("unroll") for (int kt = 0; kt < 4; kt++) {                                \
      st[kt] = __builtin_amdgcn_mfma_f32_16x16x32_f16(kf0[kt], qf[0], st[kt], 0, 0, 0); \
      st[kt] = __builtin_amdgcn_mfma_f32_16x16x32_f16(kf1[kt], qf[1], st[kt], 0, 0, 0); \
    }                                                                                 \
    __builtin_amdgcn_s_setprio(0);                                                    \
    /* max tree (max3-fusable) */                                                     \
    float x0 = fmaxf(fmaxf(st[0][0], st[0][1]), st[0][2]);                            \
    float x1 = fmaxf(fmaxf(st[0][3], st[1][0]), st[1][1]);                            \
    float x2 = fmaxf(fmaxf(st[1][2], st[1][3]), st[2][0]);                            \
    float x3 = fmaxf(fmaxf(st[2][1], st[2][2]), st[2][3]);                            \
    float x4 = fmaxf(fmaxf(st[3][0], st[3][1]), st[3][2]);                            \
    float cm = fmaxf(fmaxf(fmaxf(x0, x1), fmaxf(x2, x3)), fmaxf(x4, st[3][3]));       \
    cm = fmaxf(cm, __shfl_xor(cm, 16));                                               \
    cm = fmaxf(cm, __shfl_xor(cm, 32));                                               \
    float mc = nearc ? cm : cm + cb;                                                  \
    if (__any(mc > m_ + 8.f)) {  /* T13: rescale only when max grew by >8 (log2) */   \
      float mnew = fmaxf(m_, mc);                                                     \
      float alpha = __builtin_amdgcn_exp2f(m_ - mnew);                                \
      m_ = mnew;                                                                      \
      lac *= alpha;                                                                   \
      _Pragma("unroll") for (int dt = 0; dt < 4; dt++) o[dt] *= alpha;                \
    }                                                                                 \
    float msub = nearc ? m_ : m_ - cb;                                                \
    half4v p16[4];                                                                    \
    _Pragma("unroll") for (int kt = 0; kt < 4; kt++) {                                \
      f32x4 p_;                                                                       \
      _Pragma("unroll") for (int r = 0; r < 4; r++)                                   \
          p_[r] = __builtin_amdgcn_exp2f(st[kt][r] - msub);                           \
      p16[kt] = pack4(p_);                                                            \
    }                                                                                 \
    __builtin_amdgcn_s_setprio(1);                                                    \
    /* l-sum via MFMA: A=ones -> every acc reg += full 16-key sum of P (per q=l15) */ \
    _Pragma("unroll") for (int kt = 0; kt < 4; kt++)                                  \
        lac = __builtin_amdgcn_mfma_f32_16x16x16f16(ones, p16[kt], lac, 0, 0, 0);     \
    _Pragma("unroll") for (int dt = 0; dt < 4; dt++) {                                \
      half8 va_ = *(const half8*)(&Vs[c][rd0 + dt * 1024]);                           \
      half8 vb_ = *(const half8*)(&Vs[c][rd1 + dt * 1024]);                           \
      half4v alo = {va_[0], va_[1], va_[2], va_[3]};                                  \
      half4v ahi = {va_[4], va_[5], va_[6], va_[7]};                                  \
      half4v blo = {vb_[0], vb_[1], vb_[2], vb_[3]};                                  \
      half4v bhi = {vb_[4], vb_[5], vb_[6], vb_[7]};                                  \
      o[dt] = __builtin_amdgcn_mfma_f32_16x16x16f16(alo, p16[0], o[dt], 0, 0, 0);     \
      o[dt] = __builtin_amdgcn_mfma_f32_16x16x16f16(ahi, p16[1], o[dt], 0, 0, 0);     \
      o[dt] = __builtin_amdgcn_mfma_f32_16x16x16f16(blo, p16[2], o[dt], 0, 0, 0);     \
      o[dt] = __builtin_amdgcn_mfma_f32_16x16x16f16(bhi, p16[3], o[dt], 0, 0, 0);     \
    }                                                                                 \
    __builtin_amdgcn_s_setprio(0);                                                    \
    __syncthreads();   /* drains prefetch GLL + all LDS reads; swap safe */           \
  } while (0)

  for (int k0 = 0; k0 < S_LEN; k0 += 128) {
    TILE(0, k0, 1);                              // stage for k0+64 (always valid)
    TILE(1, k0 + 64, (k0 + 128 < S_LEN));        // stage for k0+128 (skip on last)
  }
#undef TILE
#undef STAGE

  // finalize: lac already holds full l in every reg/lane (ones-MFMA sums all quads)
  float inv = 1.0f / lac[0];
  int q = qw0 + l15;
#pragma unroll
  for (int dt = 0; dt < 4; dt++) {
    f32x4 ov = o[dt] * inv;
    *(half4v*)(attn_out + ((size_t)(b * S_LEN + q)) * DM + h * DK + dt * 16 + quad * 4) =
        pack4(ov);
  }
}

// ---------------- launch ----------------
extern "C" void kernel_launch(void* const* d_in, const int* in_sizes, int n_in,
                              void* d_out, int out_size, void* d_ws, size_t ws_size,
                              hipStream_t stream) {
  const float* hs  = (const float*)d_in[0];
  const float* Wq  = (const float*)d_in[1];
  const float* Wk  = (const float*)d_in[2];
  const float* Wv  = (const float*)d_in[3];
  const float* Wo  = (const float*)d_in[4];
  const float* tbl = (const float*)d_in[5];
  float* out = (float*)d_out;
  char* ws = (char*)d_ws;

  _Float16* Xh    = (_Float16*)(ws);                    // 8 MB
  _Float16* Wqkvt = (_Float16*)(ws + (8u << 20));       // 6 MB (Wq|Wk|Wv transposed)
  _Float16* Wot   = (_Float16*)(ws + (14u << 20));      // 2 MB
  _Float16* Qd    = (_Float16*)(ws + (16u << 20));      // Q | K | V^T, 8 MB each
  _Float16* Kd    = Qd + (size_t)QKV_SZ;
  _Float16* Vd    = Qd + (size_t)2 * QKV_SZ;
  _Float16* Ah    = (_Float16*)(ws + (40u << 20));      // 8 MB attention out (b,s,h*d)

  prep_kernel<<<dim3(32, 32, 5), 256, 0, stream>>>(hs, Wq, Wk, Wv, Wo, Xh, Wqkvt, Wot);
  gemm_f16<0><<<dim3(24, 32), 256, 0, stream>>>(Xh, Wqkvt, (void*)Qd, NB * S_LEN, 3 * DM, DM);
  attn_kernel<<<dim3(S_LEN / 64, NH, NB), 256, 0, stream>>>(Qd, Kd, Vd, tbl, Ah);
  gemm_f16_n64<<<dim3(16, 32), 256, 0, stream>>>(Ah, Wot, out, NB * S_LEN, DM, DM);
}

// Round 12
// 192.426 us; speedup vs baseline: 1.1731x; 1.0147x over previous
//
#include <hip/hip_runtime.h>
#include <hip/hip_fp16.h>

#define S_LEN 2048
#define NH 16
#define DK 64
#define DM 1024
#define NB 2
#define QKV_SZ (NB * NH * S_LEN * DK)  // 4194304 halfs per tensor

typedef _Float16 half8 __attribute__((ext_vector_type(8)));
typedef _Float16 half4v __attribute__((ext_vector_type(4)));
typedef __fp16 fp16x2 __attribute__((ext_vector_type(2)));
typedef float f32x4 __attribute__((ext_vector_type(4)));

// pack 4 f32 -> 4 f16 (rtz) as one 64-bit value
static __device__ __forceinline__ half4v pack4(const f32x4 v) {
  fp16x2 lo = __builtin_amdgcn_cvt_pkrtz(v[0], v[1]);
  fp16x2 hi = __builtin_amdgcn_cvt_pkrtz(v[2], v[3]);
  half4v r;
  ((fp16x2*)&r)[0] = lo;
  ((fp16x2*)&r)[1] = hi;
  return r;
}

#define GLL(gp, lp)                                                              \
  __builtin_amdgcn_global_load_lds(                                              \
      (const __attribute__((address_space(1))) unsigned int*)(gp),               \
      (__attribute__((address_space(3))) unsigned int*)(lp), 16, 0, 0)

// ---------------- fused prep: 4 weight transposes + hs conversion (1 launch) ----
// z<4: Wt[n][k] = (f16)(scale * W[k][n]); z==4: f32->f16 conv of hidden_states
// (grid-stride over 1M float4 with 1024 virtual blocks).
__global__ __launch_bounds__(256) void prep_kernel(
    const float* __restrict__ hs, const float* __restrict__ Wq,
    const float* __restrict__ Wk, const float* __restrict__ Wv,
    const float* __restrict__ Wo, _Float16* __restrict__ Xh,
    _Float16* __restrict__ Wqkvt, _Float16* __restrict__ Wot) {
  const int z = blockIdx.z;
  const int t = threadIdx.x;
  if (z < 4) {
    __shared__ float tile[32][33];
    const float* W = (z == 0) ? Wq : (z == 1) ? Wk : (z == 2) ? Wv : Wo;
    _Float16* Wt = (z < 3) ? (Wqkvt + (size_t)z * 1048576) : Wot;
    float scale = (z == 0) ? 1.44269504f : 1.0f;  // fold log2(e) into Q path
    int tx = t & 31, ty = t >> 5;                  // 32x8
    int nx = blockIdx.x * 32 + tx;
    int ky = blockIdx.y * 32;
#pragma unroll
    for (int i = 0; i < 32; i += 8) tile[ty + i][tx] = W[(size_t)(ky + ty + i) * DM + nx];
    __syncthreads();
    int kx = ky + tx;
    int ny = blockIdx.x * 32;
#pragma unroll
    for (int i = 0; i < 32; i += 8)
      Wt[(size_t)(ny + ty + i) * DM + kx] = (_Float16)(tile[tx][ty + i] * scale);
  } else {
    const int blk = blockIdx.x + (blockIdx.y << 5);  // 0..1023
    const int n4 = (NB * S_LEN * DM) / 4;            // 1048576
    for (int i = blk * 256 + t; i < n4; i += 1024 * 256) {
      float4 v = ((const float4*)hs)[i];
      half4v o;
      o[0] = (_Float16)v.x; o[1] = (_Float16)v.y; o[2] = (_Float16)v.z; o[3] = (_Float16)v.w;
      ((half4v*)Xh)[i] = o;
    }
  }
}

// ---------------- fp16 MFMA GEMM: C = A(MxK) @ Bt(NxK)^T ----------------
// MODE 0: scatter f16 into Q[b,h,s,d] | K[b,h,s,d] | V^T[b,h,d,s]; MODE 1: f32 row-major.
// T1 XCD swizzle: contiguous work chunk per XCD (nwg%8==0 -> bijective, m204).
// R9: double-buffered LDS + 2-phase prefetch: issue next-tile GLL BEFORE compute,
// ONE __syncthreads per K-step.
template <int MODE>
__global__ __launch_bounds__(256) void gemm_f16(const _Float16* __restrict__ A,
                                                const _Float16* __restrict__ Bt,
                                                void* __restrict__ Cout,
                                                int M, int N, int K) {
  __shared__ _Float16 As[2][128 * 32];
  __shared__ _Float16 Bs[2][128 * 32];
  const int t = threadIdx.x;
  const int gx = gridDim.x;
  const int nwg = gx * gridDim.y;
  const int orig = blockIdx.x + gx * blockIdx.y;
  const int wg = (orig & 7) * (nwg >> 3) + (orig >> 3);
  const int m0 = (wg / gx) * 128, n0 = (wg % gx) * 128;
  const int w = t >> 6, lane = t & 63, l15 = lane & 15, quad = lane >> 4;
  const int wr = (w >> 1) * 64, wc = (w & 1) * 64;
  const int swz = (quad ^ (l15 & 3)) * 8;

  // loop-invariant staging offsets
  const int row0_ = t >> 2, cg0 = (t & 3) ^ (row0_ & 3);
  const int row1_ = (t + 256) >> 2, cg1 = ((t + 256) & 3) ^ (row1_ & 3);
  const int aof0 = row0_ * K + cg0 * 8, aof1 = row1_ * K + cg1 * 8;
  const int lda = t * 16, ldb = (t + 256) * 16;

  f32x4 acc[4][4];
#pragma unroll
  for (int i = 0; i < 4; i++)
#pragma unroll
    for (int j = 0; j < 4; j++) acc[i][j] = (f32x4){0.f, 0.f, 0.f, 0.f};

#define GSTAGE(bs, kk)                                                     \
  do {                                                                     \
    const _Float16* ap_ = A + (size_t)m0 * K + (kk);                       \
    const _Float16* bp_ = Bt + (size_t)n0 * K + (kk);                      \
    GLL(ap_ + aof0, (char*)As[bs] + lda);                                  \
    GLL(ap_ + aof1, (char*)As[bs] + ldb);                                  \
    GLL(bp_ + aof0, (char*)Bs[bs] + lda);                                  \
    GLL(bp_ + aof1, (char*)Bs[bs] + ldb);                                  \
  } while (0)

  GSTAGE(0, 0);
  __syncthreads();

#define GTILE(c, kk)                                                          \
  do {                                                                        \
    if ((kk) + 32 < K) GSTAGE((c) ^ 1, (kk) + 32);                            \
    half8 af[4], bf[4];                                                       \
    _Pragma("unroll") for (int i = 0; i < 4; i++)                             \
        af[i] = *(const half8*)(As[c] + (wr + i * 16 + l15) * 32 + swz);      \
    _Pragma("unroll") for (int i = 0; i < 4; i++)                             \
        bf[i] = *(const half8*)(Bs[c] + (wc + i * 16 + l15) * 32 + swz);      \
    _Pragma("unroll") for (int i = 0; i < 4; i++)                             \
        _Pragma("unroll") for (int j = 0; j < 4; j++)                         \
            acc[i][j] =                                                       \
                __builtin_amdgcn_mfma_f32_16x16x32_f16(af[i], bf[j], acc[i][j], 0, 0, 0); \
    __syncthreads();                                                          \
  } while (0)

  for (int k0 = 0; k0 < K; k0 += 64) {
    GTILE(0, k0);
    GTILE(1, k0 + 32);
  }
#undef GTILE
#undef GSTAGE

#pragma unroll
  for (int i = 0; i < 4; i++)
#pragma unroll
    for (int j = 0; j < 4; j++) {
      int row0 = m0 + wr + i * 16 + quad * 4;   // C/D: row=(lane>>4)*4+reg
      int col = n0 + wc + j * 16 + l15;         //      col=lane&15
      if (MODE == 1) {
#pragma unroll
        for (int r = 0; r < 4; r++)
          ((float*)Cout)[(size_t)(row0 + r) * N + col] = acc[i][j][r];
      } else {
        int which = col >> 10, rem = col & 1023, hh = rem >> 6, dd = rem & 63;
        int bb = row0 >> 11, ss = row0 & 2047;
        _Float16* base = (_Float16*)Cout;
        if (which == 2) {  // V: transposed store [b,h,d,s], 4 consecutive s -> b64
          *(half4v*)(base + (size_t)2 * QKV_SZ +
                     ((size_t)((bb * NH + hh) * DK + dd)) * S_LEN + ss) = pack4(acc[i][j]);
        } else {
#pragma unroll
          for (int r = 0; r < 4; r++)
            base[(size_t)which * QKV_SZ +
                 ((size_t)((bb * NH + hh) * S_LEN) + ss + r) * DK + dd] = (_Float16)acc[i][j][r];
        }
      }
    }
}

// ---------------- 128x64-tile fp16 GEMM (f32 out) for the N=1024 output proj ----
// BN=64 -> 512 blocks = 2 blocks/CU. T1 XCD swizzle. R9 double-buffered 2-phase.
__global__ __launch_bounds__(256) void gemm_f16_n64(const _Float16* __restrict__ A,
                                                    const _Float16* __restrict__ Bt,
                                                    float* __restrict__ C,
                                                    int M, int N, int K) {
  __shared__ _Float16 As[2][128 * 32];
  __shared__ _Float16 Bs[2][64 * 32];
  const int t = threadIdx.x;
  const int gx = gridDim.x;
  const int nwg = gx * gridDim.y;
  const int orig = blockIdx.x + gx * blockIdx.y;
  const int wg = (orig & 7) * (nwg >> 3) + (orig >> 3);
  const int m0 = (wg / gx) * 128, n0 = (wg % gx) * 64;
  const int w = t >> 6, lane = t & 63, l15 = lane & 15, quad = lane >> 4;
  const int wr = (w >> 1) * 64, wc = (w & 1) * 32;   // 2x2 waves, each 64x32
  const int swz = (quad ^ (l15 & 3)) * 8;

  const int row0_ = t >> 2, cg0 = (t & 3) ^ (row0_ & 3);
  const int row1_ = (t + 256) >> 2, cg1 = ((t + 256) & 3) ^ (row1_ & 3);
  const int aof0 = row0_ * K + cg0 * 8, aof1 = row1_ * K + cg1 * 8;
  const int lda = t * 16, ldb = (t + 256) * 16;

  f32x4 acc[4][2];
#pragma unroll
  for (int i = 0; i < 4; i++)
#pragma unroll
    for (int j = 0; j < 2; j++) acc[i][j] = (f32x4){0.f, 0.f, 0.f, 0.f};

#define GSTAGE(bs, kk)                                                     \
  do {                                                                     \
    const _Float16* ap_ = A + (size_t)m0 * K + (kk);                       \
    const _Float16* bp_ = Bt + (size_t)n0 * K + (kk);                      \
    GLL(ap_ + aof0, (char*)As[bs] + lda);                                  \
    GLL(ap_ + aof1, (char*)As[bs] + ldb);                                  \
    GLL(bp_ + aof0, (char*)Bs[bs] + lda);                                  \
  } while (0)

  GSTAGE(0, 0);
  __syncthreads();

#define GTILE(c, kk)                                                          \
  do {                                                                        \
    if ((kk) + 32 < K) GSTAGE((c) ^ 1, (kk) + 32);                            \
    half8 af[4], bf[2];                                                       \
    _Pragma("unroll") for (int i = 0; i < 4; i++)                             \
        af[i] = *(const half8*)(As[c] + (wr + i * 16 + l15) * 32 + swz);      \
    _Pragma("unroll") for (int j = 0; j < 2; j++)                             \
        bf[j] = *(const half8*)(Bs[c] + (wc + j * 16 + l15) * 32 + swz);      \
    _Pragma("unroll") for (int i = 0; i < 4; i++)                             \
        _Pragma("unroll") for (int j = 0; j < 2; j++)                         \
            acc[i][j] =                                                       \
                __builtin_amdgcn_mfma_f32_16x16x32_f16(af[i], bf[j], acc[i][j], 0, 0, 0); \
    __syncthreads();                                                          \
  } while (0)

  for (int k0 = 0; k0 < K; k0 += 64) {
    GTILE(0, k0);
    GTILE(1, k0 + 32);
  }
#undef GTILE
#undef GSTAGE

#pragma unroll
  for (int i = 0; i < 4; i++)
#pragma unroll
    for (int j = 0; j < 2; j++) {
      int row0 = m0 + wr + i * 16 + quad * 4;   // C/D: row=(lane>>4)*4+reg
      int col = n0 + wc + j * 16 + l15;         //      col=lane&15
#pragma unroll
      for (int r = 0; r < 4; r++)
        C[(size_t)(row0 + r) * N + col] = acc[i][j][r];
    }
}

// ---------------- flash attention (S^T formulation, high-TLP) ----------------
// grid (S/64, H, B) = 1024 blocks (4/CU), block 256 = 4 waves; wave w owns q in [Q0+16w, +16).
// Safe 2-phase staging (R4); sigma key-permutation (R5, conflict-free b128 LDS);
// R6 VALU diet; R7 T13 defer-max; R8 T1 XCD swizzle; R10 in-block bias slab.
// R12: PV + l-sum use 16x16x32 MFMA — under sigma, concat(p16[2s],p16[2s+1]) IS the
// K=32 B-fragment (keys s*32+quad*8+0..7) and the existing b128 V-reads are the
// A-fragment. MFMA slots/tile: 28 -> 18 (PV 16->8, lac 4->2), no new data movement.
__global__ __launch_bounds__(256, 4) void attn_kernel(
    const _Float16* __restrict__ Q, const _Float16* __restrict__ K,
    const _Float16* __restrict__ Vt, const float* __restrict__ tbl,
    _Float16* __restrict__ attn_out) {
  __shared__ _Float16 Ks[2][4096];   // [buf][pos][d] 64x64, 16B-XOR swizzled, sigma-permuted keys
  __shared__ _Float16 Vs[2][4096];   // [buf][d][key] 64x64, 16B-XOR swizzled, natural keys
  __shared__ float slab[512];        // bias for rel in [-256,256), log2e-scaled

  const int t = threadIdx.x;
  // T1: orig = x + 32*h + 512*b (x fastest); chunked remap, nwg=1024, q=128
  const int orig = blockIdx.x + (blockIdx.y << 5) + (blockIdx.z << 9);
  const int wg = (orig & 7) * 128 + (orig >> 3);
  const int Q0 = (wg & 31) * 64;
  const int h = (wg >> 5) & 15, b = wg >> 9;
  const int w = t >> 6, lane = t & 63, l15 = lane & 15, quad = lane >> 4;
  const int qw0 = Q0 + w * 16;
  const int sw7 = l15 & 7;

  const _Float16* Qb = Q + (size_t)(b * NH + h) * S_LEN * DK;
  const _Float16* Kb = K + (size_t)(b * NH + h) * S_LEN * DK;
  const _Float16* Vb = Vt + (size_t)(b * NH + h) * S_LEN * DK;  // [d][s]

  // slab[i] = log2(e) * table[bucket(i-256)][h]  (T5 bidirectional bucketing)
  for (int i = t; i < 512; i += 256) {
    int rel = i - 256;  // rel = k - q
    int bucket = rel > 0 ? 16 : 0;
    int a = rel < 0 ? -rel : rel;
    if (a < 8) {
      bucket += a;
    } else {
      int lg = 31 - __clz(a * a);    // floor(2*log2(a))
      int large = 8 + (lg - 6);
      bucket += (large < 15 ? large : 15);
    }
    slab[i] = tbl[bucket * NH + h] * 1.44269504f;
  }
  const float cbn = tbl[15 * NH + h] * 1.44269504f;  // bias(rel<=-128): bucket 15
  const float cbp = tbl[31 * NH + h] * 1.44269504f;  // bias(rel>=+128): bucket 16+15

  // ---- loop-invariant staging offsets (per-thread) ----
  const int id0 = t, id1 = t + 256;
  const int r0_ = id0 >> 3, cg0 = (id0 & 7) ^ (r0_ & 7), p0 = r0_ & 31;
  const int sr0 = (r0_ & 32) | (((p0 >> 2) & 3) << 3) | ((p0 >> 4) << 2) | (p0 & 3);
  const int r1_ = id1 >> 3, cg1 = (id1 & 7) ^ (r1_ & 7), p1 = r1_ & 31;
  const int sr1 = (r1_ & 32) | (((p1 >> 2) & 3) << 3) | ((p1 >> 4) << 2) | (p1 & 3);
  const int kofa = sr0 * DK + cg0 * 8, kofb = sr1 * DK + cg1 * 8;
  const int vofa = r0_ * S_LEN + cg0 * 8, vofb = r1_ * S_LEN + cg1 * 8;
  const int lda = id0 * 16, ldb = id1 * 16;  // LDS byte offsets (linear, GLL order)

#define STAGE(bs, kk0)                                   \
  do {                                                   \
    const _Float16* kp_ = Kb + (size_t)(kk0) * DK;       \
    const _Float16* vp_ = Vb + (kk0);                    \
    GLL(kp_ + kofa, (char*)Ks[bs] + lda);                \
    GLL(kp_ + kofb, (char*)Ks[bs] + ldb);                \
    GLL(vp_ + vofa, (char*)Vs[bs] + lda);                \
    GLL(vp_ + vofb, (char*)Vs[bs] + ldb);                \
  } while (0)

  // Q B-fragments (B[k=d][n=q]): lane(n=l15,quad) holds d = dh*32+quad*8+j
  half8 qf[2];
#pragma unroll
  for (int dh = 0; dh < 2; dh++)
    qf[dh] = *(const half8*)(Qb + (size_t)(qw0 + l15) * DK + dh * 32 + quad * 8);

  f32x4 o[4];
#pragma unroll
  for (int dt = 0; dt < 4; dt++) o[dt] = (f32x4){0.f, 0.f, 0.f, 0.f};
  f32x4 lac = (f32x4){0.f, 0.f, 0.f, 0.f};   // l-sum accumulator (MFMA ones-trick)
  float m_ = -INFINITY;
  const half8 ones8 = {(_Float16)1.f, (_Float16)1.f, (_Float16)1.f, (_Float16)1.f,
                       (_Float16)1.f, (_Float16)1.f, (_Float16)1.f, (_Float16)1.f};

  // loop-invariant LDS read offsets (half-index): rd1 = rd0 ^ 32 (the dh/s=1 XOR lane)
  const int rd0 = l15 * 64 + (quad ^ sw7) * 8;
  const int rd1 = rd0 ^ 32;

  STAGE(0, 0);
  __syncthreads();   // drains tile0 GLL + slab writes; all waves see buf 0

  // ---- one 64-key tile; c is a literal so all ds_reads are base+immediate ----
#define TILE(c, kk, stage_ok)                                                         \
  do {                                                                                \
    if (stage_ok) STAGE((c) ^ 1, (kk) + 64);  /* prefetch: in flight under compute */ \
    const int dk0 = (kk) - qw0;                                                       \
    const bool farneg = (dk0 <= -191);                                                \
    const bool farpos = (dk0 >= 143);                                                 \
    const bool nearc = !(farneg || farpos);                                           \
    const float cb = farneg ? cbn : cbp;                                              \
    f32x4 st[4];                                                                      \
    if (nearc) {                                                                      \
      _Pragma("unroll") for (int kt = 0; kt < 4; kt++) {                              \
        int i0 = dk0 + (kt >> 1) * 32 + quad * 8 + (kt & 1) * 4 - l15 + 256;          \
        f32x4 v_;                                                                     \
        v_[0] = slab[i0]; v_[1] = slab[i0 + 1];                                       \
        v_[2] = slab[i0 + 2]; v_[3] = slab[i0 + 3];                                   \
        st[kt] = v_;                                                                  \
      }                                                                               \
    } else {                                                                          \
      _Pragma("unroll") for (int kt = 0; kt < 4; kt++)                                \
          st[kt] = (f32x4){0.f, 0.f, 0.f, 0.f};                                       \
    }                                                                                 \
    half8 kf0[4], kf1[4];                                                             \
    _Pragma("unroll") for (int kt = 0; kt < 4; kt++) {                                \
      kf0[kt] = *(const half8*)(&Ks[c][rd0 + kt * 1024]);                             \
      kf1[kt] = *(const half8*)(&Ks[c][rd1 + kt * 1024]);                             \
    }                                                                                 \
    __builtin_amdgcn_s_setprio(1);                                                    \
    _Pragma("unroll") for (int kt = 0; kt < 4; kt++) {                                \
      st[kt] = __builtin_amdgcn_mfma_f32_16x16x32_f16(kf0[kt], qf[0], st[kt], 0, 0, 0); \
      st[kt] = __builtin_amdgcn_mfma_f32_16x16x32_f16(kf1[kt], qf[1], st[kt], 0, 0, 0); \
    }                                                                                 \
    __builtin_amdgcn_s_setprio(0);                                                    \
    /* max tree (max3-fusable) */                                                     \
    float x0 = fmaxf(fmaxf(st[0][0], st[0][1]), st[0][2]);                            \
    float x1 = fmaxf(fmaxf(st[0][3], st[1][0]), st[1][1]);                            \
    float x2 = fmaxf(fmaxf(st[1][2], st[1][3]), st[2][0]);                            \
    float x3 = fmaxf(fmaxf(st[2][1], st[2][2]), st[2][3]);                            \
    float x4 = fmaxf(fmaxf(st[3][0], st[3][1]), st[3][2]);                            \
    float cm = fmaxf(fmaxf(fmaxf(x0, x1), fmaxf(x2, x3)), fmaxf(x4, st[3][3]));       \
    cm = fmaxf(cm, __shfl_xor(cm, 16));                                               \
    cm = fmaxf(cm, __shfl_xor(cm, 32));                                               \
    float mc = nearc ? cm : cm + cb;                                                  \
    if (__any(mc > m_ + 8.f)) {  /* T13: rescale only when max grew by >8 (log2) */   \
      float mnew = fmaxf(m_, mc);                                                     \
      float alpha = __builtin_amdgcn_exp2f(m_ - mnew);                                \
      m_ = mnew;                                                                      \
      lac *= alpha;                                                                   \
      _Pragma("unroll") for (int dt = 0; dt < 4; dt++) o[dt] *= alpha;                \
    }                                                                                 \
    float msub = nearc ? m_ : m_ - cb;                                                \
    half8 pb0, pb1;                                                                   \
    _Pragma("unroll") for (int kt = 0; kt < 4; kt++) {                                \
      f32x4 p_;                                                                       \
      _Pragma("unroll") for (int r = 0; r < 4; r++)                                   \
          p_[r] = __builtin_amdgcn_exp2f(st[kt][r] - msub);                           \
      ((half4v*)((kt < 2) ? &pb0 : &pb1))[kt & 1] = pack4(p_);                        \
    }                                                                                 \
    __builtin_amdgcn_s_setprio(1);                                                    \
    /* l-sum via K=32 MFMA: A=ones8 -> every acc reg += full 32-key sum (per q=l15) */\
    lac = __builtin_amdgcn_mfma_f32_16x16x32_f16(ones8, pb0, lac, 0, 0, 0);           \
    lac = __builtin_amdgcn_mfma_f32_16x16x32_f16(ones8, pb1, lac, 0, 0, 0);           \
    /* O^T += V^T P^T, K=32: A-frag = b128 V-read (keys s*32+quad*8+0..7), B = pbs */ \
    _Pragma("unroll") for (int dt = 0; dt < 4; dt++) {                                \
      half8 va_ = *(const half8*)(&Vs[c][rd0 + dt * 1024]);                           \
      half8 vb_ = *(const half8*)(&Vs[c][rd1 + dt * 1024]);                           \
      o[dt] = __builtin_amdgcn_mfma_f32_16x16x32_f16(va_, pb0, o[dt], 0, 0, 0);       \
      o[dt] = __builtin_amdgcn_mfma_f32_16x16x32_f16(vb_, pb1, o[dt], 0, 0, 0);       \
    }                                                                                 \
    __builtin_amdgcn_s_setprio(0);                                                    \
    __syncthreads();   /* drains prefetch GLL + all LDS reads; swap safe */           \
  } while (0)

  for (int k0 = 0; k0 < S_LEN; k0 += 128) {
    TILE(0, k0, 1);                              // stage for k0+64 (always valid)
    TILE(1, k0 + 64, (k0 + 128 < S_LEN));        // stage for k0+128 (skip on last)
  }
#undef TILE
#undef STAGE

  // finalize: lac already holds full l in every reg/lane (ones-MFMA sums all quads)
  float inv = 1.0f / lac[0];
  int q = qw0 + l15;
#pragma unroll
  for (int dt = 0; dt < 4; dt++) {
    f32x4 ov = o[dt] * inv;
    *(half4v*)(attn_out + ((size_t)(b * S_LEN + q)) * DM + h * DK + dt * 16 + quad * 4) =
        pack4(ov);
  }
}

// ---------------- launch ----------------
extern "C" void kernel_launch(void* const* d_in, const int* in_sizes, int n_in,
                              void* d_out, int out_size, void* d_ws, size_t ws_size,
                              hipStream_t stream) {
  const float* hs  = (const float*)d_in[0];
  const float* Wq  = (const float*)d_in[1];
  const float* Wk  = (const float*)d_in[2];
  const float* Wv  = (const float*)d_in[3];
  const float* Wo  = (const float*)d_in[4];
  const float* tbl = (const float*)d_in[5];
  float* out = (float*)d_out;
  char* ws = (char*)d_ws;

  _Float16* Xh    = (_Float16*)(ws);                    // 8 MB
  _Float16* Wqkvt = (_Float16*)(ws + (8u << 20));       // 6 MB (Wq|Wk|Wv transposed)
  _Float16* Wot   = (_Float16*)(ws + (14u << 20));      // 2 MB
  _Float16* Qd    = (_Float16*)(ws + (16u << 20));      // Q | K | V^T, 8 MB each
  _Float16* Kd    = Qd + (size_t)QKV_SZ;
  _Float16* Vd    = Qd + (size_t)2 * QKV_SZ;
  _Float16* Ah    = (_Float16*)(ws + (40u << 20));      // 8 MB attention out (b,s,h*d)

  prep_kernel<<<dim3(32, 32, 5), 256, 0, stream>>>(hs, Wq, Wk, Wv, Wo, Xh, Wqkvt, Wot);
  gemm_f16<0><<<dim3(24, 32), 256, 0, stream>>>(Xh, Wqkvt, (void*)Qd, NB * S_LEN, 3 * DM, DM);
  attn_kernel<<<dim3(S_LEN / 64, NH, NB), 256, 0, stream>>>(Qd, Kd, Vd, tbl, Ah);
  gemm_f16_n64<<<dim3(16, 32), 256, 0, stream>>>(Ah, Wot, out, NB * S_LEN, DM, DM);
}